// Round 4
// baseline (400.702 us; speedup 1.0000x reference)
//
#include <hip/hip_runtime.h>
#include <hip/hip_bf16.h>
#include <cstdint>
#include <cstddef>

#define N_RAYS 262144
#define NR 32
#define THREADS 256
#define FSTRIDE 292

// offsets in uint16 elements into the transposed-grid arena
#define T0_OFF 0u
#define T1_OFF 1572864u      // 6*128*128*16
#define T2_OFF 7864320u      // + 6*256*256*16
#define T_ELEMS 33030144u    // 6*16*(128^2+256^2+512^2)
#define FEAT_BYTE_OFF 66060288u   // T_ELEMS*2
#define FEAT_DWORDS 37748736u     // 262144*144
#define W1F_BYTE_OFF 217055232u   // FEAT_BYTE_OFF + FEAT_DWORDS*4
#define W1F_BYTES 73728u          // 288*128*2

typedef __attribute__((ext_vector_type(8))) short short8v;   // 8 bf16 = 4 VGPRs
typedef __attribute__((ext_vector_type(4))) float float4v;   // MFMA C/D

// ---------- helpers ----------
__device__ __forceinline__ float bf_lo(uint32_t w) { return __uint_as_float(w << 16); }
__device__ __forceinline__ float bf_hi(uint32_t w) { return __uint_as_float(w & 0xFFFF0000u); }

__device__ __forceinline__ float bf_extract(const uint4& q, int i) {
    uint32_t w = ((const uint32_t*)&q)[i >> 1];
    uint32_t h = (i & 1) ? (w & 0xFFFF0000u) : (w << 16);
    return __uint_as_float(h);
}

__device__ __forceinline__ uint16_t f2bf_rne(float f) {
    uint32_t x = __float_as_uint(f);
    uint32_t r = x + 0x7FFFu + ((x >> 16) & 1u);
    return (uint16_t)(r >> 16);
}

__device__ __forceinline__ float sel4(const float4& p, int i) {
    float r = p.x;
    r = (i == 1) ? p.y : r;
    r = (i == 2) ? p.z : r;
    r = (i == 3) ? p.w : r;
    return r;
}

// ---------- transpose: [6][16][H][H] f32 -> [6][H][H][16] bf16 ----------
__global__ void transpose_kernel(const float* __restrict__ in,
                                 __hip_bfloat16* __restrict__ out, int H) {
    int idx = blockIdx.x * blockDim.x + threadIdx.x;
    int hh = H * H;
    int total = 6 * hh;
    if (idx >= total) return;
    int c = idx / hh;
    int rem = idx - c * hh;
    const float* ip = in + (size_t)c * 16 * hh + rem;
    uint32_t words[8];
    #pragma unroll
    for (int j = 0; j < 8; ++j) {
        uint16_t lo = f2bf_rne(ip[(size_t)(2 * j) * hh]);
        uint16_t hi = f2bf_rne(ip[(size_t)(2 * j + 1) * hh]);
        words[j] = (uint32_t)lo | ((uint32_t)hi << 16);
    }
    uint4* op = (uint4*)((uint16_t*)out + (size_t)idx * 16);
    op[0] = make_uint4(words[0], words[1], words[2], words[3]);
    op[1] = make_uint4(words[4], words[5], words[6], words[7]);
}

// ---------- pack w1 [288][128] f32 -> bf16 MFMA B-frag layout ----------
__global__ void w1_pack_kernel(const float* __restrict__ w1, uint16_t* __restrict__ w1f) {
    int t = blockIdx.x * 64 + threadIdx.x;   // 4608 threads
    if (t >= 8 * 9 * 64) return;
    int lane = t & 63;
    int fr = t >> 6;
    int ct = fr / 9;
    int kc = fr - ct * 9;
    int col = ct * 16 + (lane & 15);
    int krow = kc * 32 + (lane >> 4) * 8;
    uint32_t od[4];
    #pragma unroll
    for (int j = 0; j < 4; ++j) {
        uint16_t lo = f2bf_rne(w1[(size_t)(krow + 2 * j) * 128 + col]);
        uint16_t hi = f2bf_rne(w1[(size_t)(krow + 2 * j + 1) * 128 + col]);
        od[j] = (uint32_t)lo | ((uint32_t)hi << 16);
    }
    *(uint4*)(w1f + (size_t)t * 8) = make_uint4(od[0], od[1], od[2], od[3]);
}

// ---------- gather: one thread per (ray, comb); all 3 levels batched ----------
__global__ __launch_bounds__(256, 3) void gather_kernel(
    const float4* __restrict__ ray, const uint16_t* __restrict__ gt,
    uint32_t* __restrict__ feats) {
    int t = blockIdx.x * 256 + threadIdx.x;       // < 262144*6
    int r = t / 6;
    int comb = t - r * 6;

    float4 p = ray[r];
    int c0 = (0x211000 >> (4 * comb)) & 0xF;      // 0,0,0,1,1,2
    int c1 = (0x332321 >> (4 * comb)) & 0xF;      // 1,2,3,2,3,3
    float x = sel4(p, c0);
    float y = sel4(p, c1);

    const uint4* q[6];
    float w00[3], w01[3], w10[3], w11[3];
    #pragma unroll
    for (int l = 0; l < 3; ++l) {
        int H = 128 << l;
        float u = x * (float)(H - 1);
        float v = y * (float)(H - 1);
        float u0f = fminf(fmaxf(floorf(u), 0.0f), (float)(H - 2));
        float v0f = fminf(fmaxf(floorf(v), 0.0f), (float)(H - 2));
        float wu = u - u0f, wv = v - v0f;
        int u0 = (int)u0f, v0 = (int)v0f;
        uint32_t lvl_off = (l == 0) ? T0_OFF : ((l == 1) ? T1_OFF : T2_OFF);
        const uint16_t* gp = gt + lvl_off + (((size_t)comb * H + u0) * H + v0) * 16;
        q[2 * l] = (const uint4*)gp;
        q[2 * l + 1] = (const uint4*)(gp + (size_t)16 * H);
        w00[l] = (1.0f - wu) * (1.0f - wv);
        w01[l] = (1.0f - wu) * wv;
        w10[l] = wu * (1.0f - wv);
        w11[l] = wu * wv;
    }

    // issue all 24 loads (16B each) before any use
    uint4 d[24];
    #pragma unroll
    for (int l = 0; l < 3; ++l) {
        d[8 * l + 0] = q[2 * l][0];      // (u0, v0)   lo half
        d[8 * l + 1] = q[2 * l][1];      // (u0, v0)   hi half
        d[8 * l + 2] = q[2 * l][2];      // (u0, v0+1) lo
        d[8 * l + 3] = q[2 * l][3];      // (u0, v0+1) hi
        d[8 * l + 4] = q[2 * l + 1][0];  // (u0+1, v0) lo
        d[8 * l + 5] = q[2 * l + 1][1];
        d[8 * l + 6] = q[2 * l + 1][2];  // (u0+1, v0+1) lo
        d[8 * l + 7] = q[2 * l + 1][3];
    }

    #pragma unroll
    for (int l = 0; l < 3; ++l) {
        float a = w00[l], b = w01[l], c = w10[l], e = w11[l];
        uint32_t od[8];
        #pragma unroll
        for (int j = 0; j < 8; ++j) {
            int half = j >> 2;          // which uint4 of the texel
            int wi = j & 3;             // dword within uint4
            uint32_t v00 = ((const uint32_t*)&d[8 * l + 0])[j];
            uint32_t v01 = ((const uint32_t*)&d[8 * l + 2])[j];
            uint32_t v10 = ((const uint32_t*)&d[8 * l + 4])[j];
            uint32_t v11 = ((const uint32_t*)&d[8 * l + 6])[j];
            (void)half; (void)wi;
            float lo = a * bf_lo(v00) + b * bf_lo(v01) + c * bf_lo(v10) + e * bf_lo(v11);
            float hi = a * bf_hi(v00) + b * bf_hi(v01) + c * bf_hi(v10) + e * bf_hi(v11);
            od[j] = (uint32_t)f2bf_rne(lo) | ((uint32_t)f2bf_rne(hi) << 16);
        }
        uint4* op = (uint4*)(feats + (size_t)r * 144 + (l * 6 + comb) * 8);
        op[0] = make_uint4(od[0], od[1], od[2], od[3]);
        op[1] = make_uint4(od[4], od[5], od[6], od[7]);
    }
}

// ---------- MFMA MLP: 32 rays/tile, 4 waves, wave owns 32 cols ----------
__global__ __launch_bounds__(256, 2) void mfma_mlp_kernel(
    const uint16_t* __restrict__ feats,   // [N_RAYS][288] bf16
    const uint16_t* __restrict__ w1f,     // packed B-frags
    const float* __restrict__ bias1,
    const float* __restrict__ w2, const float* __restrict__ bias2,
    float* __restrict__ out, int tiles_per_block) {
    __shared__ float s_h[32][132];

    int tid = threadIdx.x;
    int wv = tid >> 6;
    int lane = tid & 63;

    // loop-invariant: B fragments (72 VGPRs)
    short8v bfr[2][9];
    #pragma unroll
    for (int ctl = 0; ctl < 2; ++ctl) {
        int ct = wv * 2 + ctl;
        #pragma unroll
        for (int kc = 0; kc < 9; ++kc)
            bfr[ctl][kc] = *(const short8v*)(w1f + (((size_t)(ct * 9 + kc)) * 64 + lane) * 8);
    }
    float b1c0 = bias1[wv * 32 + (lane & 15)];
    float b1c1 = bias1[wv * 32 + 16 + (lane & 15)];

    int jg = tid & 7;
    int j0 = jg * 16;
    float w2r0[16], w2r1[16], w2r2[16];
    #pragma unroll
    for (int jj = 0; jj < 16; ++jj) {
        const float* w2p = w2 + (size_t)(j0 + jj) * 3;
        w2r0[jj] = w2p[0]; w2r1[jj] = w2p[1]; w2r2[jj] = w2p[2];
    }
    float bb0 = bias2[0], bb1 = bias2[1], bb2 = bias2[2];

    for (int it = 0; it < tiles_per_block; ++it) {
        int tile = blockIdx.x * tiles_per_block + it;
        int r0 = tile * 32;

        // batch all 18 A-frag loads (one latency per tile, not per kc)
        short8v af[18];
        const uint16_t* abase = feats + ((size_t)(r0 + (lane & 15)) * 288 + (lane >> 4) * 8);
        #pragma unroll
        for (int kc = 0; kc < 9; ++kc) {
            af[kc]     = *(const short8v*)(abase + kc * 32);
            af[9 + kc] = *(const short8v*)(abase + (size_t)16 * 288 + kc * 32);
        }

        float4v acc00, acc01, acc10, acc11;
        #pragma unroll
        for (int j = 0; j < 4; ++j) { acc00[j] = b1c0; acc01[j] = b1c1; acc10[j] = b1c0; acc11[j] = b1c1; }

        #pragma unroll
        for (int kc = 0; kc < 9; ++kc) {
            acc00 = __builtin_amdgcn_mfma_f32_16x16x32_bf16(af[kc],     bfr[0][kc], acc00, 0, 0, 0);
            acc01 = __builtin_amdgcn_mfma_f32_16x16x32_bf16(af[kc],     bfr[1][kc], acc01, 0, 0, 0);
            acc10 = __builtin_amdgcn_mfma_f32_16x16x32_bf16(af[9 + kc], bfr[0][kc], acc10, 0, 0, 0);
            acc11 = __builtin_amdgcn_mfma_f32_16x16x32_bf16(af[9 + kc], bfr[1][kc], acc11, 0, 0, 0);
        }

        __syncthreads();   // prior iteration's layer-2 reads must finish
        {
            int c0 = wv * 32 + (lane & 15);
            int rb = (lane >> 4) * 4;
            #pragma unroll
            for (int j = 0; j < 4; ++j) {
                s_h[rb + j][c0]           = fmaxf(acc00[j], 0.0f);
                s_h[rb + j][c0 + 16]      = fmaxf(acc01[j], 0.0f);
                s_h[rb + j + 16][c0]      = fmaxf(acc10[j], 0.0f);
                s_h[rb + j + 16][c0 + 16] = fmaxf(acc11[j], 0.0f);
            }
        }
        __syncthreads();

        int ray = tid >> 3;
        float p0 = 0.f, p1 = 0.f, p2 = 0.f;
        #pragma unroll
        for (int qq = 0; qq < 4; ++qq) {
            float4 hv = *(const float4*)&s_h[ray][j0 + qq * 4];
            float h0 = hv.x, h1 = hv.y, h2 = hv.z, h3 = hv.w;
            p0 += h0 * w2r0[qq * 4] + h1 * w2r0[qq * 4 + 1] + h2 * w2r0[qq * 4 + 2] + h3 * w2r0[qq * 4 + 3];
            p1 += h0 * w2r1[qq * 4] + h1 * w2r1[qq * 4 + 1] + h2 * w2r1[qq * 4 + 2] + h3 * w2r1[qq * 4 + 3];
            p2 += h0 * w2r2[qq * 4] + h1 * w2r2[qq * 4 + 1] + h2 * w2r2[qq * 4 + 2] + h3 * w2r2[qq * 4 + 3];
        }
        p0 += __shfl_xor(p0, 1); p0 += __shfl_xor(p0, 2); p0 += __shfl_xor(p0, 4);
        p1 += __shfl_xor(p1, 1); p1 += __shfl_xor(p1, 2); p1 += __shfl_xor(p1, 4);
        p2 += __shfl_xor(p2, 1); p2 += __shfl_xor(p2, 2); p2 += __shfl_xor(p2, 4);

        if (jg == 0) {
            float o0 = 1.0f / (1.0f + expf(-(p0 + bb0)));
            float o1 = 1.0f / (1.0f + expf(-(p1 + bb1)));
            float o2 = 1.0f / (1.0f + expf(-(p2 + bb2)));
            float* op = out + (size_t)(r0 + ray) * 3;
            op[0] = o0; op[1] = o1; op[2] = o2;
        }
    }
}

// ---------- fallback fused kernel (small ws) ----------
template <bool USE_T>
__global__ __launch_bounds__(THREADS) void fused_kernel(
    const float4* __restrict__ ray,
    const float* __restrict__ g0, const float* __restrict__ g1,
    const float* __restrict__ g2,
    const __hip_bfloat16* __restrict__ gt,
    const float* __restrict__ weights1, const float* __restrict__ bias1,
    const float* __restrict__ weights2, const float* __restrict__ bias2,
    float* __restrict__ out) {
    __shared__ float4 s_ray[NR];
    __shared__ float s_feats[NR][FSTRIDE];

    int tid = threadIdx.x;
    int rbase = blockIdx.x * NR;
    if (tid < NR) s_ray[tid] = ray[rbase + tid];
    __syncthreads();

    for (int t = tid; t < NR * 36; t += THREADS) {
        int r = t / 36;
        int rem = t - r * 36;
        int interp = rem >> 1;
        int half = rem & 1;
        int level = (interp >= 12) ? 2 : ((interp >= 6) ? 1 : 0);
        int comb = interp - level * 6;
        int H = 128 << level;
        float4 p = s_ray[r];
        int c0 = (0x211000 >> (4 * comb)) & 0xF;
        int c1 = (0x332321 >> (4 * comb)) & 0xF;
        float u = sel4(p, c0) * (float)(H - 1);
        float v = sel4(p, c1) * (float)(H - 1);
        float u0f = fminf(fmaxf(floorf(u), 0.0f), (float)(H - 2));
        float v0f = fminf(fmaxf(floorf(v), 0.0f), (float)(H - 2));
        float wu = u - u0f, wv = v - v0f;
        int u0 = (int)u0f, v0 = (int)v0f;
        float w00 = (1.0f - wu) * (1.0f - wv);
        float w01 = (1.0f - wu) * wv;
        float w10 = wu * (1.0f - wv);
        float w11 = wu * wv;
        float f[8];
        if (USE_T) {
            uint32_t lvl_off = (level == 0) ? T0_OFF : ((level == 1) ? T1_OFF : T2_OFF);
            const uint16_t* gp = (const uint16_t*)gt + lvl_off +
                                 (((size_t)comb * H + u0) * H + v0) * 16 + half * 8;
            uint4 a00 = *(const uint4*)gp;
            uint4 a01 = *(const uint4*)(gp + 16);
            uint4 a10 = *(const uint4*)(gp + (size_t)16 * H);
            uint4 a11 = *(const uint4*)(gp + (size_t)16 * H + 16);
            #pragma unroll
            for (int i = 0; i < 8; ++i) {
                f[i] = w00 * bf_extract(a00, i) + w01 * bf_extract(a01, i) +
                       w10 * bf_extract(a10, i) + w11 * bf_extract(a11, i);
            }
        } else {
            const float* gp = (level == 0) ? g0 : ((level == 1) ? g1 : g2);
            const float* base = gp + ((size_t)(comb * 16 + half * 8) * H + u0) * H + v0;
            #pragma unroll
            for (int i = 0; i < 8; ++i) {
                const float* q = base + (size_t)i * H * H;
                float a00 = q[0], a01 = q[1], a10 = q[H], a11 = q[H + 1];
                f[i] = w00 * a00 + w01 * a01 + w10 * a10 + w11 * a11;
            }
        }
        int fo = interp * 16 + half * 8;
        float* fp = &s_feats[r][fo];
        #pragma unroll
        for (int i = 0; i < 8; ++i) fp[i] = f[i];
    }
    __syncthreads();

    int r = tid >> 3;
    int jg = tid & 7;
    int j0 = jg * 16;
    float acc[16];
    #pragma unroll
    for (int jj = 0; jj < 16; ++jj) acc[jj] = bias1[j0 + jj];

    const float* wp = weights1 + j0;
    for (int k = 0; k < 288; k += 4) {
        float4 fv = *(const float4*)&s_feats[r][k];
        #pragma unroll
        for (int kk = 0; kk < 4; ++kk) {
            const float4* wr = (const float4*)(wp + (size_t)(k + kk) * 128);
            float fk = (kk == 0) ? fv.x : ((kk == 1) ? fv.y : ((kk == 2) ? fv.z : fv.w));
            float4 wa = wr[0], wb = wr[1], wc = wr[2], wd = wr[3];
            acc[0]  += fk * wa.x; acc[1]  += fk * wa.y; acc[2]  += fk * wa.z; acc[3]  += fk * wa.w;
            acc[4]  += fk * wb.x; acc[5]  += fk * wb.y; acc[6]  += fk * wb.z; acc[7]  += fk * wb.w;
            acc[8]  += fk * wc.x; acc[9]  += fk * wc.y; acc[10] += fk * wc.z; acc[11] += fk * wc.w;
            acc[12] += fk * wd.x; acc[13] += fk * wd.y; acc[14] += fk * wd.z; acc[15] += fk * wd.w;
        }
    }

    float p0 = 0.f, p1 = 0.f, p2 = 0.f;
    #pragma unroll
    for (int jj = 0; jj < 16; ++jj) {
        float h = fmaxf(acc[jj], 0.0f);
        const float* w2r = weights2 + (size_t)(j0 + jj) * 3;
        p0 += h * w2r[0];
        p1 += h * w2r[1];
        p2 += h * w2r[2];
    }
    p0 += __shfl_xor(p0, 1); p0 += __shfl_xor(p0, 2); p0 += __shfl_xor(p0, 4);
    p1 += __shfl_xor(p1, 1); p1 += __shfl_xor(p1, 2); p1 += __shfl_xor(p1, 4);
    p2 += __shfl_xor(p2, 1); p2 += __shfl_xor(p2, 2); p2 += __shfl_xor(p2, 4);

    if (jg == 0) {
        float o0 = 1.0f / (1.0f + expf(-(p0 + bias2[0])));
        float o1 = 1.0f / (1.0f + expf(-(p1 + bias2[1])));
        float o2 = 1.0f / (1.0f + expf(-(p2 + bias2[2])));
        float* op = out + (size_t)(rbase + r) * 3;
        op[0] = o0; op[1] = o1; op[2] = o2;
    }
}

extern "C" void kernel_launch(void* const* d_in, const int* in_sizes, int n_in,
                              void* d_out, int out_size, void* d_ws, size_t ws_size,
                              hipStream_t stream) {
    const float4* ray = (const float4*)d_in[0];
    const float* g0 = (const float*)d_in[1];
    const float* g1 = (const float*)d_in[2];
    const float* g2 = (const float*)d_in[3];
    const float* w1 = (const float*)d_in[4];
    const float* b1 = (const float*)d_in[5];
    const float* w2 = (const float*)d_in[6];
    const float* b2 = (const float*)d_in[7];
    float* out = (float*)d_out;

    const size_t T_BYTES = (size_t)T_ELEMS * 2;
    const size_t NEED = (size_t)W1F_BYTE_OFF + W1F_BYTES;

    if (ws_size >= NEED) {
        __hip_bfloat16* wsb = (__hip_bfloat16*)d_ws;
        transpose_kernel<<<(6 * 128 * 128 + 255) / 256, 256, 0, stream>>>(g0, wsb + T0_OFF, 128);
        transpose_kernel<<<(6 * 256 * 256 + 255) / 256, 256, 0, stream>>>(g1, wsb + T1_OFF, 256);
        transpose_kernel<<<(6 * 512 * 512 + 255) / 256, 256, 0, stream>>>(g2, wsb + T2_OFF, 512);
        uint32_t* feats = (uint32_t*)((char*)d_ws + FEAT_BYTE_OFF);
        uint16_t* w1f = (uint16_t*)((char*)d_ws + W1F_BYTE_OFF);
        w1_pack_kernel<<<72, 64, 0, stream>>>(w1, w1f);
        gather_kernel<<<N_RAYS * 6 / 256, 256, 0, stream>>>(
            ray, (const uint16_t*)wsb, feats);
        const int TILES_PER_BLOCK = 4;
        int nblk = N_RAYS / 32 / TILES_PER_BLOCK;   // 2048
        mfma_mlp_kernel<<<nblk, 256, 0, stream>>>(
            (const uint16_t*)feats, w1f, b1, w2, b2, out, TILES_PER_BLOCK);
    } else if (ws_size >= T_BYTES) {
        __hip_bfloat16* wsb = (__hip_bfloat16*)d_ws;
        transpose_kernel<<<(6 * 128 * 128 + 255) / 256, 256, 0, stream>>>(g0, wsb + T0_OFF, 128);
        transpose_kernel<<<(6 * 256 * 256 + 255) / 256, 256, 0, stream>>>(g1, wsb + T1_OFF, 256);
        transpose_kernel<<<(6 * 512 * 512 + 255) / 256, 256, 0, stream>>>(g2, wsb + T2_OFF, 512);
        fused_kernel<true><<<N_RAYS / NR, THREADS, 0, stream>>>(
            ray, g0, g1, g2, wsb, w1, b1, w2, b2, out);
    } else {
        fused_kernel<false><<<N_RAYS / NR, THREADS, 0, stream>>>(
            ray, g0, g1, g2, nullptr, w1, b1, w2, b2, out);
    }
}

// Round 5
// 348.832 us; speedup vs baseline: 1.1487x; 1.1487x over previous
//
#include <hip/hip_runtime.h>
#include <hip/hip_bf16.h>
#include <cstdint>
#include <cstddef>

#define N_RAYS 262144
#define NR 32
#define THREADS 256
#define FSTRIDE 292

// offsets in uint16 elements into the transposed-grid arena
#define T0_OFF 0u
#define T1_OFF 1572864u      // 6*128*128*16
#define T2_OFF 7864320u      // + 6*256*256*16
#define T_ELEMS 33030144u    // 6*16*(128^2+256^2+512^2)
#define FEAT_BYTE_OFF 66060288u   // T_ELEMS*2
#define FEAT_DWORDS 37748736u     // 262144*144
#define W1F_BYTE_OFF 217055232u   // FEAT_BYTE_OFF + FEAT_DWORDS*4
#define W1F_BYTES 73728u          // 288*128*2
// sort scratch (bytes)
#define KEYS_OFF   217128960u     // u16[262144]  (512 KB)
#define PERM_OFF   217653248u     // u32[262144]  (1 MB)
#define HIST_OFF   218701824u     // u32[65536]   (256 KB)
#define OFFS_OFF   218963968u     // u32[65536]   (256 KB)
#define RSORT_OFF  219226112u     // float4[262144] (4 MB)
#define NEED_SORT  223420416u

typedef __attribute__((ext_vector_type(8))) short short8v;   // 8 bf16 = 4 VGPRs
typedef __attribute__((ext_vector_type(4))) float float4v;   // MFMA C/D

// ---------- helpers ----------
__device__ __forceinline__ float bf_lo(uint32_t w) { return __uint_as_float(w << 16); }
__device__ __forceinline__ float bf_hi(uint32_t w) { return __uint_as_float(w & 0xFFFF0000u); }

__device__ __forceinline__ float bf_extract(const uint4& q, int i) {
    uint32_t w = ((const uint32_t*)&q)[i >> 1];
    uint32_t h = (i & 1) ? (w & 0xFFFF0000u) : (w << 16);
    return __uint_as_float(h);
}

__device__ __forceinline__ uint16_t f2bf_rne(float f) {
    uint32_t x = __float_as_uint(f);
    uint32_t r = x + 0x7FFFu + ((x >> 16) & 1u);
    return (uint16_t)(r >> 16);
}

__device__ __forceinline__ float sel4(const float4& p, int i) {
    float r = p.x;
    r = (i == 1) ? p.y : r;
    r = (i == 2) ? p.z : r;
    r = (i == 3) ? p.w : r;
    return r;
}

__device__ __forceinline__ uint32_t morton4(const float4& p) {
    int q0 = min(15, max(0, (int)(p.x * 16.0f)));
    int q1 = min(15, max(0, (int)(p.y * 16.0f)));
    int q2 = min(15, max(0, (int)(p.z * 16.0f)));
    int q3 = min(15, max(0, (int)(p.w * 16.0f)));
    uint32_t key = 0;
    #pragma unroll
    for (int b = 0; b < 4; ++b) {
        key |= (uint32_t)((q0 >> b) & 1) << (4 * b + 0);
        key |= (uint32_t)((q1 >> b) & 1) << (4 * b + 1);
        key |= (uint32_t)((q2 >> b) & 1) << (4 * b + 2);
        key |= (uint32_t)((q3 >> b) & 1) << (4 * b + 3);
    }
    return key;
}

// ---------- transpose: [6][16][H][H] f32 -> [6][H][H][16] bf16 ----------
__global__ void transpose_kernel(const float* __restrict__ in,
                                 __hip_bfloat16* __restrict__ out, int H) {
    int idx = blockIdx.x * blockDim.x + threadIdx.x;
    int hh = H * H;
    int total = 6 * hh;
    if (idx >= total) return;
    int c = idx / hh;
    int rem = idx - c * hh;
    const float* ip = in + (size_t)c * 16 * hh + rem;
    uint32_t words[8];
    #pragma unroll
    for (int j = 0; j < 8; ++j) {
        uint16_t lo = f2bf_rne(ip[(size_t)(2 * j) * hh]);
        uint16_t hi = f2bf_rne(ip[(size_t)(2 * j + 1) * hh]);
        words[j] = (uint32_t)lo | ((uint32_t)hi << 16);
    }
    uint4* op = (uint4*)((uint16_t*)out + (size_t)idx * 16);
    op[0] = make_uint4(words[0], words[1], words[2], words[3]);
    op[1] = make_uint4(words[4], words[5], words[6], words[7]);
}

// ---------- pack w1 [288][128] f32 -> bf16 MFMA B-frag layout ----------
__global__ void w1_pack_kernel(const float* __restrict__ w1, uint16_t* __restrict__ w1f) {
    int t = blockIdx.x * 64 + threadIdx.x;   // 4608 threads
    if (t >= 8 * 9 * 64) return;
    int lane = t & 63;
    int fr = t >> 6;
    int ct = fr / 9;
    int kc = fr - ct * 9;
    int col = ct * 16 + (lane & 15);
    int krow = kc * 32 + (lane >> 4) * 8;
    uint32_t od[4];
    #pragma unroll
    for (int j = 0; j < 4; ++j) {
        uint16_t lo = f2bf_rne(w1[(size_t)(krow + 2 * j) * 128 + col]);
        uint16_t hi = f2bf_rne(w1[(size_t)(krow + 2 * j + 1) * 128 + col]);
        od[j] = (uint32_t)lo | ((uint32_t)hi << 16);
    }
    *(uint4*)(w1f + (size_t)t * 8) = make_uint4(od[0], od[1], od[2], od[3]);
}

// ---------- sort kernels ----------
__global__ void key_hist_kernel(const float4* __restrict__ ray,
                                uint16_t* __restrict__ keys,
                                uint32_t* __restrict__ hist) {
    int r = blockIdx.x * 256 + threadIdx.x;
    float4 p = ray[r];
    uint32_t key = morton4(p);
    keys[r] = (uint16_t)key;
    atomicAdd(&hist[key], 1u);
}

__global__ void scan_kernel(const uint32_t* __restrict__ hist,
                            uint32_t* __restrict__ offs) {
    __shared__ uint32_t s_part[256];
    int tid = threadIdx.x;
    uint32_t sum = 0;
    #pragma unroll 4
    for (int i = 0; i < 256; ++i) sum += hist[tid * 256 + i];
    s_part[tid] = sum;
    __syncthreads();
    if (tid == 0) {
        uint32_t acc = 0;
        for (int i = 0; i < 256; ++i) { uint32_t v = s_part[i]; s_part[i] = acc; acc += v; }
    }
    __syncthreads();
    uint32_t acc = s_part[tid];
    for (int i = 0; i < 256; ++i) {
        uint32_t v = hist[tid * 256 + i];
        offs[tid * 256 + i] = acc;
        acc += v;
    }
}

__global__ void scatter_kernel(const float4* __restrict__ ray,
                               const uint16_t* __restrict__ keys,
                               uint32_t* __restrict__ offs,
                               uint32_t* __restrict__ perm,
                               float4* __restrict__ ray_sorted) {
    int r = blockIdx.x * 256 + threadIdx.x;
    uint32_t key = keys[r];
    uint32_t pos = atomicAdd(&offs[key], 1u);
    perm[pos] = (uint32_t)r;
    ray_sorted[pos] = ray[r];
}

// ---------- gather: one thread per (ray, interp); writes bf16 feats ----------
__global__ __launch_bounds__(256, 8) void gather_kernel(
    const float4* __restrict__ ray, const uint16_t* __restrict__ gt,
    uint32_t* __restrict__ feats) {
    // XCD-chunked bijective swizzle: 18432 blocks = 8 * 2304
    int bid = blockIdx.x;
    bid = (bid & 7) * 2304 + (bid >> 3);
    int t = bid * 256 + threadIdx.x;              // < 262144*18
    int r = t / 18;
    int interp = t - r * 18;
    int level = interp / 6;
    int comb = interp - level * 6;
    int H = 128 << level;

    float4 p = ray[r];
    int c0 = (0x211000 >> (4 * comb)) & 0xF;      // 0,0,0,1,1,2
    int c1 = (0x332321 >> (4 * comb)) & 0xF;      // 1,2,3,2,3,3
    float u = sel4(p, c0) * (float)(H - 1);
    float v = sel4(p, c1) * (float)(H - 1);
    float u0f = fminf(fmaxf(floorf(u), 0.0f), (float)(H - 2));
    float v0f = fminf(fmaxf(floorf(v), 0.0f), (float)(H - 2));
    float wu = u - u0f, wv = v - v0f;
    int u0 = (int)u0f, v0 = (int)v0f;

    uint32_t lvl_off = (level == 0) ? T0_OFF : ((level == 1) ? T1_OFF : T2_OFF);
    const uint16_t* gp0 = gt + lvl_off + (((size_t)comb * H + u0) * H + v0) * 16;
    const uint4* q0 = (const uint4*)gp0;                       // row u0: (v0, v0+1)
    const uint4* q1 = (const uint4*)(gp0 + (size_t)16 * H);    // row u0+1
    uint4 a0 = q0[0], a1 = q0[1], a2 = q0[2], a3 = q0[3];
    uint4 b0 = q1[0], b1 = q1[1], b2 = q1[2], b3 = q1[3];

    uint32_t c00[8], c01[8], c10[8], c11[8];
    #pragma unroll
    for (int j = 0; j < 4; ++j) {
        c00[j] = ((const uint32_t*)&a0)[j];  c00[j + 4] = ((const uint32_t*)&a1)[j];
        c01[j] = ((const uint32_t*)&a2)[j];  c01[j + 4] = ((const uint32_t*)&a3)[j];
        c10[j] = ((const uint32_t*)&b0)[j];  c10[j + 4] = ((const uint32_t*)&b1)[j];
        c11[j] = ((const uint32_t*)&b2)[j];  c11[j + 4] = ((const uint32_t*)&b3)[j];
    }

    float w00 = (1.0f - wu) * (1.0f - wv);
    float w01 = (1.0f - wu) * wv;
    float w10 = wu * (1.0f - wv);
    float w11 = wu * wv;

    uint32_t od[8];
    #pragma unroll
    for (int j = 0; j < 8; ++j) {
        float lo = w00 * bf_lo(c00[j]) + w01 * bf_lo(c01[j]) +
                   w10 * bf_lo(c10[j]) + w11 * bf_lo(c11[j]);
        float hi = w00 * bf_hi(c00[j]) + w01 * bf_hi(c01[j]) +
                   w10 * bf_hi(c10[j]) + w11 * bf_hi(c11[j]);
        od[j] = (uint32_t)f2bf_rne(lo) | ((uint32_t)f2bf_rne(hi) << 16);
    }

    uint4* op = (uint4*)(feats + (size_t)r * 144 + interp * 8);
    op[0] = make_uint4(od[0], od[1], od[2], od[3]);
    op[1] = make_uint4(od[4], od[5], od[6], od[7]);
}

// ---------- MFMA MLP: 32 rays/tile, 4 waves, wave owns 32 cols ----------
__global__ __launch_bounds__(256, 2) void mfma_mlp_kernel(
    const uint16_t* __restrict__ feats,   // [N_RAYS][288] bf16 (sorted order)
    const uint16_t* __restrict__ w1f,     // packed B-frags
    const float* __restrict__ bias1,
    const float* __restrict__ w2, const float* __restrict__ bias2,
    const uint32_t* __restrict__ perm,    // nullable: out scatter indices
    float* __restrict__ out, int tiles_per_block) {
    __shared__ float s_h[32][132];

    int tid = threadIdx.x;
    int wv = tid >> 6;
    int lane = tid & 63;

    short8v bfr[2][9];
    #pragma unroll
    for (int ctl = 0; ctl < 2; ++ctl) {
        int ct = wv * 2 + ctl;
        #pragma unroll
        for (int kc = 0; kc < 9; ++kc)
            bfr[ctl][kc] = *(const short8v*)(w1f + (((size_t)(ct * 9 + kc)) * 64 + lane) * 8);
    }
    float b1c0 = bias1[wv * 32 + (lane & 15)];
    float b1c1 = bias1[wv * 32 + 16 + (lane & 15)];

    int jg = tid & 7;
    int j0 = jg * 16;
    float w2r0[16], w2r1[16], w2r2[16];
    #pragma unroll
    for (int jj = 0; jj < 16; ++jj) {
        const float* w2p = w2 + (size_t)(j0 + jj) * 3;
        w2r0[jj] = w2p[0]; w2r1[jj] = w2p[1]; w2r2[jj] = w2p[2];
    }
    float bb0 = bias2[0], bb1 = bias2[1], bb2 = bias2[2];

    for (int it = 0; it < tiles_per_block; ++it) {
        int tile = blockIdx.x * tiles_per_block + it;
        int r0 = tile * 32;

        short8v af[18];
        const uint16_t* abase = feats + ((size_t)(r0 + (lane & 15)) * 288 + (lane >> 4) * 8);
        #pragma unroll
        for (int kc = 0; kc < 9; ++kc) {
            af[kc]     = *(const short8v*)(abase + kc * 32);
            af[9 + kc] = *(const short8v*)(abase + (size_t)16 * 288 + kc * 32);
        }

        float4v acc00, acc01, acc10, acc11;
        #pragma unroll
        for (int j = 0; j < 4; ++j) { acc00[j] = b1c0; acc01[j] = b1c1; acc10[j] = b1c0; acc11[j] = b1c1; }

        #pragma unroll
        for (int kc = 0; kc < 9; ++kc) {
            acc00 = __builtin_amdgcn_mfma_f32_16x16x32_bf16(af[kc],     bfr[0][kc], acc00, 0, 0, 0);
            acc01 = __builtin_amdgcn_mfma_f32_16x16x32_bf16(af[kc],     bfr[1][kc], acc01, 0, 0, 0);
            acc10 = __builtin_amdgcn_mfma_f32_16x16x32_bf16(af[9 + kc], bfr[0][kc], acc10, 0, 0, 0);
            acc11 = __builtin_amdgcn_mfma_f32_16x16x32_bf16(af[9 + kc], bfr[1][kc], acc11, 0, 0, 0);
        }

        __syncthreads();
        {
            int c0 = wv * 32 + (lane & 15);
            int rb = (lane >> 4) * 4;
            #pragma unroll
            for (int j = 0; j < 4; ++j) {
                s_h[rb + j][c0]           = fmaxf(acc00[j], 0.0f);
                s_h[rb + j][c0 + 16]      = fmaxf(acc01[j], 0.0f);
                s_h[rb + j + 16][c0]      = fmaxf(acc10[j], 0.0f);
                s_h[rb + j + 16][c0 + 16] = fmaxf(acc11[j], 0.0f);
            }
        }
        __syncthreads();

        int ray = tid >> 3;
        float p0 = 0.f, p1 = 0.f, p2 = 0.f;
        #pragma unroll
        for (int qq = 0; qq < 4; ++qq) {
            float4 hv = *(const float4*)&s_h[ray][j0 + qq * 4];
            float h0 = hv.x, h1 = hv.y, h2 = hv.z, h3 = hv.w;
            p0 += h0 * w2r0[qq * 4] + h1 * w2r0[qq * 4 + 1] + h2 * w2r0[qq * 4 + 2] + h3 * w2r0[qq * 4 + 3];
            p1 += h0 * w2r1[qq * 4] + h1 * w2r1[qq * 4 + 1] + h2 * w2r1[qq * 4 + 2] + h3 * w2r1[qq * 4 + 3];
            p2 += h0 * w2r2[qq * 4] + h1 * w2r2[qq * 4 + 1] + h2 * w2r2[qq * 4 + 2] + h3 * w2r2[qq * 4 + 3];
        }
        p0 += __shfl_xor(p0, 1); p0 += __shfl_xor(p0, 2); p0 += __shfl_xor(p0, 4);
        p1 += __shfl_xor(p1, 1); p1 += __shfl_xor(p1, 2); p1 += __shfl_xor(p1, 4);
        p2 += __shfl_xor(p2, 1); p2 += __shfl_xor(p2, 2); p2 += __shfl_xor(p2, 4);

        if (jg == 0) {
            int orig = perm ? (int)perm[r0 + ray] : (r0 + ray);
            float o0 = 1.0f / (1.0f + expf(-(p0 + bb0)));
            float o1 = 1.0f / (1.0f + expf(-(p1 + bb1)));
            float o2 = 1.0f / (1.0f + expf(-(p2 + bb2)));
            float* op = out + (size_t)orig * 3;
            op[0] = o0; op[1] = o1; op[2] = o2;
        }
    }
}

// ---------- fallback fused kernel (small ws) ----------
template <bool USE_T>
__global__ __launch_bounds__(THREADS) void fused_kernel(
    const float4* __restrict__ ray,
    const float* __restrict__ g0, const float* __restrict__ g1,
    const float* __restrict__ g2,
    const __hip_bfloat16* __restrict__ gt,
    const float* __restrict__ weights1, const float* __restrict__ bias1,
    const float* __restrict__ weights2, const float* __restrict__ bias2,
    float* __restrict__ out) {
    __shared__ float4 s_ray[NR];
    __shared__ float s_feats[NR][FSTRIDE];

    int tid = threadIdx.x;
    int rbase = blockIdx.x * NR;
    if (tid < NR) s_ray[tid] = ray[rbase + tid];
    __syncthreads();

    for (int t = tid; t < NR * 36; t += THREADS) {
        int r = t / 36;
        int rem = t - r * 36;
        int interp = rem >> 1;
        int half = rem & 1;
        int level = (interp >= 12) ? 2 : ((interp >= 6) ? 1 : 0);
        int comb = interp - level * 6;
        int H = 128 << level;
        float4 p = s_ray[r];
        int c0 = (0x211000 >> (4 * comb)) & 0xF;
        int c1 = (0x332321 >> (4 * comb)) & 0xF;
        float u = sel4(p, c0) * (float)(H - 1);
        float v = sel4(p, c1) * (float)(H - 1);
        float u0f = fminf(fmaxf(floorf(u), 0.0f), (float)(H - 2));
        float v0f = fminf(fmaxf(floorf(v), 0.0f), (float)(H - 2));
        float wu = u - u0f, wv = v - v0f;
        int u0 = (int)u0f, v0 = (int)v0f;
        float w00 = (1.0f - wu) * (1.0f - wv);
        float w01 = (1.0f - wu) * wv;
        float w10 = wu * (1.0f - wv);
        float w11 = wu * wv;
        float f[8];
        if (USE_T) {
            uint32_t lvl_off = (level == 0) ? T0_OFF : ((level == 1) ? T1_OFF : T2_OFF);
            const uint16_t* gp = (const uint16_t*)gt + lvl_off +
                                 (((size_t)comb * H + u0) * H + v0) * 16 + half * 8;
            uint4 a00 = *(const uint4*)gp;
            uint4 a01 = *(const uint4*)(gp + 16);
            uint4 a10 = *(const uint4*)(gp + (size_t)16 * H);
            uint4 a11 = *(const uint4*)(gp + (size_t)16 * H + 16);
            #pragma unroll
            for (int i = 0; i < 8; ++i) {
                f[i] = w00 * bf_extract(a00, i) + w01 * bf_extract(a01, i) +
                       w10 * bf_extract(a10, i) + w11 * bf_extract(a11, i);
            }
        } else {
            const float* gp = (level == 0) ? g0 : ((level == 1) ? g1 : g2);
            const float* base = gp + ((size_t)(comb * 16 + half * 8) * H + u0) * H + v0;
            #pragma unroll
            for (int i = 0; i < 8; ++i) {
                const float* q = base + (size_t)i * H * H;
                float a00 = q[0], a01 = q[1], a10 = q[H], a11 = q[H + 1];
                f[i] = w00 * a00 + w01 * a01 + w10 * a10 + w11 * a11;
            }
        }
        int fo = interp * 16 + half * 8;
        float* fp = &s_feats[r][fo];
        #pragma unroll
        for (int i = 0; i < 8; ++i) fp[i] = f[i];
    }
    __syncthreads();

    int r = tid >> 3;
    int jg = tid & 7;
    int j0 = jg * 16;
    float acc[16];
    #pragma unroll
    for (int jj = 0; jj < 16; ++jj) acc[jj] = bias1[j0 + jj];

    const float* wp = weights1 + j0;
    for (int k = 0; k < 288; k += 4) {
        float4 fv = *(const float4*)&s_feats[r][k];
        #pragma unroll
        for (int kk = 0; kk < 4; ++kk) {
            const float4* wr = (const float4*)(wp + (size_t)(k + kk) * 128);
            float fk = (kk == 0) ? fv.x : ((kk == 1) ? fv.y : ((kk == 2) ? fv.z : fv.w));
            float4 wa = wr[0], wb = wr[1], wc = wr[2], wd = wr[3];
            acc[0]  += fk * wa.x; acc[1]  += fk * wa.y; acc[2]  += fk * wa.z; acc[3]  += fk * wa.w;
            acc[4]  += fk * wb.x; acc[5]  += fk * wb.y; acc[6]  += fk * wb.z; acc[7]  += fk * wb.w;
            acc[8]  += fk * wc.x; acc[9]  += fk * wc.y; acc[10] += fk * wc.z; acc[11] += fk * wc.w;
            acc[12] += fk * wd.x; acc[13] += fk * wd.y; acc[14] += fk * wd.z; acc[15] += fk * wd.w;
        }
    }

    float p0 = 0.f, p1 = 0.f, p2 = 0.f;
    #pragma unroll
    for (int jj = 0; jj < 16; ++jj) {
        float h = fmaxf(acc[jj], 0.0f);
        const float* w2r = weights2 + (size_t)(j0 + jj) * 3;
        p0 += h * w2r[0];
        p1 += h * w2r[1];
        p2 += h * w2r[2];
    }
    p0 += __shfl_xor(p0, 1); p0 += __shfl_xor(p0, 2); p0 += __shfl_xor(p0, 4);
    p1 += __shfl_xor(p1, 1); p1 += __shfl_xor(p1, 2); p1 += __shfl_xor(p1, 4);
    p2 += __shfl_xor(p2, 1); p2 += __shfl_xor(p2, 2); p2 += __shfl_xor(p2, 4);

    if (jg == 0) {
        float o0 = 1.0f / (1.0f + expf(-(p0 + bias2[0])));
        float o1 = 1.0f / (1.0f + expf(-(p1 + bias2[1])));
        float o2 = 1.0f / (1.0f + expf(-(p2 + bias2[2])));
        float* op = out + (size_t)(rbase + r) * 3;
        op[0] = o0; op[1] = o1; op[2] = o2;
    }
}

extern "C" void kernel_launch(void* const* d_in, const int* in_sizes, int n_in,
                              void* d_out, int out_size, void* d_ws, size_t ws_size,
                              hipStream_t stream) {
    const float4* ray = (const float4*)d_in[0];
    const float* g0 = (const float*)d_in[1];
    const float* g1 = (const float*)d_in[2];
    const float* g2 = (const float*)d_in[3];
    const float* w1 = (const float*)d_in[4];
    const float* b1 = (const float*)d_in[5];
    const float* w2 = (const float*)d_in[6];
    const float* b2 = (const float*)d_in[7];
    float* out = (float*)d_out;

    const size_t T_BYTES = (size_t)T_ELEMS * 2;
    const size_t NEED = (size_t)W1F_BYTE_OFF + W1F_BYTES;

    if (ws_size >= (size_t)NEED_SORT) {
        char* ws = (char*)d_ws;
        __hip_bfloat16* wsb = (__hip_bfloat16*)d_ws;
        uint32_t* feats = (uint32_t*)(ws + FEAT_BYTE_OFF);
        uint16_t* w1f  = (uint16_t*)(ws + W1F_BYTE_OFF);
        uint16_t* keys = (uint16_t*)(ws + KEYS_OFF);
        uint32_t* perm = (uint32_t*)(ws + PERM_OFF);
        uint32_t* hist = (uint32_t*)(ws + HIST_OFF);
        uint32_t* offs = (uint32_t*)(ws + OFFS_OFF);
        float4* rsort  = (float4*)(ws + RSORT_OFF);

        hipMemsetAsync(hist, 0, 65536 * 4, stream);
        transpose_kernel<<<(6 * 128 * 128 + 255) / 256, 256, 0, stream>>>(g0, wsb + T0_OFF, 128);
        transpose_kernel<<<(6 * 256 * 256 + 255) / 256, 256, 0, stream>>>(g1, wsb + T1_OFF, 256);
        transpose_kernel<<<(6 * 512 * 512 + 255) / 256, 256, 0, stream>>>(g2, wsb + T2_OFF, 512);
        w1_pack_kernel<<<72, 64, 0, stream>>>(w1, w1f);
        key_hist_kernel<<<N_RAYS / 256, 256, 0, stream>>>(ray, keys, hist);
        scan_kernel<<<1, 256, 0, stream>>>(hist, offs);
        scatter_kernel<<<N_RAYS / 256, 256, 0, stream>>>(ray, keys, offs, perm, rsort);
        gather_kernel<<<N_RAYS * 18 / 256, 256, 0, stream>>>(
            rsort, (const uint16_t*)wsb, feats);
        const int TILES_PER_BLOCK = 4;
        int nblk = N_RAYS / 32 / TILES_PER_BLOCK;   // 2048
        mfma_mlp_kernel<<<nblk, 256, 0, stream>>>(
            (const uint16_t*)feats, w1f, b1, w2, b2, perm, out, TILES_PER_BLOCK);
    } else if (ws_size >= NEED) {
        __hip_bfloat16* wsb = (__hip_bfloat16*)d_ws;
        transpose_kernel<<<(6 * 128 * 128 + 255) / 256, 256, 0, stream>>>(g0, wsb + T0_OFF, 128);
        transpose_kernel<<<(6 * 256 * 256 + 255) / 256, 256, 0, stream>>>(g1, wsb + T1_OFF, 256);
        transpose_kernel<<<(6 * 512 * 512 + 255) / 256, 256, 0, stream>>>(g2, wsb + T2_OFF, 512);
        uint32_t* feats = (uint32_t*)((char*)d_ws + FEAT_BYTE_OFF);
        uint16_t* w1f = (uint16_t*)((char*)d_ws + W1F_BYTE_OFF);
        w1_pack_kernel<<<72, 64, 0, stream>>>(w1, w1f);
        gather_kernel<<<N_RAYS * 18 / 256, 256, 0, stream>>>(
            ray, (const uint16_t*)wsb, feats);
        const int TILES_PER_BLOCK = 4;
        int nblk = N_RAYS / 32 / TILES_PER_BLOCK;
        mfma_mlp_kernel<<<nblk, 256, 0, stream>>>(
            (const uint16_t*)feats, w1f, b1, w2, b2, nullptr, out, TILES_PER_BLOCK);
    } else if (ws_size >= T_BYTES) {
        __hip_bfloat16* wsb = (__hip_bfloat16*)d_ws;
        transpose_kernel<<<(6 * 128 * 128 + 255) / 256, 256, 0, stream>>>(g0, wsb + T0_OFF, 128);
        transpose_kernel<<<(6 * 256 * 256 + 255) / 256, 256, 0, stream>>>(g1, wsb + T1_OFF, 256);
        transpose_kernel<<<(6 * 512 * 512 + 255) / 256, 256, 0, stream>>>(g2, wsb + T2_OFF, 512);
        fused_kernel<true><<<N_RAYS / NR, THREADS, 0, stream>>>(
            ray, g0, g1, g2, wsb, w1, b1, w2, b2, out);
    } else {
        fused_kernel<false><<<N_RAYS / NR, THREADS, 0, stream>>>(
            ray, g0, g1, g2, nullptr, w1, b1, w2, b2, out);
    }
}

// Round 6
// 301.838 us; speedup vs baseline: 1.3275x; 1.1557x over previous
//
#include <hip/hip_runtime.h>
#include <hip/hip_bf16.h>
#include <cstdint>
#include <cstddef>

#define N_RAYS 262144
#define NR 32
#define THREADS 256
#define FSTRIDE 292

// offsets in uint16 elements into the transposed-grid arena
#define T0_OFF 0u
#define T1_OFF 1572864u      // 6*128*128*16
#define T2_OFF 7864320u      // + 6*256*256*16
#define T_ELEMS 33030144u    // 6*16*(128^2+256^2+512^2)
#define FEAT_BYTE_OFF 66060288u   // T_ELEMS*2
#define FEAT_DWORDS 37748736u     // 262144*144
#define W1F_BYTE_OFF 217055232u   // FEAT_BYTE_OFF + FEAT_DWORDS*4
#define W1F_BYTES 73728u          // 288*128*2
// sort scratch (bytes)
#define KEYS_OFF   217128960u     // u16[262144]  (512 KB)
#define PERM_OFF   217653248u     // u32[262144]  (1 MB)
#define HIST_OFF   218701824u     // u32[65536]   (256 KB)
#define OFFS_OFF   218963968u     // u32[65536]   (256 KB)
#define RSORT_OFF  219226112u     // float4[262144] (4 MB)
#define NEED_SORT  223420416u

typedef __attribute__((ext_vector_type(8))) short short8v;   // 8 bf16 = 4 VGPRs
typedef __attribute__((ext_vector_type(4))) float float4v;   // MFMA C/D

// ---------- helpers ----------
__device__ __forceinline__ float bf_lo(uint32_t w) { return __uint_as_float(w << 16); }
__device__ __forceinline__ float bf_hi(uint32_t w) { return __uint_as_float(w & 0xFFFF0000u); }

__device__ __forceinline__ float bf_extract(const uint4& q, int i) {
    uint32_t w = ((const uint32_t*)&q)[i >> 1];
    uint32_t h = (i & 1) ? (w & 0xFFFF0000u) : (w << 16);
    return __uint_as_float(h);
}

__device__ __forceinline__ uint16_t f2bf_rne(float f) {
    uint32_t x = __float_as_uint(f);
    uint32_t r = x + 0x7FFFu + ((x >> 16) & 1u);
    return (uint16_t)(r >> 16);
}

__device__ __forceinline__ float sel4(const float4& p, int i) {
    float r = p.x;
    r = (i == 1) ? p.y : r;
    r = (i == 2) ? p.z : r;
    r = (i == 3) ? p.w : r;
    return r;
}

__device__ __forceinline__ uint32_t morton4(const float4& p) {
    int q0 = min(15, max(0, (int)(p.x * 16.0f)));
    int q1 = min(15, max(0, (int)(p.y * 16.0f)));
    int q2 = min(15, max(0, (int)(p.z * 16.0f)));
    int q3 = min(15, max(0, (int)(p.w * 16.0f)));
    uint32_t key = 0;
    #pragma unroll
    for (int b = 0; b < 4; ++b) {
        key |= (uint32_t)((q0 >> b) & 1) << (4 * b + 0);
        key |= (uint32_t)((q1 >> b) & 1) << (4 * b + 1);
        key |= (uint32_t)((q2 >> b) & 1) << (4 * b + 2);
        key |= (uint32_t)((q3 >> b) & 1) << (4 * b + 3);
    }
    return key;
}

// ---------- transpose: [6][16][H][H] f32 -> [6][H][H][16] bf16 ----------
__global__ void transpose_kernel(const float* __restrict__ in,
                                 __hip_bfloat16* __restrict__ out, int H) {
    int idx = blockIdx.x * blockDim.x + threadIdx.x;
    int hh = H * H;
    int total = 6 * hh;
    if (idx >= total) return;
    int c = idx / hh;
    int rem = idx - c * hh;
    const float* ip = in + (size_t)c * 16 * hh + rem;
    uint32_t words[8];
    #pragma unroll
    for (int j = 0; j < 8; ++j) {
        uint16_t lo = f2bf_rne(ip[(size_t)(2 * j) * hh]);
        uint16_t hi = f2bf_rne(ip[(size_t)(2 * j + 1) * hh]);
        words[j] = (uint32_t)lo | ((uint32_t)hi << 16);
    }
    uint4* op = (uint4*)((uint16_t*)out + (size_t)idx * 16);
    op[0] = make_uint4(words[0], words[1], words[2], words[3]);
    op[1] = make_uint4(words[4], words[5], words[6], words[7]);
}

// ---------- pack w1 [288][128] f32 -> bf16 MFMA B-frag layout ----------
__global__ void w1_pack_kernel(const float* __restrict__ w1, uint16_t* __restrict__ w1f) {
    int t = blockIdx.x * 64 + threadIdx.x;   // 4608 threads
    if (t >= 8 * 9 * 64) return;
    int lane = t & 63;
    int fr = t >> 6;
    int ct = fr / 9;
    int kc = fr - ct * 9;
    int col = ct * 16 + (lane & 15);
    int krow = kc * 32 + (lane >> 4) * 8;
    uint32_t od[4];
    #pragma unroll
    for (int j = 0; j < 4; ++j) {
        uint16_t lo = f2bf_rne(w1[(size_t)(krow + 2 * j) * 128 + col]);
        uint16_t hi = f2bf_rne(w1[(size_t)(krow + 2 * j + 1) * 128 + col]);
        od[j] = (uint32_t)lo | ((uint32_t)hi << 16);
    }
    *(uint4*)(w1f + (size_t)t * 8) = make_uint4(od[0], od[1], od[2], od[3]);
}

// ---------- sort kernels ----------
__global__ void key_hist_kernel(const float4* __restrict__ ray,
                                uint16_t* __restrict__ keys,
                                uint32_t* __restrict__ hist) {
    int r = blockIdx.x * 256 + threadIdx.x;
    float4 p = ray[r];
    uint32_t key = morton4(p);
    keys[r] = (uint16_t)key;
    atomicAdd(&hist[key], 1u);
}

__global__ void scanA_kernel(const uint32_t* __restrict__ hist, uint32_t* __restrict__ bsum) {
    __shared__ uint32_t s[256];
    int t = threadIdx.x;
    s[t] = hist[blockIdx.x * 256 + t];
    __syncthreads();
    for (int d = 128; d > 0; d >>= 1) {
        if (t < d) s[t] += s[t + d];
        __syncthreads();
    }
    if (t == 0) bsum[blockIdx.x] = s[0];
}

__global__ void scanB_kernel(uint32_t* __restrict__ bsum) {
    __shared__ uint32_t s[256];
    int t = threadIdx.x;
    uint32_t v = bsum[t];
    s[t] = v;
    __syncthreads();
    for (int d = 1; d < 256; d <<= 1) {
        uint32_t x = (t >= d) ? s[t - d] : 0;
        __syncthreads();
        s[t] += x;
        __syncthreads();
    }
    bsum[t] = s[t] - v;   // exclusive
}

__global__ void scanC_kernel(const uint32_t* __restrict__ hist,
                             const uint32_t* __restrict__ bsum,
                             uint32_t* __restrict__ offs) {
    __shared__ uint32_t s[256];
    int t = threadIdx.x, b = blockIdx.x;
    uint32_t v = hist[b * 256 + t];
    s[t] = v;
    __syncthreads();
    for (int d = 1; d < 256; d <<= 1) {
        uint32_t x = (t >= d) ? s[t - d] : 0;
        __syncthreads();
        s[t] += x;
        __syncthreads();
    }
    offs[b * 256 + t] = bsum[b] + s[t] - v;
}

__global__ void scatter_kernel(const float4* __restrict__ ray,
                               const uint16_t* __restrict__ keys,
                               uint32_t* __restrict__ offs,
                               uint32_t* __restrict__ perm,
                               float4* __restrict__ ray_sorted) {
    int r = blockIdx.x * 256 + threadIdx.x;
    uint32_t key = keys[r];
    uint32_t pos = atomicAdd(&offs[key], 1u);
    perm[pos] = (uint32_t)r;
    ray_sorted[pos] = ray[r];
}

// ---------- gather (transposed): wave-uniform (level,comb), 64 consecutive rays/wave ----------
// featsT layout: uint16 featsT[(interp*N_RAYS + r)*16 + e], feature f = interp*16 + e
__global__ __launch_bounds__(256, 8) void gather_t_kernel(
    const float4* __restrict__ ray, const uint16_t* __restrict__ gt,
    uint32_t* __restrict__ featsT) {
    // XCD-chunked bijective swizzle: 18432 blocks = 8 * 2304
    int lb = (blockIdx.x & 7) * 2304 + (blockIdx.x >> 3);
    int interp = lb >> 10;                        // 0..17  (1024 blocks per interp)
    int r = ((lb & 1023) << 8) + threadIdx.x;     // consecutive sorted rays per wave
    int level = interp / 6;
    int comb = interp - level * 6;
    int H = 128 << level;

    float4 p = ray[r];
    int c0 = (0x211000 >> (4 * comb)) & 0xF;      // 0,0,0,1,1,2
    int c1 = (0x332321 >> (4 * comb)) & 0xF;      // 1,2,3,2,3,3
    float u = sel4(p, c0) * (float)(H - 1);
    float v = sel4(p, c1) * (float)(H - 1);
    float u0f = fminf(fmaxf(floorf(u), 0.0f), (float)(H - 2));
    float v0f = fminf(fmaxf(floorf(v), 0.0f), (float)(H - 2));
    float wu = u - u0f, wv = v - v0f;
    int u0 = (int)u0f, v0 = (int)v0f;

    uint32_t lvl_off = (level == 0) ? T0_OFF : ((level == 1) ? T1_OFF : T2_OFF);
    const uint16_t* gp0 = gt + lvl_off + (((size_t)comb * H + u0) * H + v0) * 16;
    const uint4* q0 = (const uint4*)gp0;                       // row u0: (v0, v0+1)
    const uint4* q1 = (const uint4*)(gp0 + (size_t)16 * H);    // row u0+1
    uint4 a0 = q0[0], a1 = q0[1], a2 = q0[2], a3 = q0[3];
    uint4 b0 = q1[0], b1 = q1[1], b2 = q1[2], b3 = q1[3];

    uint32_t c00[8], c01[8], c10[8], c11[8];
    #pragma unroll
    for (int j = 0; j < 4; ++j) {
        c00[j] = ((const uint32_t*)&a0)[j];  c00[j + 4] = ((const uint32_t*)&a1)[j];
        c01[j] = ((const uint32_t*)&a2)[j];  c01[j + 4] = ((const uint32_t*)&a3)[j];
        c10[j] = ((const uint32_t*)&b0)[j];  c10[j + 4] = ((const uint32_t*)&b1)[j];
        c11[j] = ((const uint32_t*)&b2)[j];  c11[j + 4] = ((const uint32_t*)&b3)[j];
    }

    float w00 = (1.0f - wu) * (1.0f - wv);
    float w01 = (1.0f - wu) * wv;
    float w10 = wu * (1.0f - wv);
    float w11 = wu * wv;

    uint32_t od[8];
    #pragma unroll
    for (int j = 0; j < 8; ++j) {
        float lo = w00 * bf_lo(c00[j]) + w01 * bf_lo(c01[j]) +
                   w10 * bf_lo(c10[j]) + w11 * bf_lo(c11[j]);
        float hi = w00 * bf_hi(c00[j]) + w01 * bf_hi(c01[j]) +
                   w10 * bf_hi(c10[j]) + w11 * bf_hi(c11[j]);
        od[j] = (uint32_t)f2bf_rne(lo) | ((uint32_t)f2bf_rne(hi) << 16);
    }

    uint4* op = (uint4*)(featsT + ((size_t)interp * N_RAYS + r) * 8);
    op[0] = make_uint4(od[0], od[1], od[2], od[3]);
    op[1] = make_uint4(od[4], od[5], od[6], od[7]);
}

// ---------- MFMA MLP: 32 rays/tile, 4 waves, wave owns 32 cols (featsT input) ----------
__global__ __launch_bounds__(256, 2) void mfma_mlp_kernel(
    const uint16_t* __restrict__ featsT,  // [18][N_RAYS][16] bf16 (sorted order)
    const uint16_t* __restrict__ w1f,     // packed B-frags
    const float* __restrict__ bias1,
    const float* __restrict__ w2, const float* __restrict__ bias2,
    const uint32_t* __restrict__ perm,    // nullable: out scatter indices
    float* __restrict__ out, int tiles_per_block) {
    __shared__ float s_h[32][132];

    int tid = threadIdx.x;
    int wv = tid >> 6;
    int lane = tid & 63;

    short8v bfr[2][9];
    #pragma unroll
    for (int ctl = 0; ctl < 2; ++ctl) {
        int ct = wv * 2 + ctl;
        #pragma unroll
        for (int kc = 0; kc < 9; ++kc)
            bfr[ctl][kc] = *(const short8v*)(w1f + (((size_t)(ct * 9 + kc)) * 64 + lane) * 8);
    }
    float b1c0 = bias1[wv * 32 + (lane & 15)];
    float b1c1 = bias1[wv * 32 + 16 + (lane & 15)];

    int jg = tid & 7;
    int j0 = jg * 16;
    float w2r0[16], w2r1[16], w2r2[16];
    #pragma unroll
    for (int jj = 0; jj < 16; ++jj) {
        const float* w2p = w2 + (size_t)(j0 + jj) * 3;
        w2r0[jj] = w2p[0]; w2r1[jj] = w2p[1]; w2r2[jj] = w2p[2];
    }
    float bb0 = bias2[0], bb1 = bias2[1], bb2 = bias2[2];

    int lg = lane >> 4;            // 0..3
    int half8 = (lg & 1) * 8;      // elem offset within a ray's 16-elem interp block
    int ipo = lg >> 1;             // interp parity

    for (int it = 0; it < tiles_per_block; ++it) {
        int tile = blockIdx.x * tiles_per_block + it;
        int r0 = tile * 32;
        int rA = r0 + (lane & 15);

        short8v af[18];
        #pragma unroll
        for (int kc = 0; kc < 9; ++kc) {
            size_t base = ((size_t)(2 * kc + ipo) * N_RAYS + rA) * 16 + half8;
            af[kc]     = *(const short8v*)(featsT + base);
            af[9 + kc] = *(const short8v*)(featsT + base + 256);   // +16 rays * 16 elems
        }

        float4v acc00, acc01, acc10, acc11;
        #pragma unroll
        for (int j = 0; j < 4; ++j) { acc00[j] = b1c0; acc01[j] = b1c1; acc10[j] = b1c0; acc11[j] = b1c1; }

        #pragma unroll
        for (int kc = 0; kc < 9; ++kc) {
            acc00 = __builtin_amdgcn_mfma_f32_16x16x32_bf16(af[kc],     bfr[0][kc], acc00, 0, 0, 0);
            acc01 = __builtin_amdgcn_mfma_f32_16x16x32_bf16(af[kc],     bfr[1][kc], acc01, 0, 0, 0);
            acc10 = __builtin_amdgcn_mfma_f32_16x16x32_bf16(af[9 + kc], bfr[0][kc], acc10, 0, 0, 0);
            acc11 = __builtin_amdgcn_mfma_f32_16x16x32_bf16(af[9 + kc], bfr[1][kc], acc11, 0, 0, 0);
        }

        __syncthreads();
        {
            int c0 = wv * 32 + (lane & 15);
            int rb = (lane >> 4) * 4;
            #pragma unroll
            for (int j = 0; j < 4; ++j) {
                s_h[rb + j][c0]           = fmaxf(acc00[j], 0.0f);
                s_h[rb + j][c0 + 16]      = fmaxf(acc01[j], 0.0f);
                s_h[rb + j + 16][c0]      = fmaxf(acc10[j], 0.0f);
                s_h[rb + j + 16][c0 + 16] = fmaxf(acc11[j], 0.0f);
            }
        }
        __syncthreads();

        int ray = tid >> 3;
        float p0 = 0.f, p1 = 0.f, p2 = 0.f;
        #pragma unroll
        for (int qq = 0; qq < 4; ++qq) {
            float4 hv = *(const float4*)&s_h[ray][j0 + qq * 4];
            float h0 = hv.x, h1 = hv.y, h2 = hv.z, h3 = hv.w;
            p0 += h0 * w2r0[qq * 4] + h1 * w2r0[qq * 4 + 1] + h2 * w2r0[qq * 4 + 2] + h3 * w2r0[qq * 4 + 3];
            p1 += h0 * w2r1[qq * 4] + h1 * w2r1[qq * 4 + 1] + h2 * w2r1[qq * 4 + 2] + h3 * w2r1[qq * 4 + 3];
            p2 += h0 * w2r2[qq * 4] + h1 * w2r2[qq * 4 + 1] + h2 * w2r2[qq * 4 + 2] + h3 * w2r2[qq * 4 + 3];
        }
        p0 += __shfl_xor(p0, 1); p0 += __shfl_xor(p0, 2); p0 += __shfl_xor(p0, 4);
        p1 += __shfl_xor(p1, 1); p1 += __shfl_xor(p1, 2); p1 += __shfl_xor(p1, 4);
        p2 += __shfl_xor(p2, 1); p2 += __shfl_xor(p2, 2); p2 += __shfl_xor(p2, 4);

        if (jg == 0) {
            int orig = perm ? (int)perm[r0 + ray] : (r0 + ray);
            float o0 = 1.0f / (1.0f + expf(-(p0 + bb0)));
            float o1 = 1.0f / (1.0f + expf(-(p1 + bb1)));
            float o2 = 1.0f / (1.0f + expf(-(p2 + bb2)));
            float* op = out + (size_t)orig * 3;
            op[0] = o0; op[1] = o1; op[2] = o2;
        }
    }
}

// ---------- fallback fused kernel (small ws) ----------
template <bool USE_T>
__global__ __launch_bounds__(THREADS) void fused_kernel(
    const float4* __restrict__ ray,
    const float* __restrict__ g0, const float* __restrict__ g1,
    const float* __restrict__ g2,
    const __hip_bfloat16* __restrict__ gt,
    const float* __restrict__ weights1, const float* __restrict__ bias1,
    const float* __restrict__ weights2, const float* __restrict__ bias2,
    float* __restrict__ out) {
    __shared__ float4 s_ray[NR];
    __shared__ float s_feats[NR][FSTRIDE];

    int tid = threadIdx.x;
    int rbase = blockIdx.x * NR;
    if (tid < NR) s_ray[tid] = ray[rbase + tid];
    __syncthreads();

    for (int t = tid; t < NR * 36; t += THREADS) {
        int r = t / 36;
        int rem = t - r * 36;
        int interp = rem >> 1;
        int half = rem & 1;
        int level = (interp >= 12) ? 2 : ((interp >= 6) ? 1 : 0);
        int comb = interp - level * 6;
        int H = 128 << level;
        float4 p = s_ray[r];
        int c0 = (0x211000 >> (4 * comb)) & 0xF;
        int c1 = (0x332321 >> (4 * comb)) & 0xF;
        float u = sel4(p, c0) * (float)(H - 1);
        float v = sel4(p, c1) * (float)(H - 1);
        float u0f = fminf(fmaxf(floorf(u), 0.0f), (float)(H - 2));
        float v0f = fminf(fmaxf(floorf(v), 0.0f), (float)(H - 2));
        float wu = u - u0f, wv = v - v0f;
        int u0 = (int)u0f, v0 = (int)v0f;
        float w00 = (1.0f - wu) * (1.0f - wv);
        float w01 = (1.0f - wu) * wv;
        float w10 = wu * (1.0f - wv);
        float w11 = wu * wv;
        float f[8];
        if (USE_T) {
            uint32_t lvl_off = (level == 0) ? T0_OFF : ((level == 1) ? T1_OFF : T2_OFF);
            const uint16_t* gp = (const uint16_t*)gt + lvl_off +
                                 (((size_t)comb * H + u0) * H + v0) * 16 + half * 8;
            uint4 a00 = *(const uint4*)gp;
            uint4 a01 = *(const uint4*)(gp + 16);
            uint4 a10 = *(const uint4*)(gp + (size_t)16 * H);
            uint4 a11 = *(const uint4*)(gp + (size_t)16 * H + 16);
            #pragma unroll
            for (int i = 0; i < 8; ++i) {
                f[i] = w00 * bf_extract(a00, i) + w01 * bf_extract(a01, i) +
                       w10 * bf_extract(a10, i) + w11 * bf_extract(a11, i);
            }
        } else {
            const float* gp = (level == 0) ? g0 : ((level == 1) ? g1 : g2);
            const float* base = gp + ((size_t)(comb * 16 + half * 8) * H + u0) * H + v0;
            #pragma unroll
            for (int i = 0; i < 8; ++i) {
                const float* q = base + (size_t)i * H * H;
                float a00 = q[0], a01 = q[1], a10 = q[H], a11 = q[H + 1];
                f[i] = w00 * a00 + w01 * a01 + w10 * a10 + w11 * a11;
            }
        }
        int fo = interp * 16 + half * 8;
        float* fp = &s_feats[r][fo];
        #pragma unroll
        for (int i = 0; i < 8; ++i) fp[i] = f[i];
    }
    __syncthreads();

    int r = tid >> 3;
    int jg = tid & 7;
    int j0 = jg * 16;
    float acc[16];
    #pragma unroll
    for (int jj = 0; jj < 16; ++jj) acc[jj] = bias1[j0 + jj];

    const float* wp = weights1 + j0;
    for (int k = 0; k < 288; k += 4) {
        float4 fv = *(const float4*)&s_feats[r][k];
        #pragma unroll
        for (int kk = 0; kk < 4; ++kk) {
            const float4* wr = (const float4*)(wp + (size_t)(k + kk) * 128);
            float fk = (kk == 0) ? fv.x : ((kk == 1) ? fv.y : ((kk == 2) ? fv.z : fv.w));
            float4 wa = wr[0], wb = wr[1], wc = wr[2], wd = wr[3];
            acc[0]  += fk * wa.x; acc[1]  += fk * wa.y; acc[2]  += fk * wa.z; acc[3]  += fk * wa.w;
            acc[4]  += fk * wb.x; acc[5]  += fk * wb.y; acc[6]  += fk * wb.z; acc[7]  += fk * wb.w;
            acc[8]  += fk * wc.x; acc[9]  += fk * wc.y; acc[10] += fk * wc.z; acc[11] += fk * wc.w;
            acc[12] += fk * wd.x; acc[13] += fk * wd.y; acc[14] += fk * wd.z; acc[15] += fk * wd.w;
        }
    }

    float p0 = 0.f, p1 = 0.f, p2 = 0.f;
    #pragma unroll
    for (int jj = 0; jj < 16; ++jj) {
        float h = fmaxf(acc[jj], 0.0f);
        const float* w2r = weights2 + (size_t)(j0 + jj) * 3;
        p0 += h * w2r[0];
        p1 += h * w2r[1];
        p2 += h * w2r[2];
    }
    p0 += __shfl_xor(p0, 1); p0 += __shfl_xor(p0, 2); p0 += __shfl_xor(p0, 4);
    p1 += __shfl_xor(p1, 1); p1 += __shfl_xor(p1, 2); p1 += __shfl_xor(p1, 4);
    p2 += __shfl_xor(p2, 1); p2 += __shfl_xor(p2, 2); p2 += __shfl_xor(p2, 4);

    if (jg == 0) {
        float o0 = 1.0f / (1.0f + expf(-(p0 + bias2[0])));
        float o1 = 1.0f / (1.0f + expf(-(p1 + bias2[1])));
        float o2 = 1.0f / (1.0f + expf(-(p2 + bias2[2])));
        float* op = out + (size_t)(rbase + r) * 3;
        op[0] = o0; op[1] = o1; op[2] = o2;
    }
}

extern "C" void kernel_launch(void* const* d_in, const int* in_sizes, int n_in,
                              void* d_out, int out_size, void* d_ws, size_t ws_size,
                              hipStream_t stream) {
    const float4* ray = (const float4*)d_in[0];
    const float* g0 = (const float*)d_in[1];
    const float* g1 = (const float*)d_in[2];
    const float* g2 = (const float*)d_in[3];
    const float* w1 = (const float*)d_in[4];
    const float* b1 = (const float*)d_in[5];
    const float* w2 = (const float*)d_in[6];
    const float* b2 = (const float*)d_in[7];
    float* out = (float*)d_out;

    const size_t T_BYTES = (size_t)T_ELEMS * 2;
    const size_t NEED = (size_t)W1F_BYTE_OFF + W1F_BYTES;

    if (ws_size >= (size_t)NEED_SORT) {
        char* ws = (char*)d_ws;
        __hip_bfloat16* wsb = (__hip_bfloat16*)d_ws;
        uint32_t* feats = (uint32_t*)(ws + FEAT_BYTE_OFF);
        uint32_t* bsum  = (uint32_t*)(ws + FEAT_BYTE_OFF);   // reused before gather writes feats
        uint16_t* w1f  = (uint16_t*)(ws + W1F_BYTE_OFF);
        uint16_t* keys = (uint16_t*)(ws + KEYS_OFF);
        uint32_t* perm = (uint32_t*)(ws + PERM_OFF);
        uint32_t* hist = (uint32_t*)(ws + HIST_OFF);
        uint32_t* offs = (uint32_t*)(ws + OFFS_OFF);
        float4* rsort  = (float4*)(ws + RSORT_OFF);

        hipMemsetAsync(hist, 0, 65536 * 4, stream);
        transpose_kernel<<<(6 * 128 * 128 + 255) / 256, 256, 0, stream>>>(g0, wsb + T0_OFF, 128);
        transpose_kernel<<<(6 * 256 * 256 + 255) / 256, 256, 0, stream>>>(g1, wsb + T1_OFF, 256);
        transpose_kernel<<<(6 * 512 * 512 + 255) / 256, 256, 0, stream>>>(g2, wsb + T2_OFF, 512);
        w1_pack_kernel<<<72, 64, 0, stream>>>(w1, w1f);
        key_hist_kernel<<<N_RAYS / 256, 256, 0, stream>>>(ray, keys, hist);
        scanA_kernel<<<256, 256, 0, stream>>>(hist, bsum);
        scanB_kernel<<<1, 256, 0, stream>>>(bsum);
        scanC_kernel<<<256, 256, 0, stream>>>(hist, bsum, offs);
        scatter_kernel<<<N_RAYS / 256, 256, 0, stream>>>(ray, keys, offs, perm, rsort);
        gather_t_kernel<<<18432, 256, 0, stream>>>(rsort, (const uint16_t*)wsb, feats);
        const int TILES_PER_BLOCK = 4;
        int nblk = N_RAYS / 32 / TILES_PER_BLOCK;   // 2048
        mfma_mlp_kernel<<<nblk, 256, 0, stream>>>(
            (const uint16_t*)feats, w1f, b1, w2, b2, perm, out, TILES_PER_BLOCK);
    } else if (ws_size >= NEED) {
        __hip_bfloat16* wsb = (__hip_bfloat16*)d_ws;
        transpose_kernel<<<(6 * 128 * 128 + 255) / 256, 256, 0, stream>>>(g0, wsb + T0_OFF, 128);
        transpose_kernel<<<(6 * 256 * 256 + 255) / 256, 256, 0, stream>>>(g1, wsb + T1_OFF, 256);
        transpose_kernel<<<(6 * 512 * 512 + 255) / 256, 256, 0, stream>>>(g2, wsb + T2_OFF, 512);
        uint32_t* feats = (uint32_t*)((char*)d_ws + FEAT_BYTE_OFF);
        uint16_t* w1f = (uint16_t*)((char*)d_ws + W1F_BYTE_OFF);
        w1_pack_kernel<<<72, 64, 0, stream>>>(w1, w1f);
        gather_t_kernel<<<18432, 256, 0, stream>>>(ray, (const uint16_t*)wsb, feats);
        const int TILES_PER_BLOCK = 4;
        int nblk = N_RAYS / 32 / TILES_PER_BLOCK;
        mfma_mlp_kernel<<<nblk, 256, 0, stream>>>(
            (const uint16_t*)feats, w1f, b1, w2, b2, nullptr, out, TILES_PER_BLOCK);
    } else if (ws_size >= T_BYTES) {
        __hip_bfloat16* wsb = (__hip_bfloat16*)d_ws;
        transpose_kernel<<<(6 * 128 * 128 + 255) / 256, 256, 0, stream>>>(g0, wsb + T0_OFF, 128);
        transpose_kernel<<<(6 * 256 * 256 + 255) / 256, 256, 0, stream>>>(g1, wsb + T1_OFF, 256);
        transpose_kernel<<<(6 * 512 * 512 + 255) / 256, 256, 0, stream>>>(g2, wsb + T2_OFF, 512);
        fused_kernel<true><<<N_RAYS / NR, THREADS, 0, stream>>>(
            ray, g0, g1, g2, wsb, w1, b1, w2, b2, out);
    } else {
        fused_kernel<false><<<N_RAYS / NR, THREADS, 0, stream>>>(
            ray, g0, g1, g2, nullptr, w1, b1, w2, b2, out);
    }
}

// Round 7
// 196.349 us; speedup vs baseline: 2.0408x; 1.5373x over previous
//
#include <hip/hip_runtime.h>
#include <hip/hip_bf16.h>
#include <cstdint>
#include <cstddef>

#define N_RAYS 262144
#define NR 32
#define THREADS 256
#define FSTRIDE 292

// offsets in uint16 elements into the transposed-grid arena
#define T0_OFF 0u
#define T1_OFF 1572864u      // 6*128*128*16
#define T2_OFF 7864320u      // + 6*256*256*16
#define T_ELEMS 33030144u    // 6*16*(128^2+256^2+512^2)
#define FEAT_BYTE_OFF 66060288u   // T_ELEMS*2
#define FEAT_DWORDS 37748736u     // 262144*144
#define W1F_BYTE_OFF 217055232u   // FEAT_BYTE_OFF + FEAT_DWORDS*4
#define W1F_BYTES 73728u          // 288*128*2
// sort scratch (bytes)
#define KEYS_OFF   217128960u     // u16[262144]  (512 KB)
#define PERM_OFF   217653248u     // u32[262144]  (1 MB)
#define HIST_OFF   218701824u     // u32[65536]   (256 KB)
#define OFFS_OFF   218963968u     // u32[65536]   (256 KB)
#define RSORT_OFF  219226112u     // float4[262144] (4 MB)
#define NEED_SORT  223420416u

typedef __attribute__((ext_vector_type(8))) short short8v;   // 8 bf16 = 4 VGPRs
typedef __attribute__((ext_vector_type(4))) float float4v;   // MFMA C/D

// ---------- helpers ----------
__device__ __forceinline__ float bf_lo(uint32_t w) { return __uint_as_float(w << 16); }
__device__ __forceinline__ float bf_hi(uint32_t w) { return __uint_as_float(w & 0xFFFF0000u); }

__device__ __forceinline__ float bf_extract(const uint4& q, int i) {
    uint32_t w = ((const uint32_t*)&q)[i >> 1];
    uint32_t h = (i & 1) ? (w & 0xFFFF0000u) : (w << 16);
    return __uint_as_float(h);
}

__device__ __forceinline__ uint16_t f2bf_rne(float f) {
    uint32_t x = __float_as_uint(f);
    uint32_t r = x + 0x7FFFu + ((x >> 16) & 1u);
    return (uint16_t)(r >> 16);
}

__device__ __forceinline__ float sel4(const float4& p, int i) {
    float r = p.x;
    r = (i == 1) ? p.y : r;
    r = (i == 2) ? p.z : r;
    r = (i == 3) ? p.w : r;
    return r;
}

__device__ __forceinline__ uint32_t morton4(const float4& p) {
    int q0 = min(15, max(0, (int)(p.x * 16.0f)));
    int q1 = min(15, max(0, (int)(p.y * 16.0f)));
    int q2 = min(15, max(0, (int)(p.z * 16.0f)));
    int q3 = min(15, max(0, (int)(p.w * 16.0f)));
    uint32_t key = 0;
    #pragma unroll
    for (int b = 0; b < 4; ++b) {
        key |= (uint32_t)((q0 >> b) & 1) << (4 * b + 0);
        key |= (uint32_t)((q1 >> b) & 1) << (4 * b + 1);
        key |= (uint32_t)((q2 >> b) & 1) << (4 * b + 2);
        key |= (uint32_t)((q3 >> b) & 1) << (4 * b + 3);
    }
    return key;
}

// ---------- transpose: [6][16][H][H] f32 -> [6][H][H][16] bf16 ----------
__global__ void transpose_kernel(const float* __restrict__ in,
                                 __hip_bfloat16* __restrict__ out, int H) {
    int idx = blockIdx.x * blockDim.x + threadIdx.x;
    int hh = H * H;
    int total = 6 * hh;
    if (idx >= total) return;
    int c = idx / hh;
    int rem = idx - c * hh;
    const float* ip = in + (size_t)c * 16 * hh + rem;
    uint32_t words[8];
    #pragma unroll
    for (int j = 0; j < 8; ++j) {
        uint16_t lo = f2bf_rne(ip[(size_t)(2 * j) * hh]);
        uint16_t hi = f2bf_rne(ip[(size_t)(2 * j + 1) * hh]);
        words[j] = (uint32_t)lo | ((uint32_t)hi << 16);
    }
    uint4* op = (uint4*)((uint16_t*)out + (size_t)idx * 16);
    op[0] = make_uint4(words[0], words[1], words[2], words[3]);
    op[1] = make_uint4(words[4], words[5], words[6], words[7]);
}

// ---------- pack w1 [288][128] f32 -> bf16 MFMA B-frag layout ----------
__global__ void w1_pack_kernel(const float* __restrict__ w1, uint16_t* __restrict__ w1f) {
    int t = blockIdx.x * 64 + threadIdx.x;   // 4608 threads
    if (t >= 8 * 9 * 64) return;
    int lane = t & 63;
    int fr = t >> 6;
    int ct = fr / 9;
    int kc = fr - ct * 9;
    int col = ct * 16 + (lane & 15);
    int krow = kc * 32 + (lane >> 4) * 8;
    uint32_t od[4];
    #pragma unroll
    for (int j = 0; j < 4; ++j) {
        uint16_t lo = f2bf_rne(w1[(size_t)(krow + 2 * j) * 128 + col]);
        uint16_t hi = f2bf_rne(w1[(size_t)(krow + 2 * j + 1) * 128 + col]);
        od[j] = (uint32_t)lo | ((uint32_t)hi << 16);
    }
    *(uint4*)(w1f + (size_t)t * 8) = make_uint4(od[0], od[1], od[2], od[3]);
}

// ---------- sort kernels ----------
__global__ void key_hist_kernel(const float4* __restrict__ ray,
                                uint16_t* __restrict__ keys,
                                uint32_t* __restrict__ hist) {
    int r = blockIdx.x * 256 + threadIdx.x;
    float4 p = ray[r];
    uint32_t key = morton4(p);
    keys[r] = (uint16_t)key;
    atomicAdd(&hist[key], 1u);
}

__global__ void scanA_kernel(const uint32_t* __restrict__ hist, uint32_t* __restrict__ bsum) {
    __shared__ uint32_t s[256];
    int t = threadIdx.x;
    s[t] = hist[blockIdx.x * 256 + t];
    __syncthreads();
    for (int d = 128; d > 0; d >>= 1) {
        if (t < d) s[t] += s[t + d];
        __syncthreads();
    }
    if (t == 0) bsum[blockIdx.x] = s[0];
}

__global__ void scanB_kernel(uint32_t* __restrict__ bsum) {
    __shared__ uint32_t s[256];
    int t = threadIdx.x;
    uint32_t v = bsum[t];
    s[t] = v;
    __syncthreads();
    for (int d = 1; d < 256; d <<= 1) {
        uint32_t x = (t >= d) ? s[t - d] : 0;
        __syncthreads();
        s[t] += x;
        __syncthreads();
    }
    bsum[t] = s[t] - v;   // exclusive
}

__global__ void scanC_kernel(const uint32_t* __restrict__ hist,
                             const uint32_t* __restrict__ bsum,
                             uint32_t* __restrict__ offs) {
    __shared__ uint32_t s[256];
    int t = threadIdx.x, b = blockIdx.x;
    uint32_t v = hist[b * 256 + t];
    s[t] = v;
    __syncthreads();
    for (int d = 1; d < 256; d <<= 1) {
        uint32_t x = (t >= d) ? s[t - d] : 0;
        __syncthreads();
        s[t] += x;
        __syncthreads();
    }
    offs[b * 256 + t] = bsum[b] + s[t] - v;
}

__global__ void scatter_kernel(const float4* __restrict__ ray,
                               const uint16_t* __restrict__ keys,
                               uint32_t* __restrict__ offs,
                               uint32_t* __restrict__ perm,
                               float4* __restrict__ ray_sorted) {
    int r = blockIdx.x * 256 + threadIdx.x;
    uint32_t key = keys[r];
    uint32_t pos = atomicAdd(&offs[key], 1u);
    perm[pos] = (uint32_t)r;
    ray_sorted[pos] = ray[r];
}

// ---------- FUSED gather + MFMA MLP: 32 sorted rays per block ----------
// LDS feats row stride 148 dwords; s_h (stride 132 floats) aliases s_feats after barrier.
__global__ __launch_bounds__(256, 4) void fused_gmlp_kernel(
    const float4* __restrict__ rsort, const uint16_t* __restrict__ gt,
    const uint16_t* __restrict__ w1f, const float* __restrict__ bias1,
    const float* __restrict__ w2, const float* __restrict__ bias2,
    const uint32_t* __restrict__ perm, float* __restrict__ out) {
    __shared__ uint32_t s_feats[32 * 148];   // 18944 B
    __shared__ float s_w2[384];
    __shared__ float4 s_ray[32];

    int tid = threadIdx.x;
    int wvid = tid >> 6;
    int lane = tid & 63;
    // XCD-chunked bijective swizzle: 8192 blocks = 8 * 1024
    int swz = ((blockIdx.x & 7) << 10) + (blockIdx.x >> 3);
    int r0 = swz << 5;

    if (tid < 32) s_ray[tid] = rsort[r0 + tid];
    s_w2[tid] = w2[tid];
    if (tid < 128) s_w2[256 + tid] = w2[256 + tid];
    __syncthreads();

    // ---- phase A: 9 slots of 64 tasks; wave wvid handles slots wvid, wvid+4, wvid+8 ----
    for (int s = wvid; s < 9; s += 4) {
        int interp = 2 * s + (lane >> 5);
        int r = lane & 31;
        int level = (interp >= 12) ? 2 : ((interp >= 6) ? 1 : 0);
        int comb = interp - level * 6;
        int H = 128 << level;
        float4 p = s_ray[r];
        int c0 = (0x211000 >> (4 * comb)) & 0xF;   // 0,0,0,1,1,2
        int c1 = (0x332321 >> (4 * comb)) & 0xF;   // 1,2,3,2,3,3
        float u = sel4(p, c0) * (float)(H - 1);
        float v = sel4(p, c1) * (float)(H - 1);
        float u0f = fminf(fmaxf(floorf(u), 0.0f), (float)(H - 2));
        float v0f = fminf(fmaxf(floorf(v), 0.0f), (float)(H - 2));
        float fu = u - u0f, fv = v - v0f;
        int u0 = (int)u0f, v0 = (int)v0f;

        uint32_t lvl_off = (level == 0) ? T0_OFF : ((level == 1) ? T1_OFF : T2_OFF);
        const uint16_t* gp0 = gt + lvl_off + (((size_t)comb * H + u0) * H + v0) * 16;
        const uint4* q0 = (const uint4*)gp0;                       // row u0: (v0, v0+1)
        const uint4* q1 = (const uint4*)(gp0 + (size_t)16 * H);    // row u0+1
        uint4 a0 = q0[0], a1 = q0[1], a2 = q0[2], a3 = q0[3];
        uint4 b0 = q1[0], b1 = q1[1], b2 = q1[2], b3 = q1[3];

        uint32_t c00[8], c01[8], c10[8], c11[8];
        #pragma unroll
        for (int j = 0; j < 4; ++j) {
            c00[j] = ((const uint32_t*)&a0)[j];  c00[j + 4] = ((const uint32_t*)&a1)[j];
            c01[j] = ((const uint32_t*)&a2)[j];  c01[j + 4] = ((const uint32_t*)&a3)[j];
            c10[j] = ((const uint32_t*)&b0)[j];  c10[j + 4] = ((const uint32_t*)&b1)[j];
            c11[j] = ((const uint32_t*)&b2)[j];  c11[j + 4] = ((const uint32_t*)&b3)[j];
        }

        float w00 = (1.0f - fu) * (1.0f - fv);
        float w01 = (1.0f - fu) * fv;
        float w10 = fu * (1.0f - fv);
        float w11 = fu * fv;

        uint32_t od[8];
        #pragma unroll
        for (int j = 0; j < 8; ++j) {
            float lo = w00 * bf_lo(c00[j]) + w01 * bf_lo(c01[j]) +
                       w10 * bf_lo(c10[j]) + w11 * bf_lo(c11[j]);
            float hi = w00 * bf_hi(c00[j]) + w01 * bf_hi(c01[j]) +
                       w10 * bf_hi(c10[j]) + w11 * bf_hi(c11[j]);
            od[j] = (uint32_t)f2bf_rne(lo) | ((uint32_t)f2bf_rne(hi) << 16);
        }
        uint32_t* op = &s_feats[r * 148 + interp * 8];
        *(uint4*)op       = make_uint4(od[0], od[1], od[2], od[3]);
        *(uint4*)(op + 4) = make_uint4(od[4], od[5], od[6], od[7]);
    }
    __syncthreads();

    // ---- phase B: MFMA (two passes over ct to cap VGPR) ----
    float b1c0 = bias1[wvid * 32 + (lane & 15)];
    float b1c1 = bias1[wvid * 32 + 16 + (lane & 15)];
    int lg = lane >> 4;
    const uint32_t* arow = &s_feats[(lane & 15) * 148 + lg * 4];

    float4v acc00, acc10, acc01, acc11;
    {
        short8v bfrA[9];
        #pragma unroll
        for (int kc = 0; kc < 9; ++kc)
            bfrA[kc] = *(const short8v*)(w1f + (((size_t)((wvid * 2) * 9 + kc)) * 64 + lane) * 8);
        #pragma unroll
        for (int j = 0; j < 4; ++j) { acc00[j] = b1c0; acc10[j] = b1c0; }
        #pragma unroll
        for (int kc = 0; kc < 9; ++kc) {
            short8v a0 = *(const short8v*)(arow + kc * 16);
            short8v a1 = *(const short8v*)(arow + 16 * 148 + kc * 16);
            acc00 = __builtin_amdgcn_mfma_f32_16x16x32_bf16(a0, bfrA[kc], acc00, 0, 0, 0);
            acc10 = __builtin_amdgcn_mfma_f32_16x16x32_bf16(a1, bfrA[kc], acc10, 0, 0, 0);
        }
    }
    {
        short8v bfrB[9];
        #pragma unroll
        for (int kc = 0; kc < 9; ++kc)
            bfrB[kc] = *(const short8v*)(w1f + (((size_t)((wvid * 2 + 1) * 9 + kc)) * 64 + lane) * 8);
        #pragma unroll
        for (int j = 0; j < 4; ++j) { acc01[j] = b1c1; acc11[j] = b1c1; }
        #pragma unroll
        for (int kc = 0; kc < 9; ++kc) {
            short8v a0 = *(const short8v*)(arow + kc * 16);
            short8v a1 = *(const short8v*)(arow + 16 * 148 + kc * 16);
            acc01 = __builtin_amdgcn_mfma_f32_16x16x32_bf16(a0, bfrB[kc], acc01, 0, 0, 0);
            acc11 = __builtin_amdgcn_mfma_f32_16x16x32_bf16(a1, bfrB[kc], acc11, 0, 0, 0);
        }
    }
    __syncthreads();   // all s_feats reads done; safe to alias as s_h

    float* s_h = (float*)s_feats;   // [32][132]
    {
        int c0 = wvid * 32 + (lane & 15);
        int rb = lg * 4;
        #pragma unroll
        for (int j = 0; j < 4; ++j) {
            s_h[(rb + j) * 132 + c0]            = fmaxf(acc00[j], 0.0f);
            s_h[(rb + j) * 132 + c0 + 16]       = fmaxf(acc01[j], 0.0f);
            s_h[(rb + j + 16) * 132 + c0]       = fmaxf(acc10[j], 0.0f);
            s_h[(rb + j + 16) * 132 + c0 + 16]  = fmaxf(acc11[j], 0.0f);
        }
    }
    __syncthreads();

    // ---- layer 2 + sigmoid + scatter ----
    int ray = tid >> 3;
    int jg = tid & 7;
    int j0 = jg * 16;
    float p0 = 0.f, p1 = 0.f, p2 = 0.f;
    #pragma unroll
    for (int qq = 0; qq < 4; ++qq) {
        float4 hv = *(const float4*)&s_h[ray * 132 + j0 + qq * 4];
        const float* w2a = &s_w2[(j0 + qq * 4) * 3];
        p0 += hv.x * w2a[0] + hv.y * w2a[3] + hv.z * w2a[6] + hv.w * w2a[9];
        p1 += hv.x * w2a[1] + hv.y * w2a[4] + hv.z * w2a[7] + hv.w * w2a[10];
        p2 += hv.x * w2a[2] + hv.y * w2a[5] + hv.z * w2a[8] + hv.w * w2a[11];
    }
    p0 += __shfl_xor(p0, 1); p0 += __shfl_xor(p0, 2); p0 += __shfl_xor(p0, 4);
    p1 += __shfl_xor(p1, 1); p1 += __shfl_xor(p1, 2); p1 += __shfl_xor(p1, 4);
    p2 += __shfl_xor(p2, 1); p2 += __shfl_xor(p2, 2); p2 += __shfl_xor(p2, 4);

    if (jg == 0) {
        int orig = (int)perm[r0 + ray];
        float o0 = 1.0f / (1.0f + expf(-(p0 + bias2[0])));
        float o1 = 1.0f / (1.0f + expf(-(p1 + bias2[1])));
        float o2 = 1.0f / (1.0f + expf(-(p2 + bias2[2])));
        float* op = out + (size_t)orig * 3;
        op[0] = o0; op[1] = o1; op[2] = o2;
    }
}

// ---------- gather (transposed) + standalone MLP: tier-2 fallback ----------
__global__ __launch_bounds__(256, 8) void gather_t_kernel(
    const float4* __restrict__ ray, const uint16_t* __restrict__ gt,
    uint32_t* __restrict__ featsT) {
    int lb = (blockIdx.x & 7) * 2304 + (blockIdx.x >> 3);
    int interp = lb >> 10;
    int r = ((lb & 1023) << 8) + threadIdx.x;
    int level = interp / 6;
    int comb = interp - level * 6;
    int H = 128 << level;

    float4 p = ray[r];
    int c0 = (0x211000 >> (4 * comb)) & 0xF;
    int c1 = (0x332321 >> (4 * comb)) & 0xF;
    float u = sel4(p, c0) * (float)(H - 1);
    float v = sel4(p, c1) * (float)(H - 1);
    float u0f = fminf(fmaxf(floorf(u), 0.0f), (float)(H - 2));
    float v0f = fminf(fmaxf(floorf(v), 0.0f), (float)(H - 2));
    float wu = u - u0f, wv = v - v0f;
    int u0 = (int)u0f, v0 = (int)v0f;

    uint32_t lvl_off = (level == 0) ? T0_OFF : ((level == 1) ? T1_OFF : T2_OFF);
    const uint16_t* gp0 = gt + lvl_off + (((size_t)comb * H + u0) * H + v0) * 16;
    const uint4* q0 = (const uint4*)gp0;
    const uint4* q1 = (const uint4*)(gp0 + (size_t)16 * H);
    uint4 a0 = q0[0], a1 = q0[1], a2 = q0[2], a3 = q0[3];
    uint4 b0 = q1[0], b1 = q1[1], b2 = q1[2], b3 = q1[3];

    uint32_t c00[8], c01[8], c10[8], c11[8];
    #pragma unroll
    for (int j = 0; j < 4; ++j) {
        c00[j] = ((const uint32_t*)&a0)[j];  c00[j + 4] = ((const uint32_t*)&a1)[j];
        c01[j] = ((const uint32_t*)&a2)[j];  c01[j + 4] = ((const uint32_t*)&a3)[j];
        c10[j] = ((const uint32_t*)&b0)[j];  c10[j + 4] = ((const uint32_t*)&b1)[j];
        c11[j] = ((const uint32_t*)&b2)[j];  c11[j + 4] = ((const uint32_t*)&b3)[j];
    }

    float w00 = (1.0f - wu) * (1.0f - wv);
    float w01 = (1.0f - wu) * wv;
    float w10 = wu * (1.0f - wv);
    float w11 = wu * wv;

    uint32_t od[8];
    #pragma unroll
    for (int j = 0; j < 8; ++j) {
        float lo = w00 * bf_lo(c00[j]) + w01 * bf_lo(c01[j]) +
                   w10 * bf_lo(c10[j]) + w11 * bf_lo(c11[j]);
        float hi = w00 * bf_hi(c00[j]) + w01 * bf_hi(c01[j]) +
                   w10 * bf_hi(c10[j]) + w11 * bf_hi(c11[j]);
        od[j] = (uint32_t)f2bf_rne(lo) | ((uint32_t)f2bf_rne(hi) << 16);
    }

    uint4* op = (uint4*)(featsT + ((size_t)interp * N_RAYS + r) * 8);
    op[0] = make_uint4(od[0], od[1], od[2], od[3]);
    op[1] = make_uint4(od[4], od[5], od[6], od[7]);
}

__global__ __launch_bounds__(256, 2) void mfma_mlp_kernel(
    const uint16_t* __restrict__ featsT,
    const uint16_t* __restrict__ w1f,
    const float* __restrict__ bias1,
    const float* __restrict__ w2, const float* __restrict__ bias2,
    const uint32_t* __restrict__ perm,
    float* __restrict__ out, int tiles_per_block) {
    __shared__ float s_h[32][132];

    int tid = threadIdx.x;
    int wv = tid >> 6;
    int lane = tid & 63;

    short8v bfr[2][9];
    #pragma unroll
    for (int ctl = 0; ctl < 2; ++ctl) {
        int ct = wv * 2 + ctl;
        #pragma unroll
        for (int kc = 0; kc < 9; ++kc)
            bfr[ctl][kc] = *(const short8v*)(w1f + (((size_t)(ct * 9 + kc)) * 64 + lane) * 8);
    }
    float b1c0 = bias1[wv * 32 + (lane & 15)];
    float b1c1 = bias1[wv * 32 + 16 + (lane & 15)];

    int jg = tid & 7;
    int j0 = jg * 16;
    float w2r0[16], w2r1[16], w2r2[16];
    #pragma unroll
    for (int jj = 0; jj < 16; ++jj) {
        const float* w2p = w2 + (size_t)(j0 + jj) * 3;
        w2r0[jj] = w2p[0]; w2r1[jj] = w2p[1]; w2r2[jj] = w2p[2];
    }
    float bb0 = bias2[0], bb1 = bias2[1], bb2 = bias2[2];

    int lg = lane >> 4;
    int half8 = (lg & 1) * 8;
    int ipo = lg >> 1;

    for (int it = 0; it < tiles_per_block; ++it) {
        int tile = blockIdx.x * tiles_per_block + it;
        int r0 = tile * 32;
        int rA = r0 + (lane & 15);

        short8v af[18];
        #pragma unroll
        for (int kc = 0; kc < 9; ++kc) {
            size_t base = ((size_t)(2 * kc + ipo) * N_RAYS + rA) * 16 + half8;
            af[kc]     = *(const short8v*)(featsT + base);
            af[9 + kc] = *(const short8v*)(featsT + base + 256);
        }

        float4v acc00, acc01, acc10, acc11;
        #pragma unroll
        for (int j = 0; j < 4; ++j) { acc00[j] = b1c0; acc01[j] = b1c1; acc10[j] = b1c0; acc11[j] = b1c1; }

        #pragma unroll
        for (int kc = 0; kc < 9; ++kc) {
            acc00 = __builtin_amdgcn_mfma_f32_16x16x32_bf16(af[kc],     bfr[0][kc], acc00, 0, 0, 0);
            acc01 = __builtin_amdgcn_mfma_f32_16x16x32_bf16(af[kc],     bfr[1][kc], acc01, 0, 0, 0);
            acc10 = __builtin_amdgcn_mfma_f32_16x16x32_bf16(af[9 + kc], bfr[0][kc], acc10, 0, 0, 0);
            acc11 = __builtin_amdgcn_mfma_f32_16x16x32_bf16(af[9 + kc], bfr[1][kc], acc11, 0, 0, 0);
        }

        __syncthreads();
        {
            int c0 = wv * 32 + (lane & 15);
            int rb = (lane >> 4) * 4;
            #pragma unroll
            for (int j = 0; j < 4; ++j) {
                s_h[rb + j][c0]           = fmaxf(acc00[j], 0.0f);
                s_h[rb + j][c0 + 16]      = fmaxf(acc01[j], 0.0f);
                s_h[rb + j + 16][c0]      = fmaxf(acc10[j], 0.0f);
                s_h[rb + j + 16][c0 + 16] = fmaxf(acc11[j], 0.0f);
            }
        }
        __syncthreads();

        int ray = tid >> 3;
        float p0 = 0.f, p1 = 0.f, p2 = 0.f;
        #pragma unroll
        for (int qq = 0; qq < 4; ++qq) {
            float4 hv = *(const float4*)&s_h[ray][j0 + qq * 4];
            float h0 = hv.x, h1 = hv.y, h2 = hv.z, h3 = hv.w;
            p0 += h0 * w2r0[qq * 4] + h1 * w2r0[qq * 4 + 1] + h2 * w2r0[qq * 4 + 2] + h3 * w2r0[qq * 4 + 3];
            p1 += h0 * w2r1[qq * 4] + h1 * w2r1[qq * 4 + 1] + h2 * w2r1[qq * 4 + 2] + h3 * w2r1[qq * 4 + 3];
            p2 += h0 * w2r2[qq * 4] + h1 * w2r2[qq * 4 + 1] + h2 * w2r2[qq * 4 + 2] + h3 * w2r2[qq * 4 + 3];
        }
        p0 += __shfl_xor(p0, 1); p0 += __shfl_xor(p0, 2); p0 += __shfl_xor(p0, 4);
        p1 += __shfl_xor(p1, 1); p1 += __shfl_xor(p1, 2); p1 += __shfl_xor(p1, 4);
        p2 += __shfl_xor(p2, 1); p2 += __shfl_xor(p2, 2); p2 += __shfl_xor(p2, 4);

        if (jg == 0) {
            int orig = perm ? (int)perm[r0 + ray] : (r0 + ray);
            float o0 = 1.0f / (1.0f + expf(-(p0 + bb0)));
            float o1 = 1.0f / (1.0f + expf(-(p1 + bb1)));
            float o2 = 1.0f / (1.0f + expf(-(p2 + bb2)));
            float* op = out + (size_t)orig * 3;
            op[0] = o0; op[1] = o1; op[2] = o2;
        }
    }
}

// ---------- fallback fused kernel (small ws) ----------
template <bool USE_T>
__global__ __launch_bounds__(THREADS) void fused_kernel(
    const float4* __restrict__ ray,
    const float* __restrict__ g0, const float* __restrict__ g1,
    const float* __restrict__ g2,
    const __hip_bfloat16* __restrict__ gt,
    const float* __restrict__ weights1, const float* __restrict__ bias1,
    const float* __restrict__ weights2, const float* __restrict__ bias2,
    float* __restrict__ out) {
    __shared__ float4 s_ray[NR];
    __shared__ float s_feats[NR][FSTRIDE];

    int tid = threadIdx.x;
    int rbase = blockIdx.x * NR;
    if (tid < NR) s_ray[tid] = ray[rbase + tid];
    __syncthreads();

    for (int t = tid; t < NR * 36; t += THREADS) {
        int r = t / 36;
        int rem = t - r * 36;
        int interp = rem >> 1;
        int half = rem & 1;
        int level = (interp >= 12) ? 2 : ((interp >= 6) ? 1 : 0);
        int comb = interp - level * 6;
        int H = 128 << level;
        float4 p = s_ray[r];
        int c0 = (0x211000 >> (4 * comb)) & 0xF;
        int c1 = (0x332321 >> (4 * comb)) & 0xF;
        float u = sel4(p, c0) * (float)(H - 1);
        float v = sel4(p, c1) * (float)(H - 1);
        float u0f = fminf(fmaxf(floorf(u), 0.0f), (float)(H - 2));
        float v0f = fminf(fmaxf(floorf(v), 0.0f), (float)(H - 2));
        float wu = u - u0f, wv = v - v0f;
        int u0 = (int)u0f, v0 = (int)v0f;
        float w00 = (1.0f - wu) * (1.0f - wv);
        float w01 = (1.0f - wu) * wv;
        float w10 = wu * (1.0f - wv);
        float w11 = wu * wv;
        float f[8];
        if (USE_T) {
            uint32_t lvl_off = (level == 0) ? T0_OFF : ((level == 1) ? T1_OFF : T2_OFF);
            const uint16_t* gp = (const uint16_t*)gt + lvl_off +
                                 (((size_t)comb * H + u0) * H + v0) * 16 + half * 8;
            uint4 a00 = *(const uint4*)gp;
            uint4 a01 = *(const uint4*)(gp + 16);
            uint4 a10 = *(const uint4*)(gp + (size_t)16 * H);
            uint4 a11 = *(const uint4*)(gp + (size_t)16 * H + 16);
            #pragma unroll
            for (int i = 0; i < 8; ++i) {
                f[i] = w00 * bf_extract(a00, i) + w01 * bf_extract(a01, i) +
                       w10 * bf_extract(a10, i) + w11 * bf_extract(a11, i);
            }
        } else {
            const float* gp = (level == 0) ? g0 : ((level == 1) ? g1 : g2);
            const float* base = gp + ((size_t)(comb * 16 + half * 8) * H + u0) * H + v0;
            #pragma unroll
            for (int i = 0; i < 8; ++i) {
                const float* q = base + (size_t)i * H * H;
                float a00 = q[0], a01 = q[1], a10 = q[H], a11 = q[H + 1];
                f[i] = w00 * a00 + w01 * a01 + w10 * a10 + w11 * a11;
            }
        }
        int fo = interp * 16 + half * 8;
        float* fp = &s_feats[r][fo];
        #pragma unroll
        for (int i = 0; i < 8; ++i) fp[i] = f[i];
    }
    __syncthreads();

    int r = tid >> 3;
    int jg = tid & 7;
    int j0 = jg * 16;
    float acc[16];
    #pragma unroll
    for (int jj = 0; jj < 16; ++jj) acc[jj] = bias1[j0 + jj];

    const float* wp = weights1 + j0;
    for (int k = 0; k < 288; k += 4) {
        float4 fv = *(const float4*)&s_feats[r][k];
        #pragma unroll
        for (int kk = 0; kk < 4; ++kk) {
            const float4* wr = (const float4*)(wp + (size_t)(k + kk) * 128);
            float fk = (kk == 0) ? fv.x : ((kk == 1) ? fv.y : ((kk == 2) ? fv.z : fv.w));
            float4 wa = wr[0], wb = wr[1], wc = wr[2], wd = wr[3];
            acc[0]  += fk * wa.x; acc[1]  += fk * wa.y; acc[2]  += fk * wa.z; acc[3]  += fk * wa.w;
            acc[4]  += fk * wb.x; acc[5]  += fk * wb.y; acc[6]  += fk * wb.z; acc[7]  += fk * wb.w;
            acc[8]  += fk * wc.x; acc[9]  += fk * wc.y; acc[10] += fk * wc.z; acc[11] += fk * wc.w;
            acc[12] += fk * wd.x; acc[13] += fk * wd.y; acc[14] += fk * wd.z; acc[15] += fk * wd.w;
        }
    }

    float p0 = 0.f, p1 = 0.f, p2 = 0.f;
    #pragma unroll
    for (int jj = 0; jj < 16; ++jj) {
        float h = fmaxf(acc[jj], 0.0f);
        const float* w2r = weights2 + (size_t)(j0 + jj) * 3;
        p0 += h * w2r[0];
        p1 += h * w2r[1];
        p2 += h * w2r[2];
    }
    p0 += __shfl_xor(p0, 1); p0 += __shfl_xor(p0, 2); p0 += __shfl_xor(p0, 4);
    p1 += __shfl_xor(p1, 1); p1 += __shfl_xor(p1, 2); p1 += __shfl_xor(p1, 4);
    p2 += __shfl_xor(p2, 1); p2 += __shfl_xor(p2, 2); p2 += __shfl_xor(p2, 4);

    if (jg == 0) {
        float o0 = 1.0f / (1.0f + expf(-(p0 + bias2[0])));
        float o1 = 1.0f / (1.0f + expf(-(p1 + bias2[1])));
        float o2 = 1.0f / (1.0f + expf(-(p2 + bias2[2])));
        float* op = out + (size_t)(rbase + r) * 3;
        op[0] = o0; op[1] = o1; op[2] = o2;
    }
}

extern "C" void kernel_launch(void* const* d_in, const int* in_sizes, int n_in,
                              void* d_out, int out_size, void* d_ws, size_t ws_size,
                              hipStream_t stream) {
    const float4* ray = (const float4*)d_in[0];
    const float* g0 = (const float*)d_in[1];
    const float* g1 = (const float*)d_in[2];
    const float* g2 = (const float*)d_in[3];
    const float* w1 = (const float*)d_in[4];
    const float* b1 = (const float*)d_in[5];
    const float* w2 = (const float*)d_in[6];
    const float* b2 = (const float*)d_in[7];
    float* out = (float*)d_out;

    const size_t T_BYTES = (size_t)T_ELEMS * 2;
    const size_t NEED = (size_t)W1F_BYTE_OFF + W1F_BYTES;

    if (ws_size >= (size_t)NEED_SORT) {
        char* ws = (char*)d_ws;
        __hip_bfloat16* wsb = (__hip_bfloat16*)d_ws;
        uint32_t* bsum  = (uint32_t*)(ws + FEAT_BYTE_OFF);   // scratch (feat arena unused)
        uint16_t* w1f  = (uint16_t*)(ws + W1F_BYTE_OFF);
        uint16_t* keys = (uint16_t*)(ws + KEYS_OFF);
        uint32_t* perm = (uint32_t*)(ws + PERM_OFF);
        uint32_t* hist = (uint32_t*)(ws + HIST_OFF);
        uint32_t* offs = (uint32_t*)(ws + OFFS_OFF);
        float4* rsort  = (float4*)(ws + RSORT_OFF);

        hipMemsetAsync(hist, 0, 65536 * 4, stream);
        transpose_kernel<<<(6 * 128 * 128 + 255) / 256, 256, 0, stream>>>(g0, wsb + T0_OFF, 128);
        transpose_kernel<<<(6 * 256 * 256 + 255) / 256, 256, 0, stream>>>(g1, wsb + T1_OFF, 256);
        transpose_kernel<<<(6 * 512 * 512 + 255) / 256, 256, 0, stream>>>(g2, wsb + T2_OFF, 512);
        w1_pack_kernel<<<72, 64, 0, stream>>>(w1, w1f);
        key_hist_kernel<<<N_RAYS / 256, 256, 0, stream>>>(ray, keys, hist);
        scanA_kernel<<<256, 256, 0, stream>>>(hist, bsum);
        scanB_kernel<<<1, 256, 0, stream>>>(bsum);
        scanC_kernel<<<256, 256, 0, stream>>>(hist, bsum, offs);
        scatter_kernel<<<N_RAYS / 256, 256, 0, stream>>>(ray, keys, offs, perm, rsort);
        fused_gmlp_kernel<<<N_RAYS / 32, 256, 0, stream>>>(
            rsort, (const uint16_t*)wsb, w1f, b1, w2, b2, perm, out);
    } else if (ws_size >= NEED) {
        __hip_bfloat16* wsb = (__hip_bfloat16*)d_ws;
        transpose_kernel<<<(6 * 128 * 128 + 255) / 256, 256, 0, stream>>>(g0, wsb + T0_OFF, 128);
        transpose_kernel<<<(6 * 256 * 256 + 255) / 256, 256, 0, stream>>>(g1, wsb + T1_OFF, 256);
        transpose_kernel<<<(6 * 512 * 512 + 255) / 256, 256, 0, stream>>>(g2, wsb + T2_OFF, 512);
        uint32_t* feats = (uint32_t*)((char*)d_ws + FEAT_BYTE_OFF);
        uint16_t* w1f = (uint16_t*)((char*)d_ws + W1F_BYTE_OFF);
        w1_pack_kernel<<<72, 64, 0, stream>>>(w1, w1f);
        gather_t_kernel<<<18432, 256, 0, stream>>>(ray, (const uint16_t*)wsb, feats);
        const int TILES_PER_BLOCK = 4;
        int nblk = N_RAYS / 32 / TILES_PER_BLOCK;
        mfma_mlp_kernel<<<nblk, 256, 0, stream>>>(
            (const uint16_t*)feats, w1f, b1, w2, b2, nullptr, out, TILES_PER_BLOCK);
    } else if (ws_size >= T_BYTES) {
        __hip_bfloat16* wsb = (__hip_bfloat16*)d_ws;
        transpose_kernel<<<(6 * 128 * 128 + 255) / 256, 256, 0, stream>>>(g0, wsb + T0_OFF, 128);
        transpose_kernel<<<(6 * 256 * 256 + 255) / 256, 256, 0, stream>>>(g1, wsb + T1_OFF, 256);
        transpose_kernel<<<(6 * 512 * 512 + 255) / 256, 256, 0, stream>>>(g2, wsb + T2_OFF, 512);
        fused_kernel<true><<<N_RAYS / NR, THREADS, 0, stream>>>(
            ray, g0, g1, g2, wsb, w1, b1, w2, b2, out);
    } else {
        fused_kernel<false><<<N_RAYS / NR, THREADS, 0, stream>>>(
            ray, g0, g1, g2, nullptr, w1, b1, w2, b2, out);
    }
}

// Round 8
// 194.513 us; speedup vs baseline: 2.0600x; 1.0094x over previous
//
#include <hip/hip_runtime.h>
#include <hip/hip_bf16.h>
#include <cstdint>
#include <cstddef>

#define N_RAYS 262144
#define NR 32
#define THREADS 256
#define FSTRIDE 292

// offsets in uint16 elements into the transposed-grid arena
#define T0_OFF 0u
#define T1_OFF 1572864u      // 6*128*128*16
#define T2_OFF 7864320u      // + 6*256*256*16
#define T_ELEMS 33030144u    // 6*16*(128^2+256^2+512^2)
#define FEAT_BYTE_OFF 66060288u   // T_ELEMS*2
#define FEAT_DWORDS 37748736u     // 262144*144
#define W1F_BYTE_OFF 217055232u   // FEAT_BYTE_OFF + FEAT_DWORDS*4
#define W1F_BYTES 73728u          // 288*128*2
// sort scratch (bytes)
#define KEYS_OFF   217128960u     // u16[262144]  (512 KB)
#define PERM_OFF   217653248u     // u32[262144]  (1 MB)
#define HIST_OFF   218701824u     // u32[65536]   (256 KB)
#define OFFS_OFF   218963968u     // u32[65536]   (256 KB)
#define RSORT_OFF  219226112u     // float4[262144] (4 MB)
#define NEED_SORT  223420416u

// prep_kernel block ranges
#define PB_L0   384       // 6*128*128/256
#define PB_L1   1920      // +6*256*256/256
#define PB_L2   8064      // +6*512*512/256
#define PB_PK   8082      // +4608/256
#define PB_HI   9106      // +262144/256

typedef __attribute__((ext_vector_type(8))) short short8v;   // 8 bf16 = 4 VGPRs
typedef __attribute__((ext_vector_type(4))) float float4v;   // MFMA C/D

// ---------- helpers ----------
__device__ __forceinline__ float bf_lo(uint32_t w) { return __uint_as_float(w << 16); }
__device__ __forceinline__ float bf_hi(uint32_t w) { return __uint_as_float(w & 0xFFFF0000u); }

__device__ __forceinline__ float bf_extract(const uint4& q, int i) {
    uint32_t w = ((const uint32_t*)&q)[i >> 1];
    uint32_t h = (i & 1) ? (w & 0xFFFF0000u) : (w << 16);
    return __uint_as_float(h);
}

__device__ __forceinline__ uint16_t f2bf_rne(float f) {
    uint32_t x = __float_as_uint(f);
    uint32_t r = x + 0x7FFFu + ((x >> 16) & 1u);
    return (uint16_t)(r >> 16);
}

__device__ __forceinline__ float sel4(const float4& p, int i) {
    float r = p.x;
    r = (i == 1) ? p.y : r;
    r = (i == 2) ? p.z : r;
    r = (i == 3) ? p.w : r;
    return r;
}

__device__ __forceinline__ uint32_t morton4(const float4& p) {
    int q0 = min(15, max(0, (int)(p.x * 16.0f)));
    int q1 = min(15, max(0, (int)(p.y * 16.0f)));
    int q2 = min(15, max(0, (int)(p.z * 16.0f)));
    int q3 = min(15, max(0, (int)(p.w * 16.0f)));
    uint32_t key = 0;
    #pragma unroll
    for (int b = 0; b < 4; ++b) {
        key |= (uint32_t)((q0 >> b) & 1) << (4 * b + 0);
        key |= (uint32_t)((q1 >> b) & 1) << (4 * b + 1);
        key |= (uint32_t)((q2 >> b) & 1) << (4 * b + 2);
        key |= (uint32_t)((q3 >> b) & 1) << (4 * b + 3);
    }
    return key;
}

__device__ __forceinline__ void transpose_body(const float* __restrict__ in,
                                               uint16_t* __restrict__ out,
                                               int H, int idx) {
    int hh = H * H;
    int c = idx / hh;
    int rem = idx - c * hh;
    const float* ip = in + (size_t)c * 16 * hh + rem;
    uint32_t words[8];
    #pragma unroll
    for (int j = 0; j < 8; ++j) {
        uint16_t lo = f2bf_rne(ip[(size_t)(2 * j) * hh]);
        uint16_t hi = f2bf_rne(ip[(size_t)(2 * j + 1) * hh]);
        words[j] = (uint32_t)lo | ((uint32_t)hi << 16);
    }
    uint4* op = (uint4*)(out + (size_t)idx * 16);
    op[0] = make_uint4(words[0], words[1], words[2], words[3]);
    op[1] = make_uint4(words[4], words[5], words[6], words[7]);
}

// ---------- merged prep: 3 transposes + w1 pack + morton keys/hist ----------
__global__ __launch_bounds__(256) void prep_kernel(
    const float* __restrict__ g0, const float* __restrict__ g1,
    const float* __restrict__ g2, const float* __restrict__ w1,
    const float4* __restrict__ ray,
    uint16_t* __restrict__ gt, uint16_t* __restrict__ w1f,
    uint16_t* __restrict__ keys, uint32_t* __restrict__ hist) {
    int b = blockIdx.x;
    int tid = threadIdx.x;
    if (b < PB_L0) {
        transpose_body(g0, gt + T0_OFF, 128, b * 256 + tid);
    } else if (b < PB_L1) {
        transpose_body(g1, gt + T1_OFF, 256, (b - PB_L0) * 256 + tid);
    } else if (b < PB_L2) {
        transpose_body(g2, gt + T2_OFF, 512, (b - PB_L1) * 256 + tid);
    } else if (b < PB_PK) {
        int t = (b - PB_L2) * 256 + tid;      // < 4608
        int lane = t & 63;
        int fr = t >> 6;
        int ct = fr / 9;
        int kc = fr - ct * 9;
        int col = ct * 16 + (lane & 15);
        int krow = kc * 32 + (lane >> 4) * 8;
        uint32_t od[4];
        #pragma unroll
        for (int j = 0; j < 4; ++j) {
            uint16_t lo = f2bf_rne(w1[(size_t)(krow + 2 * j) * 128 + col]);
            uint16_t hi = f2bf_rne(w1[(size_t)(krow + 2 * j + 1) * 128 + col]);
            od[j] = (uint32_t)lo | ((uint32_t)hi << 16);
        }
        *(uint4*)(w1f + (size_t)t * 8) = make_uint4(od[0], od[1], od[2], od[3]);
    } else {
        int r = (b - PB_PK) * 256 + tid;
        float4 p = ray[r];
        uint32_t key = morton4(p);
        keys[r] = (uint16_t)key;
        atomicAdd(&hist[key], 1u);
    }
}

// ---------- sort kernels ----------
__global__ void scanA_kernel(const uint32_t* __restrict__ hist, uint32_t* __restrict__ bsum) {
    __shared__ uint32_t s[256];
    int t = threadIdx.x;
    s[t] = hist[blockIdx.x * 256 + t];
    __syncthreads();
    for (int d = 128; d > 0; d >>= 1) {
        if (t < d) s[t] += s[t + d];
        __syncthreads();
    }
    if (t == 0) bsum[blockIdx.x] = s[0];
}

__global__ void scanB_kernel(uint32_t* __restrict__ bsum) {
    __shared__ uint32_t s[256];
    int t = threadIdx.x;
    uint32_t v = bsum[t];
    s[t] = v;
    __syncthreads();
    for (int d = 1; d < 256; d <<= 1) {
        uint32_t x = (t >= d) ? s[t - d] : 0;
        __syncthreads();
        s[t] += x;
        __syncthreads();
    }
    bsum[t] = s[t] - v;   // exclusive
}

__global__ void scanC_kernel(const uint32_t* __restrict__ hist,
                             const uint32_t* __restrict__ bsum,
                             uint32_t* __restrict__ offs) {
    __shared__ uint32_t s[256];
    int t = threadIdx.x, b = blockIdx.x;
    uint32_t v = hist[b * 256 + t];
    s[t] = v;
    __syncthreads();
    for (int d = 1; d < 256; d <<= 1) {
        uint32_t x = (t >= d) ? s[t - d] : 0;
        __syncthreads();
        s[t] += x;
        __syncthreads();
    }
    offs[b * 256 + t] = bsum[b] + s[t] - v;
}

__global__ void scatter_kernel(const float4* __restrict__ ray,
                               const uint16_t* __restrict__ keys,
                               uint32_t* __restrict__ offs,
                               uint32_t* __restrict__ perm,
                               float4* __restrict__ ray_sorted) {
    int r = blockIdx.x * 256 + threadIdx.x;
    uint32_t key = keys[r];
    uint32_t pos = atomicAdd(&offs[key], 1u);
    perm[pos] = (uint32_t)r;
    ray_sorted[pos] = ray[r];
}

// ---------- FUSED gather + MFMA MLP: 32 sorted rays per block ----------
// LDS feats row stride 148 dwords; s_h (stride 132 floats) aliases s_feats after barrier.
__global__ __launch_bounds__(256, 7) void fused_gmlp_kernel(
    const float4* __restrict__ rsort, const uint16_t* __restrict__ gt,
    const uint16_t* __restrict__ w1f, const float* __restrict__ bias1,
    const float* __restrict__ w2, const float* __restrict__ bias2,
    const uint32_t* __restrict__ perm, float* __restrict__ out) {
    __shared__ uint32_t s_feats[32 * 148];   // 18944 B
    __shared__ float s_w2[384];
    __shared__ float4 s_ray[32];

    int tid = threadIdx.x;
    int wvid = tid >> 6;
    int lane = tid & 63;
    // XCD-chunked bijective swizzle: 8192 blocks = 8 * 1024
    int swz = ((blockIdx.x & 7) << 10) + (blockIdx.x >> 3);
    int r0 = swz << 5;

    if (tid < 32) s_ray[tid] = rsort[r0 + tid];
    s_w2[tid] = w2[tid];
    if (tid < 128) s_w2[256 + tid] = w2[256 + tid];
    __syncthreads();

    // ---- phase A: 9 slots of 64 tasks; wave wvid handles slots wvid, wvid+4, wvid+8 ----
    for (int s = wvid; s < 9; s += 4) {
        int interp = 2 * s + (lane >> 5);
        int r = lane & 31;
        int level = (interp >= 12) ? 2 : ((interp >= 6) ? 1 : 0);
        int comb = interp - level * 6;
        int H = 128 << level;
        float4 p = s_ray[r];
        int c0 = (0x211000 >> (4 * comb)) & 0xF;   // 0,0,0,1,1,2
        int c1 = (0x332321 >> (4 * comb)) & 0xF;   // 1,2,3,2,3,3
        float u = sel4(p, c0) * (float)(H - 1);
        float v = sel4(p, c1) * (float)(H - 1);
        float u0f = fminf(fmaxf(floorf(u), 0.0f), (float)(H - 2));
        float v0f = fminf(fmaxf(floorf(v), 0.0f), (float)(H - 2));
        float fu = u - u0f, fv = v - v0f;
        int u0 = (int)u0f, v0 = (int)v0f;

        uint32_t lvl_off = (level == 0) ? T0_OFF : ((level == 1) ? T1_OFF : T2_OFF);
        const uint16_t* gp0 = gt + lvl_off + (((size_t)comb * H + u0) * H + v0) * 16;
        const uint4* q0 = (const uint4*)gp0;                       // row u0: (v0, v0+1)
        const uint4* q1 = (const uint4*)(gp0 + (size_t)16 * H);    // row u0+1
        uint4 a0 = q0[0], a1 = q0[1], a2 = q0[2], a3 = q0[3];
        uint4 b0 = q1[0], b1 = q1[1], b2 = q1[2], b3 = q1[3];

        uint32_t c00[8], c01[8], c10[8], c11[8];
        #pragma unroll
        for (int j = 0; j < 4; ++j) {
            c00[j] = ((const uint32_t*)&a0)[j];  c00[j + 4] = ((const uint32_t*)&a1)[j];
            c01[j] = ((const uint32_t*)&a2)[j];  c01[j + 4] = ((const uint32_t*)&a3)[j];
            c10[j] = ((const uint32_t*)&b0)[j];  c10[j + 4] = ((const uint32_t*)&b1)[j];
            c11[j] = ((const uint32_t*)&b2)[j];  c11[j + 4] = ((const uint32_t*)&b3)[j];
        }

        float w00 = (1.0f - fu) * (1.0f - fv);
        float w01 = (1.0f - fu) * fv;
        float w10 = fu * (1.0f - fv);
        float w11 = fu * fv;

        uint32_t od[8];
        #pragma unroll
        for (int j = 0; j < 8; ++j) {
            float lo = w00 * bf_lo(c00[j]) + w01 * bf_lo(c01[j]) +
                       w10 * bf_lo(c10[j]) + w11 * bf_lo(c11[j]);
            float hi = w00 * bf_hi(c00[j]) + w01 * bf_hi(c01[j]) +
                       w10 * bf_hi(c10[j]) + w11 * bf_hi(c11[j]);
            od[j] = (uint32_t)f2bf_rne(lo) | ((uint32_t)f2bf_rne(hi) << 16);
        }
        uint32_t* op = &s_feats[r * 148 + interp * 8];
        *(uint4*)op       = make_uint4(od[0], od[1], od[2], od[3]);
        *(uint4*)(op + 4) = make_uint4(od[4], od[5], od[6], od[7]);
    }
    __syncthreads();

    // ---- phase B: MFMA (two passes over ct to cap VGPR) ----
    float b1c0 = bias1[wvid * 32 + (lane & 15)];
    float b1c1 = bias1[wvid * 32 + 16 + (lane & 15)];
    int lg = lane >> 4;
    const uint32_t* arow = &s_feats[(lane & 15) * 148 + lg * 4];

    float4v acc00, acc10, acc01, acc11;
    {
        short8v bfrA[9];
        #pragma unroll
        for (int kc = 0; kc < 9; ++kc)
            bfrA[kc] = *(const short8v*)(w1f + (((size_t)((wvid * 2) * 9 + kc)) * 64 + lane) * 8);
        #pragma unroll
        for (int j = 0; j < 4; ++j) { acc00[j] = b1c0; acc10[j] = b1c0; }
        #pragma unroll
        for (int kc = 0; kc < 9; ++kc) {
            short8v a0 = *(const short8v*)(arow + kc * 16);
            short8v a1 = *(const short8v*)(arow + 16 * 148 + kc * 16);
            acc00 = __builtin_amdgcn_mfma_f32_16x16x32_bf16(a0, bfrA[kc], acc00, 0, 0, 0);
            acc10 = __builtin_amdgcn_mfma_f32_16x16x32_bf16(a1, bfrA[kc], acc10, 0, 0, 0);
        }
    }
    {
        short8v bfrB[9];
        #pragma unroll
        for (int kc = 0; kc < 9; ++kc)
            bfrB[kc] = *(const short8v*)(w1f + (((size_t)((wvid * 2 + 1) * 9 + kc)) * 64 + lane) * 8);
        #pragma unroll
        for (int j = 0; j < 4; ++j) { acc01[j] = b1c1; acc11[j] = b1c1; }
        #pragma unroll
        for (int kc = 0; kc < 9; ++kc) {
            short8v a0 = *(const short8v*)(arow + kc * 16);
            short8v a1 = *(const short8v*)(arow + 16 * 148 + kc * 16);
            acc01 = __builtin_amdgcn_mfma_f32_16x16x32_bf16(a0, bfrB[kc], acc01, 0, 0, 0);
            acc11 = __builtin_amdgcn_mfma_f32_16x16x32_bf16(a1, bfrB[kc], acc11, 0, 0, 0);
        }
    }
    __syncthreads();   // all s_feats reads done; safe to alias as s_h

    float* s_h = (float*)s_feats;   // [32][132]
    {
        int c0 = wvid * 32 + (lane & 15);
        int rb = lg * 4;
        #pragma unroll
        for (int j = 0; j < 4; ++j) {
            s_h[(rb + j) * 132 + c0]            = fmaxf(acc00[j], 0.0f);
            s_h[(rb + j) * 132 + c0 + 16]       = fmaxf(acc01[j], 0.0f);
            s_h[(rb + j + 16) * 132 + c0]       = fmaxf(acc10[j], 0.0f);
            s_h[(rb + j + 16) * 132 + c0 + 16]  = fmaxf(acc11[j], 0.0f);
        }
    }
    __syncthreads();

    // ---- layer 2 + sigmoid + scatter ----
    int ray = tid >> 3;
    int jg = tid & 7;
    int j0 = jg * 16;
    float p0 = 0.f, p1 = 0.f, p2 = 0.f;
    #pragma unroll
    for (int qq = 0; qq < 4; ++qq) {
        float4 hv = *(const float4*)&s_h[ray * 132 + j0 + qq * 4];
        const float* w2a = &s_w2[(j0 + qq * 4) * 3];
        p0 += hv.x * w2a[0] + hv.y * w2a[3] + hv.z * w2a[6] + hv.w * w2a[9];
        p1 += hv.x * w2a[1] + hv.y * w2a[4] + hv.z * w2a[7] + hv.w * w2a[10];
        p2 += hv.x * w2a[2] + hv.y * w2a[5] + hv.z * w2a[8] + hv.w * w2a[11];
    }
    p0 += __shfl_xor(p0, 1); p0 += __shfl_xor(p0, 2); p0 += __shfl_xor(p0, 4);
    p1 += __shfl_xor(p1, 1); p1 += __shfl_xor(p1, 2); p1 += __shfl_xor(p1, 4);
    p2 += __shfl_xor(p2, 1); p2 += __shfl_xor(p2, 2); p2 += __shfl_xor(p2, 4);

    if (jg == 0) {
        int orig = (int)perm[r0 + ray];
        float o0 = 1.0f / (1.0f + expf(-(p0 + bias2[0])));
        float o1 = 1.0f / (1.0f + expf(-(p1 + bias2[1])));
        float o2 = 1.0f / (1.0f + expf(-(p2 + bias2[2])));
        float* op = out + (size_t)orig * 3;
        op[0] = o0; op[1] = o1; op[2] = o2;
    }
}

// ---------- tier-2 fallback: transpose + gather_t + mfma_mlp ----------
__global__ void transpose_kernel(const float* __restrict__ in,
                                 __hip_bfloat16* __restrict__ out, int H) {
    int idx = blockIdx.x * blockDim.x + threadIdx.x;
    if (idx >= 6 * H * H) return;
    transpose_body(in, (uint16_t*)out, H, idx);
}

__global__ void w1_pack_kernel(const float* __restrict__ w1, uint16_t* __restrict__ w1f) {
    int t = blockIdx.x * 64 + threadIdx.x;
    if (t >= 8 * 9 * 64) return;
    int lane = t & 63;
    int fr = t >> 6;
    int ct = fr / 9;
    int kc = fr - ct * 9;
    int col = ct * 16 + (lane & 15);
    int krow = kc * 32 + (lane >> 4) * 8;
    uint32_t od[4];
    #pragma unroll
    for (int j = 0; j < 4; ++j) {
        uint16_t lo = f2bf_rne(w1[(size_t)(krow + 2 * j) * 128 + col]);
        uint16_t hi = f2bf_rne(w1[(size_t)(krow + 2 * j + 1) * 128 + col]);
        od[j] = (uint32_t)lo | ((uint32_t)hi << 16);
    }
    *(uint4*)(w1f + (size_t)t * 8) = make_uint4(od[0], od[1], od[2], od[3]);
}

__global__ __launch_bounds__(256, 8) void gather_t_kernel(
    const float4* __restrict__ ray, const uint16_t* __restrict__ gt,
    uint32_t* __restrict__ featsT) {
    int lb = (blockIdx.x & 7) * 2304 + (blockIdx.x >> 3);
    int interp = lb >> 10;
    int r = ((lb & 1023) << 8) + threadIdx.x;
    int level = interp / 6;
    int comb = interp - level * 6;
    int H = 128 << level;

    float4 p = ray[r];
    int c0 = (0x211000 >> (4 * comb)) & 0xF;
    int c1 = (0x332321 >> (4 * comb)) & 0xF;
    float u = sel4(p, c0) * (float)(H - 1);
    float v = sel4(p, c1) * (float)(H - 1);
    float u0f = fminf(fmaxf(floorf(u), 0.0f), (float)(H - 2));
    float v0f = fminf(fmaxf(floorf(v), 0.0f), (float)(H - 2));
    float wu = u - u0f, wv = v - v0f;
    int u0 = (int)u0f, v0 = (int)v0f;

    uint32_t lvl_off = (level == 0) ? T0_OFF : ((level == 1) ? T1_OFF : T2_OFF);
    const uint16_t* gp0 = gt + lvl_off + (((size_t)comb * H + u0) * H + v0) * 16;
    const uint4* q0 = (const uint4*)gp0;
    const uint4* q1 = (const uint4*)(gp0 + (size_t)16 * H);
    uint4 a0 = q0[0], a1 = q0[1], a2 = q0[2], a3 = q0[3];
    uint4 b0 = q1[0], b1 = q1[1], b2 = q1[2], b3 = q1[3];

    uint32_t c00[8], c01[8], c10[8], c11[8];
    #pragma unroll
    for (int j = 0; j < 4; ++j) {
        c00[j] = ((const uint32_t*)&a0)[j];  c00[j + 4] = ((const uint32_t*)&a1)[j];
        c01[j] = ((const uint32_t*)&a2)[j];  c01[j + 4] = ((const uint32_t*)&a3)[j];
        c10[j] = ((const uint32_t*)&b0)[j];  c10[j + 4] = ((const uint32_t*)&b1)[j];
        c11[j] = ((const uint32_t*)&b2)[j];  c11[j + 4] = ((const uint32_t*)&b3)[j];
    }

    float w00 = (1.0f - wu) * (1.0f - wv);
    float w01 = (1.0f - wu) * wv;
    float w10 = wu * (1.0f - wv);
    float w11 = wu * wv;

    uint32_t od[8];
    #pragma unroll
    for (int j = 0; j < 8; ++j) {
        float lo = w00 * bf_lo(c00[j]) + w01 * bf_lo(c01[j]) +
                   w10 * bf_lo(c10[j]) + w11 * bf_lo(c11[j]);
        float hi = w00 * bf_hi(c00[j]) + w01 * bf_hi(c01[j]) +
                   w10 * bf_hi(c10[j]) + w11 * bf_hi(c11[j]);
        od[j] = (uint32_t)f2bf_rne(lo) | ((uint32_t)f2bf_rne(hi) << 16);
    }

    uint4* op = (uint4*)(featsT + ((size_t)interp * N_RAYS + r) * 8);
    op[0] = make_uint4(od[0], od[1], od[2], od[3]);
    op[1] = make_uint4(od[4], od[5], od[6], od[7]);
}

__global__ __launch_bounds__(256, 2) void mfma_mlp_kernel(
    const uint16_t* __restrict__ featsT,
    const uint16_t* __restrict__ w1f,
    const float* __restrict__ bias1,
    const float* __restrict__ w2, const float* __restrict__ bias2,
    const uint32_t* __restrict__ perm,
    float* __restrict__ out, int tiles_per_block) {
    __shared__ float s_h[32][132];

    int tid = threadIdx.x;
    int wv = tid >> 6;
    int lane = tid & 63;

    short8v bfr[2][9];
    #pragma unroll
    for (int ctl = 0; ctl < 2; ++ctl) {
        int ct = wv * 2 + ctl;
        #pragma unroll
        for (int kc = 0; kc < 9; ++kc)
            bfr[ctl][kc] = *(const short8v*)(w1f + (((size_t)(ct * 9 + kc)) * 64 + lane) * 8);
    }
    float b1c0 = bias1[wv * 32 + (lane & 15)];
    float b1c1 = bias1[wv * 32 + 16 + (lane & 15)];

    int jg = tid & 7;
    int j0 = jg * 16;
    float w2r0[16], w2r1[16], w2r2[16];
    #pragma unroll
    for (int jj = 0; jj < 16; ++jj) {
        const float* w2p = w2 + (size_t)(j0 + jj) * 3;
        w2r0[jj] = w2p[0]; w2r1[jj] = w2p[1]; w2r2[jj] = w2p[2];
    }
    float bb0 = bias2[0], bb1 = bias2[1], bb2 = bias2[2];

    int lg = lane >> 4;
    int half8 = (lg & 1) * 8;
    int ipo = lg >> 1;

    for (int it = 0; it < tiles_per_block; ++it) {
        int tile = blockIdx.x * tiles_per_block + it;
        int r0 = tile * 32;
        int rA = r0 + (lane & 15);

        short8v af[18];
        #pragma unroll
        for (int kc = 0; kc < 9; ++kc) {
            size_t base = ((size_t)(2 * kc + ipo) * N_RAYS + rA) * 16 + half8;
            af[kc]     = *(const short8v*)(featsT + base);
            af[9 + kc] = *(const short8v*)(featsT + base + 256);
        }

        float4v acc00, acc01, acc10, acc11;
        #pragma unroll
        for (int j = 0; j < 4; ++j) { acc00[j] = b1c0; acc01[j] = b1c1; acc10[j] = b1c0; acc11[j] = b1c1; }

        #pragma unroll
        for (int kc = 0; kc < 9; ++kc) {
            acc00 = __builtin_amdgcn_mfma_f32_16x16x32_bf16(af[kc],     bfr[0][kc], acc00, 0, 0, 0);
            acc01 = __builtin_amdgcn_mfma_f32_16x16x32_bf16(af[kc],     bfr[1][kc], acc01, 0, 0, 0);
            acc10 = __builtin_amdgcn_mfma_f32_16x16x32_bf16(af[9 + kc], bfr[0][kc], acc10, 0, 0, 0);
            acc11 = __builtin_amdgcn_mfma_f32_16x16x32_bf16(af[9 + kc], bfr[1][kc], acc11, 0, 0, 0);
        }

        __syncthreads();
        {
            int c0 = wv * 32 + (lane & 15);
            int rb = (lane >> 4) * 4;
            #pragma unroll
            for (int j = 0; j < 4; ++j) {
                s_h[rb + j][c0]           = fmaxf(acc00[j], 0.0f);
                s_h[rb + j][c0 + 16]      = fmaxf(acc01[j], 0.0f);
                s_h[rb + j + 16][c0]      = fmaxf(acc10[j], 0.0f);
                s_h[rb + j + 16][c0 + 16] = fmaxf(acc11[j], 0.0f);
            }
        }
        __syncthreads();

        int ray = tid >> 3;
        float p0 = 0.f, p1 = 0.f, p2 = 0.f;
        #pragma unroll
        for (int qq = 0; qq < 4; ++qq) {
            float4 hv = *(const float4*)&s_h[ray][j0 + qq * 4];
            float h0 = hv.x, h1 = hv.y, h2 = hv.z, h3 = hv.w;
            p0 += h0 * w2r0[qq * 4] + h1 * w2r0[qq * 4 + 1] + h2 * w2r0[qq * 4 + 2] + h3 * w2r0[qq * 4 + 3];
            p1 += h0 * w2r1[qq * 4] + h1 * w2r1[qq * 4 + 1] + h2 * w2r1[qq * 4 + 2] + h3 * w2r1[qq * 4 + 3];
            p2 += h0 * w2r2[qq * 4] + h1 * w2r2[qq * 4 + 1] + h2 * w2r2[qq * 4 + 2] + h3 * w2r2[qq * 4 + 3];
        }
        p0 += __shfl_xor(p0, 1); p0 += __shfl_xor(p0, 2); p0 += __shfl_xor(p0, 4);
        p1 += __shfl_xor(p1, 1); p1 += __shfl_xor(p1, 2); p1 += __shfl_xor(p1, 4);
        p2 += __shfl_xor(p2, 1); p2 += __shfl_xor(p2, 2); p2 += __shfl_xor(p2, 4);

        if (jg == 0) {
            int orig = perm ? (int)perm[r0 + ray] : (r0 + ray);
            float o0 = 1.0f / (1.0f + expf(-(p0 + bb0)));
            float o1 = 1.0f / (1.0f + expf(-(p1 + bb1)));
            float o2 = 1.0f / (1.0f + expf(-(p2 + bb2)));
            float* op = out + (size_t)orig * 3;
            op[0] = o0; op[1] = o1; op[2] = o2;
        }
    }
}

// ---------- tier-3/4 fallback fused kernel (small ws) ----------
template <bool USE_T>
__global__ __launch_bounds__(THREADS) void fused_kernel(
    const float4* __restrict__ ray,
    const float* __restrict__ g0, const float* __restrict__ g1,
    const float* __restrict__ g2,
    const __hip_bfloat16* __restrict__ gt,
    const float* __restrict__ weights1, const float* __restrict__ bias1,
    const float* __restrict__ weights2, const float* __restrict__ bias2,
    float* __restrict__ out) {
    __shared__ float4 s_ray[NR];
    __shared__ float s_feats[NR][FSTRIDE];

    int tid = threadIdx.x;
    int rbase = blockIdx.x * NR;
    if (tid < NR) s_ray[tid] = ray[rbase + tid];
    __syncthreads();

    for (int t = tid; t < NR * 36; t += THREADS) {
        int r = t / 36;
        int rem = t - r * 36;
        int interp = rem >> 1;
        int half = rem & 1;
        int level = (interp >= 12) ? 2 : ((interp >= 6) ? 1 : 0);
        int comb = interp - level * 6;
        int H = 128 << level;
        float4 p = s_ray[r];
        int c0 = (0x211000 >> (4 * comb)) & 0xF;
        int c1 = (0x332321 >> (4 * comb)) & 0xF;
        float u = sel4(p, c0) * (float)(H - 1);
        float v = sel4(p, c1) * (float)(H - 1);
        float u0f = fminf(fmaxf(floorf(u), 0.0f), (float)(H - 2));
        float v0f = fminf(fmaxf(floorf(v), 0.0f), (float)(H - 2));
        float wu = u - u0f, wv = v - v0f;
        int u0 = (int)u0f, v0 = (int)v0f;
        float w00 = (1.0f - wu) * (1.0f - wv);
        float w01 = (1.0f - wu) * wv;
        float w10 = wu * (1.0f - wv);
        float w11 = wu * wv;
        float f[8];
        if (USE_T) {
            uint32_t lvl_off = (level == 0) ? T0_OFF : ((level == 1) ? T1_OFF : T2_OFF);
            const uint16_t* gp = (const uint16_t*)gt + lvl_off +
                                 (((size_t)comb * H + u0) * H + v0) * 16 + half * 8;
            uint4 a00 = *(const uint4*)gp;
            uint4 a01 = *(const uint4*)(gp + 16);
            uint4 a10 = *(const uint4*)(gp + (size_t)16 * H);
            uint4 a11 = *(const uint4*)(gp + (size_t)16 * H + 16);
            #pragma unroll
            for (int i = 0; i < 8; ++i) {
                f[i] = w00 * bf_extract(a00, i) + w01 * bf_extract(a01, i) +
                       w10 * bf_extract(a10, i) + w11 * bf_extract(a11, i);
            }
        } else {
            const float* gp = (level == 0) ? g0 : ((level == 1) ? g1 : g2);
            const float* base = gp + ((size_t)(comb * 16 + half * 8) * H + u0) * H + v0;
            #pragma unroll
            for (int i = 0; i < 8; ++i) {
                const float* q = base + (size_t)i * H * H;
                float a00 = q[0], a01 = q[1], a10 = q[H], a11 = q[H + 1];
                f[i] = w00 * a00 + w01 * a01 + w10 * a10 + w11 * a11;
            }
        }
        int fo = interp * 16 + half * 8;
        float* fp = &s_feats[r][fo];
        #pragma unroll
        for (int i = 0; i < 8; ++i) fp[i] = f[i];
    }
    __syncthreads();

    int r = tid >> 3;
    int jg = tid & 7;
    int j0 = jg * 16;
    float acc[16];
    #pragma unroll
    for (int jj = 0; jj < 16; ++jj) acc[jj] = bias1[j0 + jj];

    const float* wp = weights1 + j0;
    for (int k = 0; k < 288; k += 4) {
        float4 fv = *(const float4*)&s_feats[r][k];
        #pragma unroll
        for (int kk = 0; kk < 4; ++kk) {
            const float4* wr = (const float4*)(wp + (size_t)(k + kk) * 128);
            float fk = (kk == 0) ? fv.x : ((kk == 1) ? fv.y : ((kk == 2) ? fv.z : fv.w));
            float4 wa = wr[0], wb = wr[1], wc = wr[2], wd = wr[3];
            acc[0]  += fk * wa.x; acc[1]  += fk * wa.y; acc[2]  += fk * wa.z; acc[3]  += fk * wa.w;
            acc[4]  += fk * wb.x; acc[5]  += fk * wb.y; acc[6]  += fk * wb.z; acc[7]  += fk * wb.w;
            acc[8]  += fk * wc.x; acc[9]  += fk * wc.y; acc[10] += fk * wc.z; acc[11] += fk * wc.w;
            acc[12] += fk * wd.x; acc[13] += fk * wd.y; acc[14] += fk * wd.z; acc[15] += fk * wd.w;
        }
    }

    float p0 = 0.f, p1 = 0.f, p2 = 0.f;
    #pragma unroll
    for (int jj = 0; jj < 16; ++jj) {
        float h = fmaxf(acc[jj], 0.0f);
        const float* w2r = weights2 + (size_t)(j0 + jj) * 3;
        p0 += h * w2r[0];
        p1 += h * w2r[1];
        p2 += h * w2r[2];
    }
    p0 += __shfl_xor(p0, 1); p0 += __shfl_xor(p0, 2); p0 += __shfl_xor(p0, 4);
    p1 += __shfl_xor(p1, 1); p1 += __shfl_xor(p1, 2); p1 += __shfl_xor(p1, 4);
    p2 += __shfl_xor(p2, 1); p2 += __shfl_xor(p2, 2); p2 += __shfl_xor(p2, 4);

    if (jg == 0) {
        float o0 = 1.0f / (1.0f + expf(-(p0 + bias2[0])));
        float o1 = 1.0f / (1.0f + expf(-(p1 + bias2[1])));
        float o2 = 1.0f / (1.0f + expf(-(p2 + bias2[2])));
        float* op = out + (size_t)(rbase + r) * 3;
        op[0] = o0; op[1] = o1; op[2] = o2;
    }
}

extern "C" void kernel_launch(void* const* d_in, const int* in_sizes, int n_in,
                              void* d_out, int out_size, void* d_ws, size_t ws_size,
                              hipStream_t stream) {
    const float4* ray = (const float4*)d_in[0];
    const float* g0 = (const float*)d_in[1];
    const float* g1 = (const float*)d_in[2];
    const float* g2 = (const float*)d_in[3];
    const float* w1 = (const float*)d_in[4];
    const float* b1 = (const float*)d_in[5];
    const float* w2 = (const float*)d_in[6];
    const float* b2 = (const float*)d_in[7];
    float* out = (float*)d_out;

    const size_t T_BYTES = (size_t)T_ELEMS * 2;
    const size_t NEED = (size_t)W1F_BYTE_OFF + W1F_BYTES;

    if (ws_size >= (size_t)NEED_SORT) {
        char* ws = (char*)d_ws;
        __hip_bfloat16* wsb = (__hip_bfloat16*)d_ws;
        uint32_t* bsum  = (uint32_t*)(ws + FEAT_BYTE_OFF);   // scratch (feat arena unused)
        uint16_t* w1f  = (uint16_t*)(ws + W1F_BYTE_OFF);
        uint16_t* keys = (uint16_t*)(ws + KEYS_OFF);
        uint32_t* perm = (uint32_t*)(ws + PERM_OFF);
        uint32_t* hist = (uint32_t*)(ws + HIST_OFF);
        uint32_t* offs = (uint32_t*)(ws + OFFS_OFF);
        float4* rsort  = (float4*)(ws + RSORT_OFF);

        hipMemsetAsync(hist, 0, 65536 * 4, stream);
        prep_kernel<<<PB_HI, 256, 0, stream>>>(
            g0, g1, g2, w1, ray, (uint16_t*)wsb, w1f, keys, hist);
        scanA_kernel<<<256, 256, 0, stream>>>(hist, bsum);
        scanB_kernel<<<1, 256, 0, stream>>>(bsum);
        scanC_kernel<<<256, 256, 0, stream>>>(hist, bsum, offs);
        scatter_kernel<<<N_RAYS / 256, 256, 0, stream>>>(ray, keys, offs, perm, rsort);
        fused_gmlp_kernel<<<N_RAYS / 32, 256, 0, stream>>>(
            rsort, (const uint16_t*)wsb, w1f, b1, w2, b2, perm, out);
    } else if (ws_size >= NEED) {
        __hip_bfloat16* wsb = (__hip_bfloat16*)d_ws;
        transpose_kernel<<<(6 * 128 * 128 + 255) / 256, 256, 0, stream>>>(g0, wsb + T0_OFF, 128);
        transpose_kernel<<<(6 * 256 * 256 + 255) / 256, 256, 0, stream>>>(g1, wsb + T1_OFF, 256);
        transpose_kernel<<<(6 * 512 * 512 + 255) / 256, 256, 0, stream>>>(g2, wsb + T2_OFF, 512);
        uint32_t* feats = (uint32_t*)((char*)d_ws + FEAT_BYTE_OFF);
        uint16_t* w1f = (uint16_t*)((char*)d_ws + W1F_BYTE_OFF);
        w1_pack_kernel<<<72, 64, 0, stream>>>(w1, w1f);
        gather_t_kernel<<<18432, 256, 0, stream>>>(ray, (const uint16_t*)wsb, feats);
        const int TILES_PER_BLOCK = 4;
        int nblk = N_RAYS / 32 / TILES_PER_BLOCK;
        mfma_mlp_kernel<<<nblk, 256, 0, stream>>>(
            (const uint16_t*)feats, w1f, b1, w2, b2, nullptr, out, TILES_PER_BLOCK);
    } else if (ws_size >= T_BYTES) {
        __hip_bfloat16* wsb = (__hip_bfloat16*)d_ws;
        transpose_kernel<<<(6 * 128 * 128 + 255) / 256, 256, 0, stream>>>(g0, wsb + T0_OFF, 128);
        transpose_kernel<<<(6 * 256 * 256 + 255) / 256, 256, 0, stream>>>(g1, wsb + T1_OFF, 256);
        transpose_kernel<<<(6 * 512 * 512 + 255) / 256, 256, 0, stream>>>(g2, wsb + T2_OFF, 512);
        fused_kernel<true><<<N_RAYS / NR, THREADS, 0, stream>>>(
            ray, g0, g1, g2, wsb, w1, b1, w2, b2, out);
    } else {
        fused_kernel<false><<<N_RAYS / NR, THREADS, 0, stream>>>(
            ray, g0, g1, g2, nullptr, w1, b1, w2, b2, out);
    }
}

// Round 9
// 182.057 us; speedup vs baseline: 2.2010x; 1.0684x over previous
//
#include <hip/hip_runtime.h>
#include <hip/hip_bf16.h>
#include <cstdint>
#include <cstddef>

#define N_RAYS 262144
#define NR 32
#define THREADS 256
#define FSTRIDE 292

// offsets in uint16 elements into the transposed-grid arena
#define T0_OFF 0u
#define T1_OFF 1572864u      // 6*128*128*16
#define T2_OFF 7864320u      // + 6*256*256*16
#define T_ELEMS 33030144u    // 6*16*(128^2+256^2+512^2)
#define FEAT_BYTE_OFF 66060288u   // T_ELEMS*2
#define FEAT_DWORDS 37748736u     // 262144*144
#define W1F_BYTE_OFF 217055232u   // FEAT_BYTE_OFF + FEAT_DWORDS*4
#define W1F_BYTES 73728u          // 288*128*2
// sort scratch (bytes)
#define KEYS_OFF   217128960u     // u16[262144]  (512 KB)
#define PERM_OFF   217653248u     // u32[262144]  (1 MB)
#define HIST_OFF   218701824u     // u32[65536]   (256 KB)
#define OFFS_OFF   218963968u     // u32[65536]   (256 KB)
#define RSORT_OFF  219226112u     // float4[262144] (4 MB)
#define NEED_SORT  223420416u

// prep_kernel block ranges
#define PB_L0   384       // 6*128*128/256
#define PB_L1   1920      // +6*256*256/256
#define PB_L2   8064      // +6*512*512/256
#define PB_PK   8082      // +4608/256
#define PB_HI   9106      // +262144/256

typedef __attribute__((ext_vector_type(8))) short short8v;   // 8 bf16 = 4 VGPRs
typedef __attribute__((ext_vector_type(4))) float float4v;   // MFMA C/D

// ---------- helpers ----------
__device__ __forceinline__ float bf_lo(uint32_t w) { return __uint_as_float(w << 16); }
__device__ __forceinline__ float bf_hi(uint32_t w) { return __uint_as_float(w & 0xFFFF0000u); }

__device__ __forceinline__ float bf_extract(const uint4& q, int i) {
    uint32_t w = ((const uint32_t*)&q)[i >> 1];
    uint32_t h = (i & 1) ? (w & 0xFFFF0000u) : (w << 16);
    return __uint_as_float(h);
}

__device__ __forceinline__ uint16_t f2bf_rne(float f) {
    uint32_t x = __float_as_uint(f);
    uint32_t r = x + 0x7FFFu + ((x >> 16) & 1u);
    return (uint16_t)(r >> 16);
}

__device__ __forceinline__ float sel4(const float4& p, int i) {
    float r = p.x;
    r = (i == 1) ? p.y : r;
    r = (i == 2) ? p.z : r;
    r = (i == 3) ? p.w : r;
    return r;
}

__device__ __forceinline__ uint32_t morton4(const float4& p) {
    int q0 = min(15, max(0, (int)(p.x * 16.0f)));
    int q1 = min(15, max(0, (int)(p.y * 16.0f)));
    int q2 = min(15, max(0, (int)(p.z * 16.0f)));
    int q3 = min(15, max(0, (int)(p.w * 16.0f)));
    uint32_t key = 0;
    #pragma unroll
    for (int b = 0; b < 4; ++b) {
        key |= (uint32_t)((q0 >> b) & 1) << (4 * b + 0);
        key |= (uint32_t)((q1 >> b) & 1) << (4 * b + 1);
        key |= (uint32_t)((q2 >> b) & 1) << (4 * b + 2);
        key |= (uint32_t)((q3 >> b) & 1) << (4 * b + 3);
    }
    return key;
}

__device__ __forceinline__ void transpose_body(const float* __restrict__ in,
                                               uint16_t* __restrict__ out,
                                               int H, int idx) {
    int hh = H * H;
    int c = idx / hh;
    int rem = idx - c * hh;
    const float* ip = in + (size_t)c * 16 * hh + rem;
    uint32_t words[8];
    #pragma unroll
    for (int j = 0; j < 8; ++j) {
        uint16_t lo = f2bf_rne(ip[(size_t)(2 * j) * hh]);
        uint16_t hi = f2bf_rne(ip[(size_t)(2 * j + 1) * hh]);
        words[j] = (uint32_t)lo | ((uint32_t)hi << 16);
    }
    uint4* op = (uint4*)(out + (size_t)idx * 16);
    op[0] = make_uint4(words[0], words[1], words[2], words[3]);
    op[1] = make_uint4(words[4], words[5], words[6], words[7]);
}

// ---------- merged prep: 3 transposes + w1 pack + morton keys/hist ----------
__global__ __launch_bounds__(256) void prep_kernel(
    const float* __restrict__ g0, const float* __restrict__ g1,
    const float* __restrict__ g2, const float* __restrict__ w1,
    const float4* __restrict__ ray,
    uint16_t* __restrict__ gt, uint16_t* __restrict__ w1f,
    uint16_t* __restrict__ keys, uint32_t* __restrict__ hist) {
    int b = blockIdx.x;
    int tid = threadIdx.x;
    if (b < PB_L0) {
        transpose_body(g0, gt + T0_OFF, 128, b * 256 + tid);
    } else if (b < PB_L1) {
        transpose_body(g1, gt + T1_OFF, 256, (b - PB_L0) * 256 + tid);
    } else if (b < PB_L2) {
        transpose_body(g2, gt + T2_OFF, 512, (b - PB_L1) * 256 + tid);
    } else if (b < PB_PK) {
        int t = (b - PB_L2) * 256 + tid;      // < 4608
        int lane = t & 63;
        int fr = t >> 6;
        int ct = fr / 9;
        int kc = fr - ct * 9;
        int col = ct * 16 + (lane & 15);
        int krow = kc * 32 + (lane >> 4) * 8;
        uint32_t od[4];
        #pragma unroll
        for (int j = 0; j < 4; ++j) {
            uint16_t lo = f2bf_rne(w1[(size_t)(krow + 2 * j) * 128 + col]);
            uint16_t hi = f2bf_rne(w1[(size_t)(krow + 2 * j + 1) * 128 + col]);
            od[j] = (uint32_t)lo | ((uint32_t)hi << 16);
        }
        *(uint4*)(w1f + (size_t)t * 8) = make_uint4(od[0], od[1], od[2], od[3]);
    } else {
        int r = (b - PB_PK) * 256 + tid;
        float4 p = ray[r];
        uint32_t key = morton4(p);
        keys[r] = (uint16_t)key;
        atomicAdd(&hist[key], 1u);
    }
}

// ---------- sort kernels (2-stage scan; scanC folded into scatter) ----------
// scanA: per-256-bin block, local exclusive scan -> offs, block total -> bsum
__global__ void scanA_kernel(const uint32_t* __restrict__ hist,
                             uint32_t* __restrict__ bsum,
                             uint32_t* __restrict__ offs) {
    __shared__ uint32_t s[256];
    int t = threadIdx.x, b = blockIdx.x;
    uint32_t v = hist[b * 256 + t];
    s[t] = v;
    __syncthreads();
    for (int d = 1; d < 256; d <<= 1) {
        uint32_t x = (t >= d) ? s[t - d] : 0;
        __syncthreads();
        s[t] += x;
        __syncthreads();
    }
    offs[b * 256 + t] = s[t] - v;           // local exclusive
    if (t == 255) bsum[b] = s[255];         // block total
}

__global__ void scanB_kernel(uint32_t* __restrict__ bsum) {
    __shared__ uint32_t s[256];
    int t = threadIdx.x;
    uint32_t v = bsum[t];
    s[t] = v;
    __syncthreads();
    for (int d = 1; d < 256; d <<= 1) {
        uint32_t x = (t >= d) ? s[t - d] : 0;
        __syncthreads();
        s[t] += x;
        __syncthreads();
    }
    bsum[t] = s[t] - v;   // exclusive block bases
}

__global__ void scatter_kernel(const float4* __restrict__ ray,
                               const uint16_t* __restrict__ keys,
                               uint32_t* __restrict__ offs,
                               const uint32_t* __restrict__ bsum,
                               uint32_t* __restrict__ perm,
                               float4* __restrict__ ray_sorted) {
    int r = blockIdx.x * 256 + threadIdx.x;
    uint32_t key = keys[r];
    uint32_t pos = atomicAdd(&offs[key], 1u) + bsum[key >> 8];
    perm[pos] = (uint32_t)r;
    ray_sorted[pos] = ray[r];
}

// ---------- FUSED gather + MFMA MLP: 32 sorted rays per block ----------
// LDS feats row stride 148 dwords; s_h (stride 132 floats) aliases s_feats after barrier.
__global__ __launch_bounds__(256, 4) void fused_gmlp_kernel(
    const float4* __restrict__ rsort, const uint16_t* __restrict__ gt,
    const uint16_t* __restrict__ w1f, const float* __restrict__ bias1,
    const float* __restrict__ w2, const float* __restrict__ bias2,
    const uint32_t* __restrict__ perm, float* __restrict__ out) {
    __shared__ uint32_t s_feats[32 * 148];   // 18944 B
    __shared__ float s_w2[384];
    __shared__ float4 s_ray[32];

    int tid = threadIdx.x;
    int wvid = tid >> 6;
    int lane = tid & 63;
    // XCD-chunked bijective swizzle: 8192 blocks = 8 * 1024
    int swz = ((blockIdx.x & 7) << 10) + (blockIdx.x >> 3);
    int r0 = swz << 5;

    if (tid < 32) s_ray[tid] = rsort[r0 + tid];
    s_w2[tid] = w2[tid];
    if (tid < 128) s_w2[256 + tid] = w2[256 + tid];
    __syncthreads();

    // ---- phase A: 9 slots of 64 tasks; wave wvid handles slots wvid, wvid+4, wvid+8 ----
    for (int s = wvid; s < 9; s += 4) {
        int interp = 2 * s + (lane >> 5);
        int r = lane & 31;
        int level = (interp >= 12) ? 2 : ((interp >= 6) ? 1 : 0);
        int comb = interp - level * 6;
        int H = 128 << level;
        float4 p = s_ray[r];
        int c0 = (0x211000 >> (4 * comb)) & 0xF;   // 0,0,0,1,1,2
        int c1 = (0x332321 >> (4 * comb)) & 0xF;   // 1,2,3,2,3,3
        float u = sel4(p, c0) * (float)(H - 1);
        float v = sel4(p, c1) * (float)(H - 1);
        float u0f = fminf(fmaxf(floorf(u), 0.0f), (float)(H - 2));
        float v0f = fminf(fmaxf(floorf(v), 0.0f), (float)(H - 2));
        float fu = u - u0f, fv = v - v0f;
        int u0 = (int)u0f, v0 = (int)v0f;

        uint32_t lvl_off = (level == 0) ? T0_OFF : ((level == 1) ? T1_OFF : T2_OFF);
        const uint16_t* gp0 = gt + lvl_off + (((size_t)comb * H + u0) * H + v0) * 16;
        const uint4* q0 = (const uint4*)gp0;                       // row u0: (v0, v0+1)
        const uint4* q1 = (const uint4*)(gp0 + (size_t)16 * H);    // row u0+1
        uint4 a0 = q0[0], a1 = q0[1], a2 = q0[2], a3 = q0[3];
        uint4 b0 = q1[0], b1 = q1[1], b2 = q1[2], b3 = q1[3];

        uint32_t c00[8], c01[8], c10[8], c11[8];
        #pragma unroll
        for (int j = 0; j < 4; ++j) {
            c00[j] = ((const uint32_t*)&a0)[j];  c00[j + 4] = ((const uint32_t*)&a1)[j];
            c01[j] = ((const uint32_t*)&a2)[j];  c01[j + 4] = ((const uint32_t*)&a3)[j];
            c10[j] = ((const uint32_t*)&b0)[j];  c10[j + 4] = ((const uint32_t*)&b1)[j];
            c11[j] = ((const uint32_t*)&b2)[j];  c11[j + 4] = ((const uint32_t*)&b3)[j];
        }

        float w00 = (1.0f - fu) * (1.0f - fv);
        float w01 = (1.0f - fu) * fv;
        float w10 = fu * (1.0f - fv);
        float w11 = fu * fv;

        uint32_t od[8];
        #pragma unroll
        for (int j = 0; j < 8; ++j) {
            float lo = w00 * bf_lo(c00[j]) + w01 * bf_lo(c01[j]) +
                       w10 * bf_lo(c10[j]) + w11 * bf_lo(c11[j]);
            float hi = w00 * bf_hi(c00[j]) + w01 * bf_hi(c01[j]) +
                       w10 * bf_hi(c10[j]) + w11 * bf_hi(c11[j]);
            od[j] = (uint32_t)f2bf_rne(lo) | ((uint32_t)f2bf_rne(hi) << 16);
        }
        uint32_t* op = &s_feats[r * 148 + interp * 8];
        *(uint4*)op       = make_uint4(od[0], od[1], od[2], od[3]);
        *(uint4*)(op + 4) = make_uint4(od[4], od[5], od[6], od[7]);
    }
    __syncthreads();

    // ---- phase B: MFMA (two passes over ct to cap VGPR) ----
    float b1c0 = bias1[wvid * 32 + (lane & 15)];
    float b1c1 = bias1[wvid * 32 + 16 + (lane & 15)];
    int lg = lane >> 4;
    const uint32_t* arow = &s_feats[(lane & 15) * 148 + lg * 4];

    float4v acc00, acc10, acc01, acc11;
    {
        short8v bfrA[9];
        #pragma unroll
        for (int kc = 0; kc < 9; ++kc)
            bfrA[kc] = *(const short8v*)(w1f + (((size_t)((wvid * 2) * 9 + kc)) * 64 + lane) * 8);
        #pragma unroll
        for (int j = 0; j < 4; ++j) { acc00[j] = b1c0; acc10[j] = b1c0; }
        #pragma unroll
        for (int kc = 0; kc < 9; ++kc) {
            short8v a0 = *(const short8v*)(arow + kc * 16);
            short8v a1 = *(const short8v*)(arow + 16 * 148 + kc * 16);
            acc00 = __builtin_amdgcn_mfma_f32_16x16x32_bf16(a0, bfrA[kc], acc00, 0, 0, 0);
            acc10 = __builtin_amdgcn_mfma_f32_16x16x32_bf16(a1, bfrA[kc], acc10, 0, 0, 0);
        }
    }
    {
        short8v bfrB[9];
        #pragma unroll
        for (int kc = 0; kc < 9; ++kc)
            bfrB[kc] = *(const short8v*)(w1f + (((size_t)((wvid * 2 + 1) * 9 + kc)) * 64 + lane) * 8);
        #pragma unroll
        for (int j = 0; j < 4; ++j) { acc01[j] = b1c1; acc11[j] = b1c1; }
        #pragma unroll
        for (int kc = 0; kc < 9; ++kc) {
            short8v a0 = *(const short8v*)(arow + kc * 16);
            short8v a1 = *(const short8v*)(arow + 16 * 148 + kc * 16);
            acc01 = __builtin_amdgcn_mfma_f32_16x16x32_bf16(a0, bfrB[kc], acc01, 0, 0, 0);
            acc11 = __builtin_amdgcn_mfma_f32_16x16x32_bf16(a1, bfrB[kc], acc11, 0, 0, 0);
        }
    }
    __syncthreads();   // all s_feats reads done; safe to alias as s_h

    float* s_h = (float*)s_feats;   // [32][132]
    {
        int c0 = wvid * 32 + (lane & 15);
        int rb = lg * 4;
        #pragma unroll
        for (int j = 0; j < 4; ++j) {
            s_h[(rb + j) * 132 + c0]            = fmaxf(acc00[j], 0.0f);
            s_h[(rb + j) * 132 + c0 + 16]       = fmaxf(acc01[j], 0.0f);
            s_h[(rb + j + 16) * 132 + c0]       = fmaxf(acc10[j], 0.0f);
            s_h[(rb + j + 16) * 132 + c0 + 16]  = fmaxf(acc11[j], 0.0f);
        }
    }
    __syncthreads();

    // ---- layer 2 + sigmoid + scatter ----
    int ray = tid >> 3;
    int jg = tid & 7;
    int j0 = jg * 16;
    float p0 = 0.f, p1 = 0.f, p2 = 0.f;
    #pragma unroll
    for (int qq = 0; qq < 4; ++qq) {
        float4 hv = *(const float4*)&s_h[ray * 132 + j0 + qq * 4];
        const float* w2a = &s_w2[(j0 + qq * 4) * 3];
        p0 += hv.x * w2a[0] + hv.y * w2a[3] + hv.z * w2a[6] + hv.w * w2a[9];
        p1 += hv.x * w2a[1] + hv.y * w2a[4] + hv.z * w2a[7] + hv.w * w2a[10];
        p2 += hv.x * w2a[2] + hv.y * w2a[5] + hv.z * w2a[8] + hv.w * w2a[11];
    }
    p0 += __shfl_xor(p0, 1); p0 += __shfl_xor(p0, 2); p0 += __shfl_xor(p0, 4);
    p1 += __shfl_xor(p1, 1); p1 += __shfl_xor(p1, 2); p1 += __shfl_xor(p1, 4);
    p2 += __shfl_xor(p2, 1); p2 += __shfl_xor(p2, 2); p2 += __shfl_xor(p2, 4);

    if (jg == 0) {
        int orig = (int)perm[r0 + ray];
        float o0 = 1.0f / (1.0f + expf(-(p0 + bias2[0])));
        float o1 = 1.0f / (1.0f + expf(-(p1 + bias2[1])));
        float o2 = 1.0f / (1.0f + expf(-(p2 + bias2[2])));
        float* op = out + (size_t)orig * 3;
        op[0] = o0; op[1] = o1; op[2] = o2;
    }
}

// ---------- tier-2 fallback: transpose + gather_t + mfma_mlp ----------
__global__ void transpose_kernel(const float* __restrict__ in,
                                 __hip_bfloat16* __restrict__ out, int H) {
    int idx = blockIdx.x * blockDim.x + threadIdx.x;
    if (idx >= 6 * H * H) return;
    transpose_body(in, (uint16_t*)out, H, idx);
}

__global__ void w1_pack_kernel(const float* __restrict__ w1, uint16_t* __restrict__ w1f) {
    int t = blockIdx.x * 64 + threadIdx.x;
    if (t >= 8 * 9 * 64) return;
    int lane = t & 63;
    int fr = t >> 6;
    int ct = fr / 9;
    int kc = fr - ct * 9;
    int col = ct * 16 + (lane & 15);
    int krow = kc * 32 + (lane >> 4) * 8;
    uint32_t od[4];
    #pragma unroll
    for (int j = 0; j < 4; ++j) {
        uint16_t lo = f2bf_rne(w1[(size_t)(krow + 2 * j) * 128 + col]);
        uint16_t hi = f2bf_rne(w1[(size_t)(krow + 2 * j + 1) * 128 + col]);
        od[j] = (uint32_t)lo | ((uint32_t)hi << 16);
    }
    *(uint4*)(w1f + (size_t)t * 8) = make_uint4(od[0], od[1], od[2], od[3]);
}

__global__ __launch_bounds__(256, 8) void gather_t_kernel(
    const float4* __restrict__ ray, const uint16_t* __restrict__ gt,
    uint32_t* __restrict__ featsT) {
    int lb = (blockIdx.x & 7) * 2304 + (blockIdx.x >> 3);
    int interp = lb >> 10;
    int r = ((lb & 1023) << 8) + threadIdx.x;
    int level = interp / 6;
    int comb = interp - level * 6;
    int H = 128 << level;

    float4 p = ray[r];
    int c0 = (0x211000 >> (4 * comb)) & 0xF;
    int c1 = (0x332321 >> (4 * comb)) & 0xF;
    float u = sel4(p, c0) * (float)(H - 1);
    float v = sel4(p, c1) * (float)(H - 1);
    float u0f = fminf(fmaxf(floorf(u), 0.0f), (float)(H - 2));
    float v0f = fminf(fmaxf(floorf(v), 0.0f), (float)(H - 2));
    float wu = u - u0f, wv = v - v0f;
    int u0 = (int)u0f, v0 = (int)v0f;

    uint32_t lvl_off = (level == 0) ? T0_OFF : ((level == 1) ? T1_OFF : T2_OFF);
    const uint16_t* gp0 = gt + lvl_off + (((size_t)comb * H + u0) * H + v0) * 16;
    const uint4* q0 = (const uint4*)gp0;
    const uint4* q1 = (const uint4*)(gp0 + (size_t)16 * H);
    uint4 a0 = q0[0], a1 = q0[1], a2 = q0[2], a3 = q0[3];
    uint4 b0 = q1[0], b1 = q1[1], b2 = q1[2], b3 = q1[3];

    uint32_t c00[8], c01[8], c10[8], c11[8];
    #pragma unroll
    for (int j = 0; j < 4; ++j) {
        c00[j] = ((const uint32_t*)&a0)[j];  c00[j + 4] = ((const uint32_t*)&a1)[j];
        c01[j] = ((const uint32_t*)&a2)[j];  c01[j + 4] = ((const uint32_t*)&a3)[j];
        c10[j] = ((const uint32_t*)&b0)[j];  c10[j + 4] = ((const uint32_t*)&b1)[j];
        c11[j] = ((const uint32_t*)&b2)[j];  c11[j + 4] = ((const uint32_t*)&b3)[j];
    }

    float w00 = (1.0f - wu) * (1.0f - wv);
    float w01 = (1.0f - wu) * wv;
    float w10 = wu * (1.0f - wv);
    float w11 = wu * wv;

    uint32_t od[8];
    #pragma unroll
    for (int j = 0; j < 8; ++j) {
        float lo = w00 * bf_lo(c00[j]) + w01 * bf_lo(c01[j]) +
                   w10 * bf_lo(c10[j]) + w11 * bf_lo(c11[j]);
        float hi = w00 * bf_hi(c00[j]) + w01 * bf_hi(c01[j]) +
                   w10 * bf_hi(c10[j]) + w11 * bf_hi(c11[j]);
        od[j] = (uint32_t)f2bf_rne(lo) | ((uint32_t)f2bf_rne(hi) << 16);
    }

    uint4* op = (uint4*)(featsT + ((size_t)interp * N_RAYS + r) * 8);
    op[0] = make_uint4(od[0], od[1], od[2], od[3]);
    op[1] = make_uint4(od[4], od[5], od[6], od[7]);
}

__global__ __launch_bounds__(256, 2) void mfma_mlp_kernel(
    const uint16_t* __restrict__ featsT,
    const uint16_t* __restrict__ w1f,
    const float* __restrict__ bias1,
    const float* __restrict__ w2, const float* __restrict__ bias2,
    const uint32_t* __restrict__ perm,
    float* __restrict__ out, int tiles_per_block) {
    __shared__ float s_h[32][132];

    int tid = threadIdx.x;
    int wv = tid >> 6;
    int lane = tid & 63;

    short8v bfr[2][9];
    #pragma unroll
    for (int ctl = 0; ctl < 2; ++ctl) {
        int ct = wv * 2 + ctl;
        #pragma unroll
        for (int kc = 0; kc < 9; ++kc)
            bfr[ctl][kc] = *(const short8v*)(w1f + (((size_t)(ct * 9 + kc)) * 64 + lane) * 8);
    }
    float b1c0 = bias1[wv * 32 + (lane & 15)];
    float b1c1 = bias1[wv * 32 + 16 + (lane & 15)];

    int jg = tid & 7;
    int j0 = jg * 16;
    float w2r0[16], w2r1[16], w2r2[16];
    #pragma unroll
    for (int jj = 0; jj < 16; ++jj) {
        const float* w2p = w2 + (size_t)(j0 + jj) * 3;
        w2r0[jj] = w2p[0]; w2r1[jj] = w2p[1]; w2r2[jj] = w2p[2];
    }
    float bb0 = bias2[0], bb1 = bias2[1], bb2 = bias2[2];

    int lg = lane >> 4;
    int half8 = (lg & 1) * 8;
    int ipo = lg >> 1;

    for (int it = 0; it < tiles_per_block; ++it) {
        int tile = blockIdx.x * tiles_per_block + it;
        int r0 = tile * 32;
        int rA = r0 + (lane & 15);

        short8v af[18];
        #pragma unroll
        for (int kc = 0; kc < 9; ++kc) {
            size_t base = ((size_t)(2 * kc + ipo) * N_RAYS + rA) * 16 + half8;
            af[kc]     = *(const short8v*)(featsT + base);
            af[9 + kc] = *(const short8v*)(featsT + base + 256);
        }

        float4v acc00, acc01, acc10, acc11;
        #pragma unroll
        for (int j = 0; j < 4; ++j) { acc00[j] = b1c0; acc01[j] = b1c1; acc10[j] = b1c0; acc11[j] = b1c1; }

        #pragma unroll
        for (int kc = 0; kc < 9; ++kc) {
            acc00 = __builtin_amdgcn_mfma_f32_16x16x32_bf16(af[kc],     bfr[0][kc], acc00, 0, 0, 0);
            acc01 = __builtin_amdgcn_mfma_f32_16x16x32_bf16(af[kc],     bfr[1][kc], acc01, 0, 0, 0);
            acc10 = __builtin_amdgcn_mfma_f32_16x16x32_bf16(af[9 + kc], bfr[0][kc], acc10, 0, 0, 0);
            acc11 = __builtin_amdgcn_mfma_f32_16x16x32_bf16(af[9 + kc], bfr[1][kc], acc11, 0, 0, 0);
        }

        __syncthreads();
        {
            int c0 = wv * 32 + (lane & 15);
            int rb = (lane >> 4) * 4;
            #pragma unroll
            for (int j = 0; j < 4; ++j) {
                s_h[rb + j][c0]           = fmaxf(acc00[j], 0.0f);
                s_h[rb + j][c0 + 16]      = fmaxf(acc01[j], 0.0f);
                s_h[rb + j + 16][c0]      = fmaxf(acc10[j], 0.0f);
                s_h[rb + j + 16][c0 + 16] = fmaxf(acc11[j], 0.0f);
            }
        }
        __syncthreads();

        int ray = tid >> 3;
        float p0 = 0.f, p1 = 0.f, p2 = 0.f;
        #pragma unroll
        for (int qq = 0; qq < 4; ++qq) {
            float4 hv = *(const float4*)&s_h[ray][j0 + qq * 4];
            float h0 = hv.x, h1 = hv.y, h2 = hv.z, h3 = hv.w;
            p0 += h0 * w2r0[qq * 4] + h1 * w2r0[qq * 4 + 1] + h2 * w2r0[qq * 4 + 2] + h3 * w2r0[qq * 4 + 3];
            p1 += h0 * w2r1[qq * 4] + h1 * w2r1[qq * 4 + 1] + h2 * w2r1[qq * 4 + 2] + h3 * w2r1[qq * 4 + 3];
            p2 += h0 * w2r2[qq * 4] + h1 * w2r2[qq * 4 + 1] + h2 * w2r2[qq * 4 + 2] + h3 * w2r2[qq * 4 + 3];
        }
        p0 += __shfl_xor(p0, 1); p0 += __shfl_xor(p0, 2); p0 += __shfl_xor(p0, 4);
        p1 += __shfl_xor(p1, 1); p1 += __shfl_xor(p1, 2); p1 += __shfl_xor(p1, 4);
        p2 += __shfl_xor(p2, 1); p2 += __shfl_xor(p2, 2); p2 += __shfl_xor(p2, 4);

        if (jg == 0) {
            int orig = perm ? (int)perm[r0 + ray] : (r0 + ray);
            float o0 = 1.0f / (1.0f + expf(-(p0 + bb0)));
            float o1 = 1.0f / (1.0f + expf(-(p1 + bb1)));
            float o2 = 1.0f / (1.0f + expf(-(p2 + bb2)));
            float* op = out + (size_t)orig * 3;
            op[0] = o0; op[1] = o1; op[2] = o2;
        }
    }
}

// ---------- tier-3/4 fallback fused kernel (small ws) ----------
template <bool USE_T>
__global__ __launch_bounds__(THREADS) void fused_kernel(
    const float4* __restrict__ ray,
    const float* __restrict__ g0, const float* __restrict__ g1,
    const float* __restrict__ g2,
    const __hip_bfloat16* __restrict__ gt,
    const float* __restrict__ weights1, const float* __restrict__ bias1,
    const float* __restrict__ weights2, const float* __restrict__ bias2,
    float* __restrict__ out) {
    __shared__ float4 s_ray[NR];
    __shared__ float s_feats[NR][FSTRIDE];

    int tid = threadIdx.x;
    int rbase = blockIdx.x * NR;
    if (tid < NR) s_ray[tid] = ray[rbase + tid];
    __syncthreads();

    for (int t = tid; t < NR * 36; t += THREADS) {
        int r = t / 36;
        int rem = t - r * 36;
        int interp = rem >> 1;
        int half = rem & 1;
        int level = (interp >= 12) ? 2 : ((interp >= 6) ? 1 : 0);
        int comb = interp - level * 6;
        int H = 128 << level;
        float4 p = s_ray[r];
        int c0 = (0x211000 >> (4 * comb)) & 0xF;
        int c1 = (0x332321 >> (4 * comb)) & 0xF;
        float u = sel4(p, c0) * (float)(H - 1);
        float v = sel4(p, c1) * (float)(H - 1);
        float u0f = fminf(fmaxf(floorf(u), 0.0f), (float)(H - 2));
        float v0f = fminf(fmaxf(floorf(v), 0.0f), (float)(H - 2));
        float wu = u - u0f, wv = v - v0f;
        int u0 = (int)u0f, v0 = (int)v0f;
        float w00 = (1.0f - wu) * (1.0f - wv);
        float w01 = (1.0f - wu) * wv;
        float w10 = wu * (1.0f - wv);
        float w11 = wu * wv;
        float f[8];
        if (USE_T) {
            uint32_t lvl_off = (level == 0) ? T0_OFF : ((level == 1) ? T1_OFF : T2_OFF);
            const uint16_t* gp = (const uint16_t*)gt + lvl_off +
                                 (((size_t)comb * H + u0) * H + v0) * 16 + half * 8;
            uint4 a00 = *(const uint4*)gp;
            uint4 a01 = *(const uint4*)(gp + 16);
            uint4 a10 = *(const uint4*)(gp + (size_t)16 * H);
            uint4 a11 = *(const uint4*)(gp + (size_t)16 * H + 16);
            #pragma unroll
            for (int i = 0; i < 8; ++i) {
                f[i] = w00 * bf_extract(a00, i) + w01 * bf_extract(a01, i) +
                       w10 * bf_extract(a10, i) + w11 * bf_extract(a11, i);
            }
        } else {
            const float* gp = (level == 0) ? g0 : ((level == 1) ? g1 : g2);
            const float* base = gp + ((size_t)(comb * 16 + half * 8) * H + u0) * H + v0;
            #pragma unroll
            for (int i = 0; i < 8; ++i) {
                const float* q = base + (size_t)i * H * H;
                float a00 = q[0], a01 = q[1], a10 = q[H], a11 = q[H + 1];
                f[i] = w00 * a00 + w01 * a01 + w10 * a10 + w11 * a11;
            }
        }
        int fo = interp * 16 + half * 8;
        float* fp = &s_feats[r][fo];
        #pragma unroll
        for (int i = 0; i < 8; ++i) fp[i] = f[i];
    }
    __syncthreads();

    int r = tid >> 3;
    int jg = tid & 7;
    int j0 = jg * 16;
    float acc[16];
    #pragma unroll
    for (int jj = 0; jj < 16; ++jj) acc[jj] = bias1[j0 + jj];

    const float* wp = weights1 + j0;
    for (int k = 0; k < 288; k += 4) {
        float4 fv = *(const float4*)&s_feats[r][k];
        #pragma unroll
        for (int kk = 0; kk < 4; ++kk) {
            const float4* wr = (const float4*)(wp + (size_t)(k + kk) * 128);
            float fk = (kk == 0) ? fv.x : ((kk == 1) ? fv.y : ((kk == 2) ? fv.z : fv.w));
            float4 wa = wr[0], wb = wr[1], wc = wr[2], wd = wr[3];
            acc[0]  += fk * wa.x; acc[1]  += fk * wa.y; acc[2]  += fk * wa.z; acc[3]  += fk * wa.w;
            acc[4]  += fk * wb.x; acc[5]  += fk * wb.y; acc[6]  += fk * wb.z; acc[7]  += fk * wb.w;
            acc[8]  += fk * wc.x; acc[9]  += fk * wc.y; acc[10] += fk * wc.z; acc[11] += fk * wc.w;
            acc[12] += fk * wd.x; acc[13] += fk * wd.y; acc[14] += fk * wd.z; acc[15] += fk * wd.w;
        }
    }

    float p0 = 0.f, p1 = 0.f, p2 = 0.f;
    #pragma unroll
    for (int jj = 0; jj < 16; ++jj) {
        float h = fmaxf(acc[jj], 0.0f);
        const float* w2r = weights2 + (size_t)(j0 + jj) * 3;
        p0 += h * w2r[0];
        p1 += h * w2r[1];
        p2 += h * w2r[2];
    }
    p0 += __shfl_xor(p0, 1); p0 += __shfl_xor(p0, 2); p0 += __shfl_xor(p0, 4);
    p1 += __shfl_xor(p1, 1); p1 += __shfl_xor(p1, 2); p1 += __shfl_xor(p1, 4);
    p2 += __shfl_xor(p2, 1); p2 += __shfl_xor(p2, 2); p2 += __shfl_xor(p2, 4);

    if (jg == 0) {
        float o0 = 1.0f / (1.0f + expf(-(p0 + bias2[0])));
        float o1 = 1.0f / (1.0f + expf(-(p1 + bias2[1])));
        float o2 = 1.0f / (1.0f + expf(-(p2 + bias2[2])));
        float* op = out + (size_t)(rbase + r) * 3;
        op[0] = o0; op[1] = o1; op[2] = o2;
    }
}

extern "C" void kernel_launch(void* const* d_in, const int* in_sizes, int n_in,
                              void* d_out, int out_size, void* d_ws, size_t ws_size,
                              hipStream_t stream) {
    const float4* ray = (const float4*)d_in[0];
    const float* g0 = (const float*)d_in[1];
    const float* g1 = (const float*)d_in[2];
    const float* g2 = (const float*)d_in[3];
    const float* w1 = (const float*)d_in[4];
    const float* b1 = (const float*)d_in[5];
    const float* w2 = (const float*)d_in[6];
    const float* b2 = (const float*)d_in[7];
    float* out = (float*)d_out;

    const size_t T_BYTES = (size_t)T_ELEMS * 2;
    const size_t NEED = (size_t)W1F_BYTE_OFF + W1F_BYTES;

    if (ws_size >= (size_t)NEED_SORT) {
        char* ws = (char*)d_ws;
        __hip_bfloat16* wsb = (__hip_bfloat16*)d_ws;
        uint32_t* bsum  = (uint32_t*)(ws + FEAT_BYTE_OFF);   // scratch (feat arena unused)
        uint16_t* w1f  = (uint16_t*)(ws + W1F_BYTE_OFF);
        uint16_t* keys = (uint16_t*)(ws + KEYS_OFF);
        uint32_t* perm = (uint32_t*)(ws + PERM_OFF);
        uint32_t* hist = (uint32_t*)(ws + HIST_OFF);
        uint32_t* offs = (uint32_t*)(ws + OFFS_OFF);
        float4* rsort  = (float4*)(ws + RSORT_OFF);

        hipMemsetAsync(hist, 0, 65536 * 4, stream);
        prep_kernel<<<PB_HI, 256, 0, stream>>>(
            g0, g1, g2, w1, ray, (uint16_t*)wsb, w1f, keys, hist);
        scanA_kernel<<<256, 256, 0, stream>>>(hist, bsum, offs);
        scanB_kernel<<<1, 256, 0, stream>>>(bsum);
        scatter_kernel<<<N_RAYS / 256, 256, 0, stream>>>(ray, keys, offs, bsum, perm, rsort);
        fused_gmlp_kernel<<<N_RAYS / 32, 256, 0, stream>>>(
            rsort, (const uint16_t*)wsb, w1f, b1, w2, b2, perm, out);
    } else if (ws_size >= NEED) {
        __hip_bfloat16* wsb = (__hip_bfloat16*)d_ws;
        transpose_kernel<<<(6 * 128 * 128 + 255) / 256, 256, 0, stream>>>(g0, wsb + T0_OFF, 128);
        transpose_kernel<<<(6 * 256 * 256 + 255) / 256, 256, 0, stream>>>(g1, wsb + T1_OFF, 256);
        transpose_kernel<<<(6 * 512 * 512 + 255) / 256, 256, 0, stream>>>(g2, wsb + T2_OFF, 512);
        uint32_t* feats = (uint32_t*)((char*)d_ws + FEAT_BYTE_OFF);
        uint16_t* w1f = (uint16_t*)((char*)d_ws + W1F_BYTE_OFF);
        w1_pack_kernel<<<72, 64, 0, stream>>>(w1, w1f);
        gather_t_kernel<<<18432, 256, 0, stream>>>(ray, (const uint16_t*)wsb, feats);
        const int TILES_PER_BLOCK = 4;
        int nblk = N_RAYS / 32 / TILES_PER_BLOCK;
        mfma_mlp_kernel<<<nblk, 256, 0, stream>>>(
            (const uint16_t*)feats, w1f, b1, w2, b2, nullptr, out, TILES_PER_BLOCK);
    } else if (ws_size >= T_BYTES) {
        __hip_bfloat16* wsb = (__hip_bfloat16*)d_ws;
        transpose_kernel<<<(6 * 128 * 128 + 255) / 256, 256, 0, stream>>>(g0, wsb + T0_OFF, 128);
        transpose_kernel<<<(6 * 256 * 256 + 255) / 256, 256, 0, stream>>>(g1, wsb + T1_OFF, 256);
        transpose_kernel<<<(6 * 512 * 512 + 255) / 256, 256, 0, stream>>>(g2, wsb + T2_OFF, 512);
        fused_kernel<true><<<N_RAYS / NR, THREADS, 0, stream>>>(
            ray, g0, g1, g2, wsb, w1, b1, w2, b2, out);
    } else {
        fused_kernel<false><<<N_RAYS / NR, THREADS, 0, stream>>>(
            ray, g0, g1, g2, nullptr, w1, b1, w2, b2, out);
    }
}

// Round 10
// 177.400 us; speedup vs baseline: 2.2588x; 1.0263x over previous
//
#include <hip/hip_runtime.h>
#include <hip/hip_bf16.h>
#include <cstdint>
#include <cstddef>

#define N_RAYS 262144
#define NR 32
#define THREADS 256
#define FSTRIDE 292

// offsets in uint16 elements into the transposed-grid arena
#define T0_OFF 0u
#define T1_OFF 1572864u      // 6*128*128*16
#define T2_OFF 7864320u      // + 6*256*256*16
#define T_ELEMS 33030144u    // 6*16*(128^2+256^2+512^2)
#define FEAT_BYTE_OFF 66060288u   // T_ELEMS*2
#define FEAT_DWORDS 37748736u     // 262144*144
#define W1F_BYTE_OFF 217055232u   // FEAT_BYTE_OFF + FEAT_DWORDS*4
#define W1F_BYTES 73728u          // 288*128*2
// sort scratch (bytes)
#define KEYS_OFF   217128960u     // u16[262144]  (512 KB)
#define PERM_OFF   217653248u     // u32[262144]  (1 MB)
#define HIST_OFF   218701824u     // u32[65536]   (256 KB)
#define OFFS_OFF   218963968u     // u32[65536]   (256 KB)
#define RSORT_OFF  219226112u     // float4[262144] (4 MB)
#define NEED_SORT  223420416u

// prep_kernel block ranges
#define PB_L0   384       // 6*128*128/256
#define PB_L1   1920      // +6*256*256/256
#define PB_L2   8064      // +6*512*512/256
#define PB_PK   8082      // +4608/256
#define PB_HI   9106      // +262144/256

typedef __attribute__((ext_vector_type(8))) short short8v;   // 8 bf16 = 4 VGPRs
typedef __attribute__((ext_vector_type(4))) float float4v;   // MFMA C/D

// ---------- helpers ----------
__device__ __forceinline__ float bf_lo(uint32_t w) { return __uint_as_float(w << 16); }
__device__ __forceinline__ float bf_hi(uint32_t w) { return __uint_as_float(w & 0xFFFF0000u); }

__device__ __forceinline__ float bf_extract(const uint4& q, int i) {
    uint32_t w = ((const uint32_t*)&q)[i >> 1];
    uint32_t h = (i & 1) ? (w & 0xFFFF0000u) : (w << 16);
    return __uint_as_float(h);
}

__device__ __forceinline__ uint16_t f2bf_rne(float f) {
    uint32_t x = __float_as_uint(f);
    uint32_t r = x + 0x7FFFu + ((x >> 16) & 1u);
    return (uint16_t)(r >> 16);
}

__device__ __forceinline__ float sel4(const float4& p, int i) {
    float r = p.x;
    r = (i == 1) ? p.y : r;
    r = (i == 2) ? p.z : r;
    r = (i == 3) ? p.w : r;
    return r;
}

__device__ __forceinline__ uint32_t morton4(const float4& p) {
    int q0 = min(15, max(0, (int)(p.x * 16.0f)));
    int q1 = min(15, max(0, (int)(p.y * 16.0f)));
    int q2 = min(15, max(0, (int)(p.z * 16.0f)));
    int q3 = min(15, max(0, (int)(p.w * 16.0f)));
    uint32_t key = 0;
    #pragma unroll
    for (int b = 0; b < 4; ++b) {
        key |= (uint32_t)((q0 >> b) & 1) << (4 * b + 0);
        key |= (uint32_t)((q1 >> b) & 1) << (4 * b + 1);
        key |= (uint32_t)((q2 >> b) & 1) << (4 * b + 2);
        key |= (uint32_t)((q3 >> b) & 1) << (4 * b + 3);
    }
    return key;
}

__device__ __forceinline__ void transpose_body(const float* __restrict__ in,
                                               uint16_t* __restrict__ out,
                                               int H, int idx) {
    int hh = H * H;
    int c = idx / hh;
    int rem = idx - c * hh;
    const float* ip = in + (size_t)c * 16 * hh + rem;
    uint32_t words[8];
    #pragma unroll
    for (int j = 0; j < 8; ++j) {
        uint16_t lo = f2bf_rne(ip[(size_t)(2 * j) * hh]);
        uint16_t hi = f2bf_rne(ip[(size_t)(2 * j + 1) * hh]);
        words[j] = (uint32_t)lo | ((uint32_t)hi << 16);
    }
    uint4* op = (uint4*)(out + (size_t)idx * 16);
    op[0] = make_uint4(words[0], words[1], words[2], words[3]);
    op[1] = make_uint4(words[4], words[5], words[6], words[7]);
}

// ---------- merged prep: 3 transposes + w1 pack + morton keys/hist ----------
__global__ __launch_bounds__(256) void prep_kernel(
    const float* __restrict__ g0, const float* __restrict__ g1,
    const float* __restrict__ g2, const float* __restrict__ w1,
    const float4* __restrict__ ray,
    uint16_t* __restrict__ gt, uint16_t* __restrict__ w1f,
    uint16_t* __restrict__ keys, uint32_t* __restrict__ hist) {
    int b = blockIdx.x;
    int tid = threadIdx.x;
    if (b < PB_L0) {
        transpose_body(g0, gt + T0_OFF, 128, b * 256 + tid);
    } else if (b < PB_L1) {
        transpose_body(g1, gt + T1_OFF, 256, (b - PB_L0) * 256 + tid);
    } else if (b < PB_L2) {
        transpose_body(g2, gt + T2_OFF, 512, (b - PB_L1) * 256 + tid);
    } else if (b < PB_PK) {
        int t = (b - PB_L2) * 256 + tid;      // < 4608
        int lane = t & 63;
        int fr = t >> 6;
        int ct = fr / 9;
        int kc = fr - ct * 9;
        int col = ct * 16 + (lane & 15);
        int krow = kc * 32 + (lane >> 4) * 8;
        uint32_t od[4];
        #pragma unroll
        for (int j = 0; j < 4; ++j) {
            uint16_t lo = f2bf_rne(w1[(size_t)(krow + 2 * j) * 128 + col]);
            uint16_t hi = f2bf_rne(w1[(size_t)(krow + 2 * j + 1) * 128 + col]);
            od[j] = (uint32_t)lo | ((uint32_t)hi << 16);
        }
        *(uint4*)(w1f + (size_t)t * 8) = make_uint4(od[0], od[1], od[2], od[3]);
    } else {
        int r = (b - PB_PK) * 256 + tid;
        float4 p = ray[r];
        uint32_t key = morton4(p);
        keys[r] = (uint16_t)key;
        atomicAdd(&hist[key], 1u);
    }
}

// ---------- sort kernels (2-stage scan; scanC folded into scatter) ----------
__global__ void scanA_kernel(const uint32_t* __restrict__ hist,
                             uint32_t* __restrict__ bsum,
                             uint32_t* __restrict__ offs) {
    __shared__ uint32_t s[256];
    int t = threadIdx.x, b = blockIdx.x;
    uint32_t v = hist[b * 256 + t];
    s[t] = v;
    __syncthreads();
    for (int d = 1; d < 256; d <<= 1) {
        uint32_t x = (t >= d) ? s[t - d] : 0;
        __syncthreads();
        s[t] += x;
        __syncthreads();
    }
    offs[b * 256 + t] = s[t] - v;           // local exclusive
    if (t == 255) bsum[b] = s[255];         // block total
}

__global__ void scanB_kernel(uint32_t* __restrict__ bsum) {
    __shared__ uint32_t s[256];
    int t = threadIdx.x;
    uint32_t v = bsum[t];
    s[t] = v;
    __syncthreads();
    for (int d = 1; d < 256; d <<= 1) {
        uint32_t x = (t >= d) ? s[t - d] : 0;
        __syncthreads();
        s[t] += x;
        __syncthreads();
    }
    bsum[t] = s[t] - v;   // exclusive block bases
}

__global__ void scatter_kernel(const float4* __restrict__ ray,
                               const uint16_t* __restrict__ keys,
                               uint32_t* __restrict__ offs,
                               const uint32_t* __restrict__ bsum,
                               uint32_t* __restrict__ perm,
                               float4* __restrict__ ray_sorted) {
    int r = blockIdx.x * 256 + threadIdx.x;
    uint32_t key = keys[r];
    uint32_t pos = atomicAdd(&offs[key], 1u) + bsum[key >> 8];
    perm[pos] = (uint32_t)r;
    ray_sorted[pos] = ray[r];
}

// ---------- FUSED gather + MFMA MLP: 32 sorted rays per block ----------
// Phase A: 18 wave-uniform slots (one (level,comb) plane per wave-instruction);
// 2 lanes per ray, each lane loads the 4 corner 16B-halves of its channel half.
// LDS feats row stride 148 dwords; s_h (stride 132 floats) aliases s_feats after barrier.
__global__ __launch_bounds__(256, 4) void fused_gmlp_kernel(
    const float4* __restrict__ rsort, const uint16_t* __restrict__ gt,
    const uint16_t* __restrict__ w1f, const float* __restrict__ bias1,
    const float* __restrict__ w2, const float* __restrict__ bias2,
    const uint32_t* __restrict__ perm, float* __restrict__ out) {
    __shared__ uint32_t s_feats[32 * 148];   // 18944 B
    __shared__ float s_w2[384];
    __shared__ float4 s_ray[32];

    int tid = threadIdx.x;
    int wvid = tid >> 6;
    int lane = tid & 63;
    // XCD-chunked bijective swizzle: 8192 blocks = 8 * 1024
    int swz = ((blockIdx.x & 7) << 10) + (blockIdx.x >> 3);
    int r0 = swz << 5;

    if (tid < 32) s_ray[tid] = rsort[r0 + tid];
    s_w2[tid] = w2[tid];
    if (tid < 128) s_w2[256 + tid] = w2[256 + tid];
    __syncthreads();

    // ---- phase A: 18 slots; slot = one interp, wave-uniform plane ----
    {
        int r = lane >> 1;          // ray 0..31
        int half = lane & 1;        // channel half (8 channels = 16B)
        for (int interp = wvid; interp < 18; interp += 4) {
            int level = (interp >= 12) ? 2 : ((interp >= 6) ? 1 : 0);
            int comb = interp - level * 6;
            int H = 128 << level;
            float4 p = s_ray[r];
            int c0 = (0x211000 >> (4 * comb)) & 0xF;   // 0,0,0,1,1,2
            int c1 = (0x332321 >> (4 * comb)) & 0xF;   // 1,2,3,2,3,3
            float u = sel4(p, c0) * (float)(H - 1);
            float v = sel4(p, c1) * (float)(H - 1);
            float u0f = fminf(fmaxf(floorf(u), 0.0f), (float)(H - 2));
            float v0f = fminf(fmaxf(floorf(v), 0.0f), (float)(H - 2));
            float fu = u - u0f, fv = v - v0f;
            int u0 = (int)u0f, v0 = (int)v0f;

            uint32_t lvl_off = (level == 0) ? T0_OFF : ((level == 1) ? T1_OFF : T2_OFF);
            const uint16_t* gp = gt + lvl_off +
                                 (((size_t)comb * H + u0) * H + v0) * 16 + half * 8;
            uint4 c00 = *(const uint4*)gp;                            // (u0,   v0)
            uint4 c01 = *(const uint4*)(gp + 16);                     // (u0,   v0+1)
            uint4 c10 = *(const uint4*)(gp + (size_t)16 * H);         // (u0+1, v0)
            uint4 c11 = *(const uint4*)(gp + (size_t)16 * H + 16);    // (u0+1, v0+1)

            float w00 = (1.0f - fu) * (1.0f - fv);
            float w01 = (1.0f - fu) * fv;
            float w10 = fu * (1.0f - fv);
            float w11 = fu * fv;

            uint32_t od[4];
            #pragma unroll
            for (int j = 0; j < 4; ++j) {
                uint32_t v00 = ((const uint32_t*)&c00)[j];
                uint32_t v01 = ((const uint32_t*)&c01)[j];
                uint32_t v10 = ((const uint32_t*)&c10)[j];
                uint32_t v11 = ((const uint32_t*)&c11)[j];
                float lo = w00 * bf_lo(v00) + w01 * bf_lo(v01) +
                           w10 * bf_lo(v10) + w11 * bf_lo(v11);
                float hi = w00 * bf_hi(v00) + w01 * bf_hi(v01) +
                           w10 * bf_hi(v10) + w11 * bf_hi(v11);
                od[j] = (uint32_t)f2bf_rne(lo) | ((uint32_t)f2bf_rne(hi) << 16);
            }
            *(uint4*)&s_feats[r * 148 + interp * 8 + half * 4] =
                make_uint4(od[0], od[1], od[2], od[3]);
        }
    }
    __syncthreads();

    // ---- phase B: MFMA (two passes over ct to cap VGPR) ----
    float b1c0 = bias1[wvid * 32 + (lane & 15)];
    float b1c1 = bias1[wvid * 32 + 16 + (lane & 15)];
    int lg = lane >> 4;
    const uint32_t* arow = &s_feats[(lane & 15) * 148 + lg * 4];

    float4v acc00, acc10, acc01, acc11;
    {
        short8v bfrA[9];
        #pragma unroll
        for (int kc = 0; kc < 9; ++kc)
            bfrA[kc] = *(const short8v*)(w1f + (((size_t)((wvid * 2) * 9 + kc)) * 64 + lane) * 8);
        #pragma unroll
        for (int j = 0; j < 4; ++j) { acc00[j] = b1c0; acc10[j] = b1c0; }
        #pragma unroll
        for (int kc = 0; kc < 9; ++kc) {
            short8v a0 = *(const short8v*)(arow + kc * 16);
            short8v a1 = *(const short8v*)(arow + 16 * 148 + kc * 16);
            acc00 = __builtin_amdgcn_mfma_f32_16x16x32_bf16(a0, bfrA[kc], acc00, 0, 0, 0);
            acc10 = __builtin_amdgcn_mfma_f32_16x16x32_bf16(a1, bfrA[kc], acc10, 0, 0, 0);
        }
    }
    {
        short8v bfrB[9];
        #pragma unroll
        for (int kc = 0; kc < 9; ++kc)
            bfrB[kc] = *(const short8v*)(w1f + (((size_t)((wvid * 2 + 1) * 9 + kc)) * 64 + lane) * 8);
        #pragma unroll
        for (int j = 0; j < 4; ++j) { acc01[j] = b1c1; acc11[j] = b1c1; }
        #pragma unroll
        for (int kc = 0; kc < 9; ++kc) {
            short8v a0 = *(const short8v*)(arow + kc * 16);
            short8v a1 = *(const short8v*)(arow + 16 * 148 + kc * 16);
            acc01 = __builtin_amdgcn_mfma_f32_16x16x32_bf16(a0, bfrB[kc], acc01, 0, 0, 0);
            acc11 = __builtin_amdgcn_mfma_f32_16x16x32_bf16(a1, bfrB[kc], acc11, 0, 0, 0);
        }
    }
    __syncthreads();   // all s_feats reads done; safe to alias as s_h

    float* s_h = (float*)s_feats;   // [32][132]
    {
        int c0 = wvid * 32 + (lane & 15);
        int rb = lg * 4;
        #pragma unroll
        for (int j = 0; j < 4; ++j) {
            s_h[(rb + j) * 132 + c0]            = fmaxf(acc00[j], 0.0f);
            s_h[(rb + j) * 132 + c0 + 16]       = fmaxf(acc01[j], 0.0f);
            s_h[(rb + j + 16) * 132 + c0]       = fmaxf(acc10[j], 0.0f);
            s_h[(rb + j + 16) * 132 + c0 + 16]  = fmaxf(acc11[j], 0.0f);
        }
    }
    __syncthreads();

    // ---- layer 2 + sigmoid + scatter ----
    int ray = tid >> 3;
    int jg = tid & 7;
    int j0 = jg * 16;
    float p0 = 0.f, p1 = 0.f, p2 = 0.f;
    #pragma unroll
    for (int qq = 0; qq < 4; ++qq) {
        float4 hv = *(const float4*)&s_h[ray * 132 + j0 + qq * 4];
        const float* w2a = &s_w2[(j0 + qq * 4) * 3];
        p0 += hv.x * w2a[0] + hv.y * w2a[3] + hv.z * w2a[6] + hv.w * w2a[9];
        p1 += hv.x * w2a[1] + hv.y * w2a[4] + hv.z * w2a[7] + hv.w * w2a[10];
        p2 += hv.x * w2a[2] + hv.y * w2a[5] + hv.z * w2a[8] + hv.w * w2a[11];
    }
    p0 += __shfl_xor(p0, 1); p0 += __shfl_xor(p0, 2); p0 += __shfl_xor(p0, 4);
    p1 += __shfl_xor(p1, 1); p1 += __shfl_xor(p1, 2); p1 += __shfl_xor(p1, 4);
    p2 += __shfl_xor(p2, 1); p2 += __shfl_xor(p2, 2); p2 += __shfl_xor(p2, 4);

    if (jg == 0) {
        int orig = (int)perm[r0 + ray];
        float o0 = 1.0f / (1.0f + expf(-(p0 + bias2[0])));
        float o1 = 1.0f / (1.0f + expf(-(p1 + bias2[1])));
        float o2 = 1.0f / (1.0f + expf(-(p2 + bias2[2])));
        float* op = out + (size_t)orig * 3;
        op[0] = o0; op[1] = o1; op[2] = o2;
    }
}

// ---------- tier-2 fallback: transpose + gather_t + mfma_mlp ----------
__global__ void transpose_kernel(const float* __restrict__ in,
                                 __hip_bfloat16* __restrict__ out, int H) {
    int idx = blockIdx.x * blockDim.x + threadIdx.x;
    if (idx >= 6 * H * H) return;
    transpose_body(in, (uint16_t*)out, H, idx);
}

__global__ void w1_pack_kernel(const float* __restrict__ w1, uint16_t* __restrict__ w1f) {
    int t = blockIdx.x * 64 + threadIdx.x;
    if (t >= 8 * 9 * 64) return;
    int lane = t & 63;
    int fr = t >> 6;
    int ct = fr / 9;
    int kc = fr - ct * 9;
    int col = ct * 16 + (lane & 15);
    int krow = kc * 32 + (lane >> 4) * 8;
    uint32_t od[4];
    #pragma unroll
    for (int j = 0; j < 4; ++j) {
        uint16_t lo = f2bf_rne(w1[(size_t)(krow + 2 * j) * 128 + col]);
        uint16_t hi = f2bf_rne(w1[(size_t)(krow + 2 * j + 1) * 128 + col]);
        od[j] = (uint32_t)lo | ((uint32_t)hi << 16);
    }
    *(uint4*)(w1f + (size_t)t * 8) = make_uint4(od[0], od[1], od[2], od[3]);
}

__global__ __launch_bounds__(256, 8) void gather_t_kernel(
    const float4* __restrict__ ray, const uint16_t* __restrict__ gt,
    uint32_t* __restrict__ featsT) {
    int lb = (blockIdx.x & 7) * 2304 + (blockIdx.x >> 3);
    int interp = lb >> 10;
    int r = ((lb & 1023) << 8) + threadIdx.x;
    int level = interp / 6;
    int comb = interp - level * 6;
    int H = 128 << level;

    float4 p = ray[r];
    int c0 = (0x211000 >> (4 * comb)) & 0xF;
    int c1 = (0x332321 >> (4 * comb)) & 0xF;
    float u = sel4(p, c0) * (float)(H - 1);
    float v = sel4(p, c1) * (float)(H - 1);
    float u0f = fminf(fmaxf(floorf(u), 0.0f), (float)(H - 2));
    float v0f = fminf(fmaxf(floorf(v), 0.0f), (float)(H - 2));
    float wu = u - u0f, wv = v - v0f;
    int u0 = (int)u0f, v0 = (int)v0f;

    uint32_t lvl_off = (level == 0) ? T0_OFF : ((level == 1) ? T1_OFF : T2_OFF);
    const uint16_t* gp0 = gt + lvl_off + (((size_t)comb * H + u0) * H + v0) * 16;
    const uint4* q0 = (const uint4*)gp0;
    const uint4* q1 = (const uint4*)(gp0 + (size_t)16 * H);
    uint4 a0 = q0[0], a1 = q0[1], a2 = q0[2], a3 = q0[3];
    uint4 b0 = q1[0], b1 = q1[1], b2 = q1[2], b3 = q1[3];

    uint32_t c00[8], c01[8], c10[8], c11[8];
    #pragma unroll
    for (int j = 0; j < 4; ++j) {
        c00[j] = ((const uint32_t*)&a0)[j];  c00[j + 4] = ((const uint32_t*)&a1)[j];
        c01[j] = ((const uint32_t*)&a2)[j];  c01[j + 4] = ((const uint32_t*)&a3)[j];
        c10[j] = ((const uint32_t*)&b0)[j];  c10[j + 4] = ((const uint32_t*)&b1)[j];
        c11[j] = ((const uint32_t*)&b2)[j];  c11[j + 4] = ((const uint32_t*)&b3)[j];
    }

    float w00 = (1.0f - wu) * (1.0f - wv);
    float w01 = (1.0f - wu) * wv;
    float w10 = wu * (1.0f - wv);
    float w11 = wu * wv;

    uint32_t od[8];
    #pragma unroll
    for (int j = 0; j < 8; ++j) {
        float lo = w00 * bf_lo(c00[j]) + w01 * bf_lo(c01[j]) +
                   w10 * bf_lo(c10[j]) + w11 * bf_lo(c11[j]);
        float hi = w00 * bf_hi(c00[j]) + w01 * bf_hi(c01[j]) +
                   w10 * bf_hi(c10[j]) + w11 * bf_hi(c11[j]);
        od[j] = (uint32_t)f2bf_rne(lo) | ((uint32_t)f2bf_rne(hi) << 16);
    }

    uint4* op = (uint4*)(featsT + ((size_t)interp * N_RAYS + r) * 8);
    op[0] = make_uint4(od[0], od[1], od[2], od[3]);
    op[1] = make_uint4(od[4], od[5], od[6], od[7]);
}

__global__ __launch_bounds__(256, 2) void mfma_mlp_kernel(
    const uint16_t* __restrict__ featsT,
    const uint16_t* __restrict__ w1f,
    const float* __restrict__ bias1,
    const float* __restrict__ w2, const float* __restrict__ bias2,
    const uint32_t* __restrict__ perm,
    float* __restrict__ out, int tiles_per_block) {
    __shared__ float s_h[32][132];

    int tid = threadIdx.x;
    int wv = tid >> 6;
    int lane = tid & 63;

    short8v bfr[2][9];
    #pragma unroll
    for (int ctl = 0; ctl < 2; ++ctl) {
        int ct = wv * 2 + ctl;
        #pragma unroll
        for (int kc = 0; kc < 9; ++kc)
            bfr[ctl][kc] = *(const short8v*)(w1f + (((size_t)(ct * 9 + kc)) * 64 + lane) * 8);
    }
    float b1c0 = bias1[wv * 32 + (lane & 15)];
    float b1c1 = bias1[wv * 32 + 16 + (lane & 15)];

    int jg = tid & 7;
    int j0 = jg * 16;
    float w2r0[16], w2r1[16], w2r2[16];
    #pragma unroll
    for (int jj = 0; jj < 16; ++jj) {
        const float* w2p = w2 + (size_t)(j0 + jj) * 3;
        w2r0[jj] = w2p[0]; w2r1[jj] = w2p[1]; w2r2[jj] = w2p[2];
    }
    float bb0 = bias2[0], bb1 = bias2[1], bb2 = bias2[2];

    int lg = lane >> 4;
    int half8 = (lg & 1) * 8;
    int ipo = lg >> 1;

    for (int it = 0; it < tiles_per_block; ++it) {
        int tile = blockIdx.x * tiles_per_block + it;
        int r0 = tile * 32;
        int rA = r0 + (lane & 15);

        short8v af[18];
        #pragma unroll
        for (int kc = 0; kc < 9; ++kc) {
            size_t base = ((size_t)(2 * kc + ipo) * N_RAYS + rA) * 16 + half8;
            af[kc]     = *(const short8v*)(featsT + base);
            af[9 + kc] = *(const short8v*)(featsT + base + 256);
        }

        float4v acc00, acc01, acc10, acc11;
        #pragma unroll
        for (int j = 0; j < 4; ++j) { acc00[j] = b1c0; acc01[j] = b1c1; acc10[j] = b1c0; acc11[j] = b1c1; }

        #pragma unroll
        for (int kc = 0; kc < 9; ++kc) {
            acc00 = __builtin_amdgcn_mfma_f32_16x16x32_bf16(af[kc],     bfr[0][kc], acc00, 0, 0, 0);
            acc01 = __builtin_amdgcn_mfma_f32_16x16x32_bf16(af[kc],     bfr[1][kc], acc01, 0, 0, 0);
            acc10 = __builtin_amdgcn_mfma_f32_16x16x32_bf16(af[9 + kc], bfr[0][kc], acc10, 0, 0, 0);
            acc11 = __builtin_amdgcn_mfma_f32_16x16x32_bf16(af[9 + kc], bfr[1][kc], acc11, 0, 0, 0);
        }

        __syncthreads();
        {
            int c0 = wv * 32 + (lane & 15);
            int rb = (lane >> 4) * 4;
            #pragma unroll
            for (int j = 0; j < 4; ++j) {
                s_h[rb + j][c0]           = fmaxf(acc00[j], 0.0f);
                s_h[rb + j][c0 + 16]      = fmaxf(acc01[j], 0.0f);
                s_h[rb + j + 16][c0]      = fmaxf(acc10[j], 0.0f);
                s_h[rb + j + 16][c0 + 16] = fmaxf(acc11[j], 0.0f);
            }
        }
        __syncthreads();

        int ray = tid >> 3;
        float p0 = 0.f, p1 = 0.f, p2 = 0.f;
        #pragma unroll
        for (int qq = 0; qq < 4; ++qq) {
            float4 hv = *(const float4*)&s_h[ray][j0 + qq * 4];
            float h0 = hv.x, h1 = hv.y, h2 = hv.z, h3 = hv.w;
            p0 += h0 * w2r0[qq * 4] + h1 * w2r0[qq * 4 + 1] + h2 * w2r0[qq * 4 + 2] + h3 * w2r0[qq * 4 + 3];
            p1 += h0 * w2r1[qq * 4] + h1 * w2r1[qq * 4 + 1] + h2 * w2r1[qq * 4 + 2] + h3 * w2r1[qq * 4 + 3];
            p2 += h0 * w2r2[qq * 4] + h1 * w2r2[qq * 4 + 1] + h2 * w2r2[qq * 4 + 2] + h3 * w2r2[qq * 4 + 3];
        }
        p0 += __shfl_xor(p0, 1); p0 += __shfl_xor(p0, 2); p0 += __shfl_xor(p0, 4);
        p1 += __shfl_xor(p1, 1); p1 += __shfl_xor(p1, 2); p1 += __shfl_xor(p1, 4);
        p2 += __shfl_xor(p2, 1); p2 += __shfl_xor(p2, 2); p2 += __shfl_xor(p2, 4);

        if (jg == 0) {
            int orig = perm ? (int)perm[r0 + ray] : (r0 + ray);
            float o0 = 1.0f / (1.0f + expf(-(p0 + bb0)));
            float o1 = 1.0f / (1.0f + expf(-(p1 + bb1)));
            float o2 = 1.0f / (1.0f + expf(-(p2 + bb2)));
            float* op = out + (size_t)orig * 3;
            op[0] = o0; op[1] = o1; op[2] = o2;
        }
    }
}

// ---------- tier-3/4 fallback fused kernel (small ws) ----------
template <bool USE_T>
__global__ __launch_bounds__(THREADS) void fused_kernel(
    const float4* __restrict__ ray,
    const float* __restrict__ g0, const float* __restrict__ g1,
    const float* __restrict__ g2,
    const __hip_bfloat16* __restrict__ gt,
    const float* __restrict__ weights1, const float* __restrict__ bias1,
    const float* __restrict__ weights2, const float* __restrict__ bias2,
    float* __restrict__ out) {
    __shared__ float4 s_ray[NR];
    __shared__ float s_feats[NR][FSTRIDE];

    int tid = threadIdx.x;
    int rbase = blockIdx.x * NR;
    if (tid < NR) s_ray[tid] = ray[rbase + tid];
    __syncthreads();

    for (int t = tid; t < NR * 36; t += THREADS) {
        int r = t / 36;
        int rem = t - r * 36;
        int interp = rem >> 1;
        int half = rem & 1;
        int level = (interp >= 12) ? 2 : ((interp >= 6) ? 1 : 0);
        int comb = interp - level * 6;
        int H = 128 << level;
        float4 p = s_ray[r];
        int c0 = (0x211000 >> (4 * comb)) & 0xF;
        int c1 = (0x332321 >> (4 * comb)) & 0xF;
        float u = sel4(p, c0) * (float)(H - 1);
        float v = sel4(p, c1) * (float)(H - 1);
        float u0f = fminf(fmaxf(floorf(u), 0.0f), (float)(H - 2));
        float v0f = fminf(fmaxf(floorf(v), 0.0f), (float)(H - 2));
        float wu = u - u0f, wv = v - v0f;
        int u0 = (int)u0f, v0 = (int)v0f;
        float w00 = (1.0f - wu) * (1.0f - wv);
        float w01 = (1.0f - wu) * wv;
        float w10 = wu * (1.0f - wv);
        float w11 = wu * wv;
        float f[8];
        if (USE_T) {
            uint32_t lvl_off = (level == 0) ? T0_OFF : ((level == 1) ? T1_OFF : T2_OFF);
            const uint16_t* gp = (const uint16_t*)gt + lvl_off +
                                 (((size_t)comb * H + u0) * H + v0) * 16 + half * 8;
            uint4 a00 = *(const uint4*)gp;
            uint4 a01 = *(const uint4*)(gp + 16);
            uint4 a10 = *(const uint4*)(gp + (size_t)16 * H);
            uint4 a11 = *(const uint4*)(gp + (size_t)16 * H + 16);
            #pragma unroll
            for (int i = 0; i < 8; ++i) {
                f[i] = w00 * bf_extract(a00, i) + w01 * bf_extract(a01, i) +
                       w10 * bf_extract(a10, i) + w11 * bf_extract(a11, i);
            }
        } else {
            const float* gp = (level == 0) ? g0 : ((level == 1) ? g1 : g2);
            const float* base = gp + ((size_t)(comb * 16 + half * 8) * H + u0) * H + v0;
            #pragma unroll
            for (int i = 0; i < 8; ++i) {
                const float* q = base + (size_t)i * H * H;
                float a00 = q[0], a01 = q[1], a10 = q[H], a11 = q[H + 1];
                f[i] = w00 * a00 + w01 * a01 + w10 * a10 + w11 * a11;
            }
        }
        int fo = interp * 16 + half * 8;
        float* fp = &s_feats[r][fo];
        #pragma unroll
        for (int i = 0; i < 8; ++i) fp[i] = f[i];
    }
    __syncthreads();

    int r = tid >> 3;
    int jg = tid & 7;
    int j0 = jg * 16;
    float acc[16];
    #pragma unroll
    for (int jj = 0; jj < 16; ++jj) acc[jj] = bias1[j0 + jj];

    const float* wp = weights1 + j0;
    for (int k = 0; k < 288; k += 4) {
        float4 fv = *(const float4*)&s_feats[r][k];
        #pragma unroll
        for (int kk = 0; kk < 4; ++kk) {
            const float4* wr = (const float4*)(wp + (size_t)(k + kk) * 128);
            float fk = (kk == 0) ? fv.x : ((kk == 1) ? fv.y : ((kk == 2) ? fv.z : fv.w));
            float4 wa = wr[0], wb = wr[1], wc = wr[2], wd = wr[3];
            acc[0]  += fk * wa.x; acc[1]  += fk * wa.y; acc[2]  += fk * wa.z; acc[3]  += fk * wa.w;
            acc[4]  += fk * wb.x; acc[5]  += fk * wb.y; acc[6]  += fk * wb.z; acc[7]  += fk * wb.w;
            acc[8]  += fk * wc.x; acc[9]  += fk * wc.y; acc[10] += fk * wc.z; acc[11] += fk * wc.w;
            acc[12] += fk * wd.x; acc[13] += fk * wd.y; acc[14] += fk * wd.z; acc[15] += fk * wd.w;
        }
    }

    float p0 = 0.f, p1 = 0.f, p2 = 0.f;
    #pragma unroll
    for (int jj = 0; jj < 16; ++jj) {
        float h = fmaxf(acc[jj], 0.0f);
        const float* w2r = weights2 + (size_t)(j0 + jj) * 3;
        p0 += h * w2r[0];
        p1 += h * w2r[1];
        p2 += h * w2r[2];
    }
    p0 += __shfl_xor(p0, 1); p0 += __shfl_xor(p0, 2); p0 += __shfl_xor(p0, 4);
    p1 += __shfl_xor(p1, 1); p1 += __shfl_xor(p1, 2); p1 += __shfl_xor(p1, 4);
    p2 += __shfl_xor(p2, 1); p2 += __shfl_xor(p2, 2); p2 += __shfl_xor(p2, 4);

    if (jg == 0) {
        float o0 = 1.0f / (1.0f + expf(-(p0 + bias2[0])));
        float o1 = 1.0f / (1.0f + expf(-(p1 + bias2[1])));
        float o2 = 1.0f / (1.0f + expf(-(p2 + bias2[2])));
        float* op = out + (size_t)(rbase + r) * 3;
        op[0] = o0; op[1] = o1; op[2] = o2;
    }
}

extern "C" void kernel_launch(void* const* d_in, const int* in_sizes, int n_in,
                              void* d_out, int out_size, void* d_ws, size_t ws_size,
                              hipStream_t stream) {
    const float4* ray = (const float4*)d_in[0];
    const float* g0 = (const float*)d_in[1];
    const float* g1 = (const float*)d_in[2];
    const float* g2 = (const float*)d_in[3];
    const float* w1 = (const float*)d_in[4];
    const float* b1 = (const float*)d_in[5];
    const float* w2 = (const float*)d_in[6];
    const float* b2 = (const float*)d_in[7];
    float* out = (float*)d_out;

    const size_t T_BYTES = (size_t)T_ELEMS * 2;
    const size_t NEED = (size_t)W1F_BYTE_OFF + W1F_BYTES;

    if (ws_size >= (size_t)NEED_SORT) {
        char* ws = (char*)d_ws;
        __hip_bfloat16* wsb = (__hip_bfloat16*)d_ws;
        uint32_t* bsum  = (uint32_t*)(ws + FEAT_BYTE_OFF);   // scratch (feat arena unused)
        uint16_t* w1f  = (uint16_t*)(ws + W1F_BYTE_OFF);
        uint16_t* keys = (uint16_t*)(ws + KEYS_OFF);
        uint32_t* perm = (uint32_t*)(ws + PERM_OFF);
        uint32_t* hist = (uint32_t*)(ws + HIST_OFF);
        uint32_t* offs = (uint32_t*)(ws + OFFS_OFF);
        float4* rsort  = (float4*)(ws + RSORT_OFF);

        hipMemsetAsync(hist, 0, 65536 * 4, stream);
        prep_kernel<<<PB_HI, 256, 0, stream>>>(
            g0, g1, g2, w1, ray, (uint16_t*)wsb, w1f, keys, hist);
        scanA_kernel<<<256, 256, 0, stream>>>(hist, bsum, offs);
        scanB_kernel<<<1, 256, 0, stream>>>(bsum);
        scatter_kernel<<<N_RAYS / 256, 256, 0, stream>>>(ray, keys, offs, bsum, perm, rsort);
        fused_gmlp_kernel<<<N_RAYS / 32, 256, 0, stream>>>(
            rsort, (const uint16_t*)wsb, w1f, b1, w2, b2, perm, out);
    } else if (ws_size >= NEED) {
        __hip_bfloat16* wsb = (__hip_bfloat16*)d_ws;
        transpose_kernel<<<(6 * 128 * 128 + 255) / 256, 256, 0, stream>>>(g0, wsb + T0_OFF, 128);
        transpose_kernel<<<(6 * 256 * 256 + 255) / 256, 256, 0, stream>>>(g1, wsb + T1_OFF, 256);
        transpose_kernel<<<(6 * 512 * 512 + 255) / 256, 256, 0, stream>>>(g2, wsb + T2_OFF, 512);
        uint32_t* feats = (uint32_t*)((char*)d_ws + FEAT_BYTE_OFF);
        uint16_t* w1f = (uint16_t*)((char*)d_ws + W1F_BYTE_OFF);
        w1_pack_kernel<<<72, 64, 0, stream>>>(w1, w1f);
        gather_t_kernel<<<18432, 256, 0, stream>>>(ray, (const uint16_t*)wsb, feats);
        const int TILES_PER_BLOCK = 4;
        int nblk = N_RAYS / 32 / TILES_PER_BLOCK;
        mfma_mlp_kernel<<<nblk, 256, 0, stream>>>(
            (const uint16_t*)feats, w1f, b1, w2, b2, nullptr, out, TILES_PER_BLOCK);
    } else if (ws_size >= T_BYTES) {
        __hip_bfloat16* wsb = (__hip_bfloat16*)d_ws;
        transpose_kernel<<<(6 * 128 * 128 + 255) / 256, 256, 0, stream>>>(g0, wsb + T0_OFF, 128);
        transpose_kernel<<<(6 * 256 * 256 + 255) / 256, 256, 0, stream>>>(g1, wsb + T1_OFF, 256);
        transpose_kernel<<<(6 * 512 * 512 + 255) / 256, 256, 0, stream>>>(g2, wsb + T2_OFF, 512);
        fused_kernel<true><<<N_RAYS / NR, THREADS, 0, stream>>>(
            ray, g0, g1, g2, wsb, w1, b1, w2, b2, out);
    } else {
        fused_kernel<false><<<N_RAYS / NR, THREADS, 0, stream>>>(
            ray, g0, g1, g2, nullptr, w1, b1, w2, b2, out);
    }
}